// Round 10
// baseline (1798.802 us; speedup 1.0000x reference)
//
#include <hip/hip_runtime.h>

typedef unsigned int uint;
typedef unsigned short ushort;
using half8v  = __attribute__((ext_vector_type(8))) _Float16;
using half4v  = __attribute__((ext_vector_type(4))) _Float16;
using float4v = __attribute__((ext_vector_type(4))) float;

#define EPS_SINK 0.0025f
#define EPS_LOG512 0.015595811562598769f
// base-2 sinkhorn constants: fold log2(e) into the scales
#define S_SCALE_L2   577.0780163555852f     // 400 * log2(e)
#define C_SCALE_L2  (-5.770780163555852f)   // -4 * log2(e)
#define EPS_LN2      0.0017328679513999f    // EPS_SINK * ln(2)

// ---- workspace layout (BYTE offsets), peak ~165 MB ----
static const size_t O_W1   = 0ull;             // 512*512*8 f16 = 4,194,304 B
static const size_t O_W2   = 4194304ull;       // 2,097,152 B each
static const size_t O_W3   = 6291456ull;
static const size_t O_W4   = 8388608ull;
static const size_t O_H0   = 20971520ull;      // 16*512*6400 f16 = 104,857,600 B
static const size_t O_H1   = 125829120ull;     // 16*256*1598 uint = 26,181,632 B
static const size_t O_H2   = 20971520ull;      // alias h0 (dead after conv1)
static const size_t O_H3   = 34045952ull;
static const size_t O_FEATX= 152010752ull;     // 16*512*224 f16 = 3,670,016 B
static const size_t O_FEATY= 158498816ull;
static const size_t O_STATS= 164986880ull;     // 512 floats
// cost phase (weights/h0/h1 all dead).  C stored f16, value = 100*C:
static const size_t O_CXY  = 0ull;             // 8,388,608 B each
static const size_t O_CTXY = 8388608ull;
static const size_t O_CXX  = 16777216ull;
static const size_t O_CYY  = 25165824ull;
static const size_t O_AAX  = 33554432ull;
static const size_t O_AAY  = 33587200ull;
static const size_t O_F    = 33619968ull;      // 3*16*512 fp32
static const size_t O_G    = 33718272ull;

#define GLOAD_LDS16(gp, lp) __builtin_amdgcn_global_load_lds( \
    (const __attribute__((address_space(1))) void*)(gp),       \
    (__attribute__((address_space(3))) void*)(lp), 16, 0, 0)

// ---------------------------------------------------------------------------
// prep_w: convert conv weights fp32 -> single f16. W1 [oc][ic][8 taps];
// W2-4 pair-interleaved [oc][icpair][dt0 icA, dt0 icB, dt1 icA, ...].
// ---------------------------------------------------------------------------
__global__ __launch_bounds__(256) void prep_w(
    const float* __restrict__ W1, const float* __restrict__ W2,
    const float* __restrict__ W3, const float* __restrict__ W4,
    _Float16* __restrict__ w1, _Float16* __restrict__ w2,
    _Float16* __restrict__ w3, _Float16* __restrict__ w4)
{
    const int layer = blockIdx.y;
    const int e = blockIdx.x * 256 + threadIdx.x;
    float v[8];
    _Float16* dh;
    if (layer == 0) {
        const float4 a = *(const float4*)(W1 + (size_t)e * 8);
        const float4 c = *(const float4*)(W1 + (size_t)e * 8 + 4);
        v[0]=a.x; v[1]=a.y; v[2]=a.z; v[3]=a.w; v[4]=c.x; v[5]=c.y; v[6]=c.z; v[7]=c.w;
        dh = w1;
    } else {
        if (e >= 131072) return;
        const float* W = (layer == 1) ? W2 : (layer == 2) ? W3 : W4;
        dh = (layer == 1) ? w2 : (layer == 2) ? w3 : w4;
        const int oc = e >> 8, icp = e & 255;
        const float4 a = *(const float4*)(W + ((size_t)oc * 512 + icp * 2) * 4);
        const float4 c = *(const float4*)(W + ((size_t)oc * 512 + icp * 2 + 1) * 4);
        v[0]=a.x; v[1]=c.x; v[2]=a.y; v[3]=c.y; v[4]=a.z; v[5]=c.z; v[6]=a.w; v[7]=c.w;
    }
    half8v hi;
#pragma unroll
    for (int k = 0; k < 8; ++k) hi[k] = (_Float16)v[k];
    *(half8v*)(dh + (size_t)e * 8) = hi;
}

// ---------------------------------------------------------------------------
// conv0_store: raw conv0 (k=10,s=5) -> h0 f16 [b][512][6400] + GN stats.
// ---------------------------------------------------------------------------
__global__ __launch_bounds__(256) void conv0_store(
    const float* __restrict__ wav, const float* __restrict__ W0,
    _Float16* __restrict__ h0, float* __restrict__ stats)
{
    __shared__ float LW[5120];
    __shared__ float red[2][256];
    const int tid = threadIdx.x;
    for (int e = tid; e < 5120; e += 256) LW[e] = W0[e];

    const int b = blockIdx.y;
    const int t = blockIdx.x * 256 + tid;
    const bool valid = (t < 6399);
    float xv[10];
#pragma unroll
    for (int d = 0; d < 10; ++d) xv[d] = 0.f;
    if (valid) {
        const float* wp = wav + (size_t)b * 32000 + (size_t)t * 5;
#pragma unroll
        for (int d = 0; d < 10; ++d) xv[d] = wp[d];
    }
    __syncthreads();

    float lsum = 0.f, lsq = 0.f;
    _Float16* hb = h0 + (size_t)b * 512 * 6400;
    for (int oc = 0; oc < 512; ++oc) {
        float a = 0.f;
#pragma unroll
        for (int d = 0; d < 10; ++d) a += LW[oc * 10 + d] * xv[d];
        if (valid) {
            hb[(size_t)oc * 6400 + t] = (_Float16)a;
            lsum += a; lsq += a * a;
        }
    }
    red[0][tid] = lsum; red[1][tid] = lsq;
    __syncthreads();
    for (int s2 = 128; s2 > 0; s2 >>= 1) {
        if (tid < s2) { red[0][tid] += red[0][tid + s2]; red[1][tid] += red[1][tid + s2]; }
        __syncthreads();
    }
    if (tid == 0) {
        atomicAdd(&stats[2 * b], red[0][0]);
        atomicAdd(&stats[2 * b + 1], red[1][0]);
    }
}

// ---------------------------------------------------------------------------
// conv1_mfma v6: layer1 (K=8,S=4), 128oc x 128t tile (proven structure,
// round-8 = 1690us config) + FUSED GN0 affine+ReLU on the X-load path.
// relu's v>0?v:0 maps NaN/garbage (unwritten h0 tail slot 6399) to 0.
// LDS 38 KB -> 4 blocks/CU.
// ---------------------------------------------------------------------------
__global__ __launch_bounds__(256, 4) void conv1_mfma(
    const _Float16* __restrict__ h0,
    const _Float16* __restrict__ w1,
    const float* __restrict__ stats0,
    const float* __restrict__ gamma0, const float* __restrict__ beta0,
    _Float16* __restrict__ oh, float* __restrict__ stats1)
{
    __shared__ _Float16 LW[2][2][4][128][8];   // 32 KB [buf][k32l][q][oc][8]
    __shared__ float LSC[512], LSH[512];       // 4 KB GN0 fold tables
    __shared__ float red[2][256];

    const int tid  = threadIdx.x;
    const int lane = tid & 63, wv = tid >> 6;
    const int m    = lane & 15, quad = lane >> 4;
    const int wv2  = wv >> 1, wvt = wv & 1;

    // chunked XCD swizzle: 832 blocks = 8 chunks of 104; y (oc-tile) fastest
    const int raw = blockIdx.x;
    const int cid = (raw & 7) * 104 + (raw >> 3);
    const int b   = cid / 52;
    const int r2  = cid - b * 52;
    const int xt  = r2 >> 2, yt = r2 & 3;
    const int ocb = yt * 128;
    const int t0  = xt * 128;
    const int Lout = 1598;

    // --- GN0 fold tables (stats0 complete at launch boundary)
    {
        const float invN = 1.f / (512.f * 6399.f);
        const float mu = stats0[2 * b] * invN;
        const float var = stats0[2 * b + 1] * invN - mu * mu;
        const float rs = rsqrtf(var + 1e-5f);
        for (int ic = tid; ic < 512; ic += 256) {
            const float sc = rs * gamma0[ic];
            LSC[ic] = sc;
            LSH[ic] = beta0[ic] - mu * sc;
        }
    }

    float4v acc[4][4];
#pragma unroll
    for (int i = 0; i < 4; ++i)
#pragma unroll
        for (int j = 0; j < 4; ++j) acc[i][j] = (float4v){0.f, 0.f, 0.f, 0.f};

    const _Float16* hb = h0 + (size_t)b * 512 * 6400;
    const int gbase = t0 * 4;
    const _Float16* px = hb + (size_t)quad * 6400 + gbase + (wvt * 64 + m) * 4;

    const _Float16* wsrc[4];
#pragma unroll
    for (int r = 0; r < 4; ++r) {
        const int e = wv * 4 + r;
        const int oh2 = e & 1, q = (e >> 1) & 3, k32l = e >> 3;
        wsrc[r] = w1 + ((size_t)(ocb + oh2 * 64 + lane) * 512 + (k32l * 4 + q)) * 8;
    }
    auto stageW = [&](int buf) {
#pragma unroll
        for (int r = 0; r < 4; ++r) {
            const int e = wv * 4 + r;
            const int oh2 = e & 1, q = (e >> 1) & 3, k32l = e >> 3;
            GLOAD_LDS16(wsrc[r], &LW[buf][k32l][q][oh2 * 64][0]);
            wsrc[r] += 64;                     // 8 ic * 8 taps
        }
    };

    stageW(0);
    __syncthreads();

    for (int it = 0; it < 64; ++it) {
        const int buf = it & 1;
        if (it < 63) stageW(buf ^ 1);
#pragma unroll
        for (int k32l = 0; k32l < 2; ++k32l) {
            half8v a4[4], bfv[4];
#pragma unroll
            for (int i = 0; i < 4; ++i)
                a4[i] = *(const half8v*)&LW[buf][k32l][quad][wv2 * 64 + i * 16 + m][0];
            const int ic = quad + 4 * k32l + 8 * it;
            const _Float16 sch = (_Float16)LSC[ic];
            const _Float16 shh = (_Float16)LSH[ic];
            const _Float16* pr = px + (size_t)k32l * 25600;   // +4 rows
#pragma unroll
            for (int j = 0; j < 4; ++j) {
                half8v xv = *(const half8v*)(pr + j * 64);
#pragma unroll
                for (int k = 0; k < 8; ++k) {
                    const _Float16 v = xv[k] * sch + shh;
                    xv[k] = (v > (_Float16)0.f) ? v : (_Float16)0.f;
                }
                bfv[j] = xv;
            }
#pragma unroll
            for (int i = 0; i < 4; ++i)
#pragma unroll
                for (int j = 0; j < 4; ++j)
                    acc[i][j] = __builtin_amdgcn_mfma_f32_16x16x32_f16(a4[i], bfv[j], acc[i][j], 0, 0, 0);
        }
        px += 51200;                           // +8 rows
        __syncthreads();
    }

    // --- epilogue: pack f16 pairs + stats (RAW conv1 outputs, pre-GN1)
    float lsum = 0.f, lsq = 0.f;
    uint* ohU = (uint*)oh;
#pragma unroll
    for (int i = 0; i < 4; ++i) {
        const int ocb2 = ocb + wv2 * 64 + i * 16 + quad * 4;
#pragma unroll
        for (int j = 0; j < 4; ++j) {
            const int t = t0 + wvt * 64 + j * 16 + m;
            if (t < Lout) {
#pragma unroll
                for (int pr = 0; pr < 2; ++pr) {
                    const float v0 = acc[i][j][pr * 2], v1 = acc[i][j][pr * 2 + 1];
                    union { uint u; _Float16 h[2]; } pk;
                    pk.h[0] = (_Float16)v0; pk.h[1] = (_Float16)v1;
                    const uint p = (uint)((ocb2 >> 1) + pr);
                    ohU[((size_t)(b * 256 + p)) * Lout + t] = pk.u;
                    lsum += v0 + v1; lsq += v0 * v0 + v1 * v1;
                }
            }
        }
    }
    red[0][tid] = lsum; red[1][tid] = lsq;
    __syncthreads();
    for (int s2 = 128; s2 > 0; s2 >>= 1) {
        if (tid < s2) { red[0][tid] += red[0][tid + s2]; red[1][tid] += red[1][tid + s2]; }
        __syncthreads();
    }
    if (tid == 0) {
        atomicAdd(&stats1[2 * b], red[0][0]);
        atomicAdd(&stats1[2 * b + 1], red[1][0]);
    }
}

// ---------------------------------------------------------------------------
// conv_mfma v5: layers 2-4 (K=4,S=2). 128oc x 64t tile, register dbuf X
// prefetch + FUSED prev-layer GN affine+ReLU at consume time (round-8 =
// 1690us config; 64t keeps grids at 832/448/256 blocks -- the 128t port
// starved the machine: 448/256/128 blocks = 0.5-1.75 blk/CU, +104us).
// PAIRED: f16 pair-interleaved out; else f16 features [ch][224] (padded).
// ---------------------------------------------------------------------------
template <bool PAIRED>
__global__ __launch_bounds__(256, 4) void conv_mfma(
    const _Float16* __restrict__ x,
    const _Float16* __restrict__ w,
    const float* __restrict__ statsP,
    const float* __restrict__ gammaP, const float* __restrict__ betaP,
    _Float16* __restrict__ oh, _Float16* __restrict__ ofeat,
    float* __restrict__ statsO, int Lin, int Lout, int nx)
{
    __shared__ _Float16 LW[2][2][4][128][8];   // 32 KB
    __shared__ float LN[256][4];               // sc0,sh0,sc1,sh1 per pair, 4 KB
    __shared__ float red[2][256];

    const int tid  = threadIdx.x;
    const int lane = tid & 63, wv = tid >> 6;
    const int m    = lane & 15, quad = lane >> 4;
    const int wv2  = wv >> 1, wvt = wv & 1;

    // chunked XCD swizzle (nwg = nx*64, always % 8 == 0), y fastest in chunk
    const int raw = blockIdx.x;
    const int chunk = (nx * 64) >> 3;
    const int cid = (raw & 7) * chunk + (raw >> 3);
    const int perb = nx * 4;
    const int b   = cid / perb;
    const int r2  = cid - b * perb;
    const int xt  = r2 >> 2, yt = r2 & 3;
    const int ocb = yt * 128;
    const int t0  = xt * 64;

    // --- prev-layer GN fold tables
    {
        const float invN = 1.f / (512.f * (float)Lin);
        const float mu = statsP[2 * b] * invN;
        const float var = statsP[2 * b + 1] * invN - mu * mu;
        const float rs = rsqrtf(var + 1e-5f);
        const int c0 = 2 * tid, c1 = 2 * tid + 1;
        const float sc0 = rs * gammaP[c0], sc1 = rs * gammaP[c1];
        LN[tid][0] = sc0; LN[tid][1] = betaP[c0] - mu * sc0;
        LN[tid][2] = sc1; LN[tid][3] = betaP[c1] - mu * sc1;
    }

    float4v acc[4][2];
#pragma unroll
    for (int i = 0; i < 4; ++i)
#pragma unroll
        for (int j = 0; j < 2; ++j) acc[i][j] = (float4v){0.f, 0.f, 0.f, 0.f};

    const size_t rstride = (size_t)Lin * 2;
    const _Float16* px = x + ((size_t)(b * 256) + quad) * rstride
                           + t0 * 4 + (wvt * 32 + m) * 4;

    const _Float16* wsrc[4];
#pragma unroll
    for (int r = 0; r < 4; ++r) {
        const int e = wv * 4 + r;
        const int oh2 = e & 1, q = (e >> 1) & 3, k32l = e >> 3;
        wsrc[r] = w + ((size_t)(ocb + oh2 * 64 + lane) * 256 + (k32l * 4 + q)) * 8;
    }
    auto stageW = [&](int buf) {
#pragma unroll
        for (int r = 0; r < 4; ++r) {
            const int e = wv * 4 + r;
            const int oh2 = e & 1, q = (e >> 1) & 3, k32l = e >> 3;
            GLOAD_LDS16(wsrc[r], &LW[buf][k32l][q][oh2 * 64][0]);
            wsrc[r] += 64;                     // 8 icp * 8
        }
    };
    auto loadX = [&](half8v (&xr)[4], const _Float16* p) {
#pragma unroll
        for (int k32l = 0; k32l < 2; ++k32l)
#pragma unroll
            for (int j = 0; j < 2; ++j)
                xr[k32l * 2 + j] = *(const half8v*)(p + (size_t)k32l * 4 * rstride + j * 64);
    };
    auto compute = [&](int buf, half8v (&xr)[4], int plB) {
#pragma unroll
        for (int k32l = 0; k32l < 2; ++k32l) {
            half8v a4[4];
#pragma unroll
            for (int i = 0; i < 4; ++i)
                a4[i] = *(const half8v*)&LW[buf][k32l][quad][wv2 * 64 + i * 16 + m][0];
            const int pl = plB + quad + 4 * k32l;
            const _Float16 s0 = (_Float16)LN[pl][0], h0v = (_Float16)LN[pl][1];
            const _Float16 s1 = (_Float16)LN[pl][2], h1v = (_Float16)LN[pl][3];
            half8v xn[2];
#pragma unroll
            for (int j = 0; j < 2; ++j) {
                half8v xv = xr[k32l * 2 + j];
#pragma unroll
                for (int k = 0; k < 8; ++k) {
                    const _Float16 v = xv[k] * ((k & 1) ? s1 : s0) + ((k & 1) ? h1v : h0v);
                    xv[k] = (v > (_Float16)0.f) ? v : (_Float16)0.f;
                }
                xn[j] = xv;
            }
#pragma unroll
            for (int i = 0; i < 4; ++i)
#pragma unroll
                for (int j = 0; j < 2; ++j)
                    acc[i][j] = __builtin_amdgcn_mfma_f32_16x16x32_f16(a4[i], xn[j], acc[i][j], 0, 0, 0);
        }
    };

    half8v xrA[4], xrB[4];
    loadX(xrA, px); px += 8 * rstride;         // iter 0
    stageW(0);
    __syncthreads();

    for (int it = 0; it < 32; it += 2) {
        stageW(1);
        loadX(xrB, px); px += 8 * rstride;     // iter it+1
        compute(0, xrA, 8 * it);
        __syncthreads();
        if (it + 2 < 32) {
            stageW(0);
            loadX(xrA, px);                    // iter it+2
        }
        px += 8 * rstride;
        compute(1, xrB, 8 * (it + 1));
        __syncthreads();
    }

    // --- epilogue (RAW conv outputs, pre-GN)
    float lsum = 0.f, lsq = 0.f;
    uint* ohU = (uint*)oh;
#pragma unroll
    for (int i = 0; i < 4; ++i) {
        const int ocb2 = ocb + wv2 * 64 + i * 16 + quad * 4;
#pragma unroll
        for (int j = 0; j < 2; ++j) {
            const int t = t0 + wvt * 32 + j * 16 + m;
            if (t < Lout) {
                if (PAIRED) {
#pragma unroll
                    for (int pr = 0; pr < 2; ++pr) {
                        const float v0 = acc[i][j][pr * 2], v1 = acc[i][j][pr * 2 + 1];
                        union { uint u; _Float16 h[2]; } pk;
                        pk.h[0] = (_Float16)v0; pk.h[1] = (_Float16)v1;
                        const uint p = (uint)((ocb2 >> 1) + pr);
                        ohU[((size_t)(b * 256 + p)) * Lout + t] = pk.u;
                        lsum += v0 + v1; lsq += v0 * v0 + v1 * v1;
                    }
                } else {
#pragma unroll
                    for (int r = 0; r < 4; ++r) {
                        const float v = acc[i][j][r];
                        ofeat[((size_t)(b * 512 + ocb2 + r)) * 224 + t] = (_Float16)v;
                        lsum += v; lsq += v * v;
                    }
                }
            }
        }
    }
    red[0][tid] = lsum; red[1][tid] = lsq;
    __syncthreads();
    for (int s2 = 128; s2 > 0; s2 >>= 1) {
        if (tid < s2) { red[0][tid] += red[0][tid + s2]; red[1][tid] += red[1][tid + s2]; }
        __syncthreads();
    }
    if (tid == 0) {
        atomicAdd(&statsO[2 * b], red[0][0]);
        atomicAdd(&statsO[2 * b + 1], red[1][0]);
    }
}

// ---------------------------------------------------------------------------
// norm_feat: GN+affine+ReLU in place on f16 features [row][224], t<198.
// ---------------------------------------------------------------------------
__global__ __launch_bounds__(256) void norm_feat(
    _Float16* __restrict__ h, const float* __restrict__ stats,
    const float* __restrict__ gamma, const float* __restrict__ beta)
{
    const int row = blockIdx.y;
    const int b = row >> 9, oc = row & 511;
    const int t = threadIdx.x;
    if (t >= 198) return;
    const float invN = 1.f / (512.f * 198.f);
    const float mu = stats[2 * b] * invN;
    const float var = stats[2 * b + 1] * invN - mu * mu;
    const float rs = rsqrtf(var + 1e-5f);
    const float sc = rs * gamma[oc];
    const float sh = beta[oc] - mu * sc;
    const size_t i = (size_t)row * 224 + t;
    const float v = (float)h[i] * sc + sh;
    h[i] = (_Float16)(v > 0.f ? v : 0.f);
}

// ---------------------------------------------------------------------------
// aa_kernel: row squared-norms of f16 features [row][224] (pad is zero).
// ---------------------------------------------------------------------------
__global__ __launch_bounds__(256) void aa_kernel(
    const _Float16* __restrict__ fX, const _Float16* __restrict__ fY,
    float* __restrict__ aaX, float* __restrict__ aaY)
{
    const int wave = threadIdx.x >> 6, lane = threadIdx.x & 63;
    const int R = blockIdx.x * 4 + wave;
    const _Float16* f = (R < 8192) ? fX : fY;
    const int r = R & 8191;
    const _Float16* row = f + (size_t)r * 224;
    float s = 0.f;
    if (lane < 56) {
        const half4v v = *(const half4v*)(row + lane * 4);
#pragma unroll
        for (int k = 0; k < 4; ++k) { const float x = (float)v[k]; s += x * x; }
    }
#pragma unroll
    for (int off = 32; off > 0; off >>= 1) s += __shfl_xor(s, off);
    if (lane == 0) ((R < 8192) ? aaX : aaY)[r] = s;
}

// ---------------------------------------------------------------------------
// cost_kernel v2: MFMA GEMM on f16 features (K padded to 224, zeros).
// Symmetric mats (xx,yy): upper tiles only, mirror-write.
// M = f16( min(50 * max(aa[n]+bb[m]-2<p,q>, 0), 65000) ) == 100*C
// ---------------------------------------------------------------------------
__global__ __launch_bounds__(256) void cost_kernel(
    const _Float16* __restrict__ fX, const _Float16* __restrict__ fY,
    const float* __restrict__ aaX, const float* __restrict__ aaY,
    _Float16* __restrict__ Cxy, _Float16* __restrict__ Cxx,
    _Float16* __restrict__ Cyy, _Float16* __restrict__ CTxy)
{
    const int z = blockIdx.y;
    const int mat = z >> 4, b = z & 15;
    const int nt = blockIdx.x & 3, mt = blockIdx.x >> 2;
    if (mat != 0 && nt > mt) return;
    const _Float16 *P, *Q; const float *aP, *aQ;
    _Float16 *Cm, *CT;
    if (mat == 0)      { P = fX; Q = fY; aP = aaX; aQ = aaY; Cm = Cxy; CT = CTxy; }
    else if (mat == 1) { P = fX; Q = fX; aP = aaX; aQ = aaX; Cm = Cxx; CT = (nt < mt) ? Cxx : nullptr; }
    else               { P = fY; Q = fY; aP = aaY; aQ = aaY; Cm = Cyy; CT = (nt < mt) ? Cyy : nullptr; }

    const int tid = threadIdx.x, lane = tid & 63, wv = tid >> 6;
    const int m16 = lane & 15, quad = lane >> 4;
    const int wv2 = wv >> 1, wvt = wv & 1;
    const int nb = nt * 128 + wv2 * 64;
    const int mb = mt * 128 + wvt * 64;
    const _Float16* Pb = P + (size_t)b * 512 * 224;
    const _Float16* Qb = Q + (size_t)b * 512 * 224;

    float4v acc[4][4];
#pragma unroll
    for (int i = 0; i < 4; ++i)
#pragma unroll
        for (int j = 0; j < 4; ++j) acc[i][j] = (float4v){0.f, 0.f, 0.f, 0.f};

    for (int k32 = 0; k32 < 7; ++k32) {
        const int ko = k32 * 32 + quad * 8;
        half8v a4[4], b4[4];
#pragma unroll
        for (int i = 0; i < 4; ++i)
            a4[i] = *(const half8v*)(Pb + (size_t)(nb + i * 16 + m16) * 224 + ko);
#pragma unroll
        for (int j = 0; j < 4; ++j)
            b4[j] = *(const half8v*)(Qb + (size_t)(mb + j * 16 + m16) * 224 + ko);
#pragma unroll
        for (int i = 0; i < 4; ++i)
#pragma unroll
            for (int j = 0; j < 4; ++j)
                acc[i][j] = __builtin_amdgcn_mfma_f32_16x16x32_f16(a4[i], b4[j], acc[i][j], 0, 0, 0);
    }

#pragma unroll
    for (int i = 0; i < 4; ++i) {
        const int nrow0 = nb + i * 16 + quad * 4;
        float aa4[4];
#pragma unroll
        for (int r = 0; r < 4; ++r) aa4[r] = aP[b * 512 + nrow0 + r];
#pragma unroll
        for (int j = 0; j < 4; ++j) {
            const int mcol = mb + j * 16 + m16;
            const float bbm = aQ[b * 512 + mcol];
#pragma unroll
            for (int r = 0; r < 4; ++r) {
                const int n = nrow0 + r;
                float c = 50.f * fmaxf(aa4[r] + bbm - 2.f * acc[i][j][r], 0.f);
                c = fminf(c, 65000.f);
                const _Float16 ch = (_Float16)c;
                Cm[((size_t)(b * 512 + n)) * 512 + mcol] = ch;
                if (CT) CT[((size_t)(b * 512 + mcol)) * 512 + n] = ch;
            }
        }
    }
}

// ---------------------------------------------------------------------------
// Per-row half-update, base-2 domain (log2e folded into the scales):
// LSE_nat = ln2 * (MX + log2( sum 2^(A-MX) )), A = 400*log2e*src - 4*log2e*C.
// dst[p*512+i] = eps*log512 - eps*ln2*(MX + log2(ss))
// exp2f/log2f are native v_exp_f32/v_log_f32 (verified absmax=0, round 9).
// ---------------------------------------------------------------------------
static __device__ __forceinline__ void sink_rows(
    float* __restrict__ dst, const float* __restrict__ src,
    const _Float16* __restrict__ Mb, int p, int i0, int lane)
{
    const float* sp = src + (size_t)p * 512;
    float s8[8];
    {
        const float4 sa = *(const float4*)&sp[lane * 8];
        const float4 sb = *(const float4*)&sp[lane * 8 + 4];
        s8[0]=sa.x*S_SCALE_L2; s8[1]=sa.y*S_SCALE_L2; s8[2]=sa.z*S_SCALE_L2; s8[3]=sa.w*S_SCALE_L2;
        s8[4]=sb.x*S_SCALE_L2; s8[5]=sb.y*S_SCALE_L2; s8[6]=sb.z*S_SCALE_L2; s8[7]=sb.w*S_SCALE_L2;
    }
#pragma unroll
    for (int rr = 0; rr < 4; ++rr) {
        const int i = i0 + rr;
        const half8v rv = *(const half8v*)(Mb + (size_t)i * 512 + lane * 8);
        float a8[8];
#pragma unroll
        for (int k = 0; k < 8; ++k) a8[k] = fmaf(C_SCALE_L2, (float)rv[k], s8[k]);
        float mx = a8[0];
#pragma unroll
        for (int k = 1; k < 8; ++k) mx = fmaxf(mx, a8[k]);
        // wave-global max (fmax butterfly, no exps)
#pragma unroll
        for (int off = 32; off > 0; off >>= 1) mx = fmaxf(mx, __shfl_xor(mx, off));
        // sum of 2^(a - global max)
        float ss = 0.f;
#pragma unroll
        for (int k = 0; k < 8; ++k) ss += exp2f(a8[k] - mx);
#pragma unroll
        for (int off = 32; off > 0; off >>= 1) ss += __shfl_xor(ss, off);
        if (lane == 0)
            dst[(size_t)p * 512 + i] = EPS_LOG512 - EPS_LN2 * (mx + log2f(ss));
    }
}

// ---------------------------------------------------------------------------
// sink_update: one half-update per launch; grid (32,48), 256 thr.
// ---------------------------------------------------------------------------
__global__ __launch_bounds__(256) void sink_update(
    float* __restrict__ dst, const float* __restrict__ src,
    const _Float16* __restrict__ M0, const _Float16* __restrict__ M1,
    const _Float16* __restrict__ M2)
{
    const int p = blockIdx.y;
    const int mat = p >> 4, b = p & 15;
    const _Float16* M = ((mat == 0) ? M0 : ((mat == 1) ? M1 : M2)) + (size_t)b * 512 * 512;
    const int wave = threadIdx.x >> 6, lane = threadIdx.x & 63;
    const int i0 = blockIdx.x * 16 + wave * 4;
    sink_rows(dst, src, M, p, i0, lane);
}

// ---------------------------------------------------------------------------
__global__ __launch_bounds__(256) void final_kernel(
    const float* __restrict__ f, const float* __restrict__ g,
    float* __restrict__ out)
{
    const int b = blockIdx.x, tid = threadIdx.x;
    __shared__ float red[256];
    float a = 0.f;
    for (int n = tid; n < 512; n += 256) {
        const float xy = f[(0 * 16 + b) * 512 + n] + g[(0 * 16 + b) * 512 + n];
        const float xx = f[(1 * 16 + b) * 512 + n] + g[(1 * 16 + b) * 512 + n];
        const float yy = f[(2 * 16 + b) * 512 + n] + g[(2 * 16 + b) * 512 + n];
        a += xy - 0.5f * (xx + yy);
    }
    red[tid] = a;
    __syncthreads();
    for (int s2 = 128; s2 > 0; s2 >>= 1) {
        if (tid < s2) red[tid] += red[tid + s2];
        __syncthreads();
    }
    if (tid == 0) out[b] = red[0] * (1.0f / 512.0f);
}

// ---------------------------------------------------------------------------
extern "C" void kernel_launch(void* const* d_in, const int* in_sizes, int n_in,
                              void* d_out, int out_size, void* d_ws, size_t ws_size,
                              hipStream_t stream)
{
    (void)in_sizes; (void)n_in; (void)out_size; (void)ws_size;
    char* ws = (char*)d_ws;
    const float* yhat = (const float*)d_in[0];
    const float* ysig = (const float*)d_in[1];
    const float* Wl[5]; const float* gl[5]; const float* bl[5];
    for (int i = 0; i < 5; ++i) {
        Wl[i] = (const float*)d_in[2 + 3 * i];
        gl[i] = (const float*)d_in[3 + 3 * i];
        bl[i] = (const float*)d_in[4 + 3 * i];
    }
    float* out = (float*)d_out;
    float* statsA = (float*)(ws + O_STATS);

    _Float16* w1 = (_Float16*)(ws + O_W1);
    _Float16* w2 = (_Float16*)(ws + O_W2);
    _Float16* w3 = (_Float16*)(ws + O_W3);
    _Float16* w4 = (_Float16*)(ws + O_W4);
    _Float16* h0 = (_Float16*)(ws + O_H0);
    _Float16* h1 = (_Float16*)(ws + O_H1);
    _Float16* h2 = (_Float16*)(ws + O_H2);
    _Float16* h3 = (_Float16*)(ws + O_H3);

    hipMemsetAsync(statsA, 0, 512 * sizeof(float), stream);
    // zero f16 feature buffers (incl. K-pad columns 198..223)
    hipMemsetAsync(ws + O_FEATX, 0, 16 * 512 * 224 * 2, stream);
    hipMemsetAsync(ws + O_FEATY, 0, 16 * 512 * 224 * 2, stream);
    prep_w<<<dim3(1024, 4), 256, 0, stream>>>(Wl[1], Wl[2], Wl[3], Wl[4],
        w1, w2, w3, w4);

    for (int s = 0; s < 2; ++s) {
        const float* wav = (s == 0) ? yhat : ysig;
        float* st = statsA + (size_t)s * 160;
        _Float16* ft = (_Float16*)(ws + ((s == 0) ? O_FEATX : O_FEATY));

        conv0_store<<<dim3(25, 16), 256, 0, stream>>>(wav, Wl[0], h0, st);

        conv1_mfma<<<dim3(832), 256, 0, stream>>>(
            h0, w1, st, gl[0], bl[0], h1, st + 32);

        conv_mfma<true><<<dim3(832), 256, 0, stream>>>(
            h1, w2, st + 32, gl[1], bl[1], h2, nullptr, st + 64, 1598, 798, 13);

        conv_mfma<true><<<dim3(448), 256, 0, stream>>>(
            h2, w3, st + 64, gl[2], bl[2], h3, nullptr, st + 96, 798, 398, 7);

        conv_mfma<false><<<dim3(256), 256, 0, stream>>>(
            h3, w4, st + 96, gl[3], bl[3], nullptr, ft, st + 128, 398, 198, 4);

        norm_feat<<<dim3(1, 8192), 256, 0, stream>>>(
            ft, st + 128, gl[4], bl[4]);
    }

    _Float16* featX = (_Float16*)(ws + O_FEATX);
    _Float16* featY = (_Float16*)(ws + O_FEATY);
    aa_kernel<<<4096, 256, 0, stream>>>(featX, featY, (float*)(ws + O_AAX), (float*)(ws + O_AAY));
    cost_kernel<<<dim3(16, 48), 256, 0, stream>>>(
        featX, featY, (float*)(ws + O_AAX), (float*)(ws + O_AAY),
        (_Float16*)(ws + O_CXY), (_Float16*)(ws + O_CXX), (_Float16*)(ws + O_CYY),
        (_Float16*)(ws + O_CTXY));

    hipMemsetAsync(ws + O_F, 0, 2 * 24576 * sizeof(float), stream);

    float* fptr = (float*)(ws + O_F);
    float* gptr = (float*)(ws + O_G);
    _Float16* cxy  = (_Float16*)(ws + O_CXY);
    _Float16* ctxy = (_Float16*)(ws + O_CTXY);
    _Float16* cxx  = (_Float16*)(ws + O_CXX);
    _Float16* cyy  = (_Float16*)(ws + O_CYY);

    for (int it = 0; it < 50; ++it) {
        sink_update<<<dim3(32, 48), 256, 0, stream>>>(gptr, fptr, ctxy, cxx, cyy);
        sink_update<<<dim3(32, 48), 256, 0, stream>>>(fptr, gptr, cxy, cxx, cyy);
    }

    final_kernel<<<16, 256, 0, stream>>>(fptr, gptr, out);
}

// Round 11
// 1676.363 us; speedup vs baseline: 1.0730x; 1.0730x over previous
//
#include <hip/hip_runtime.h>

typedef unsigned int uint;
typedef unsigned short ushort;
using half8v  = __attribute__((ext_vector_type(8))) _Float16;
using half4v  = __attribute__((ext_vector_type(4))) _Float16;
using float4v = __attribute__((ext_vector_type(4))) float;

#define EPS_SINK 0.0025f
#define EPS_LOG512 0.015595811562598769f

// ---- workspace layout (BYTE offsets), peak ~165 MB ----
static const size_t O_W1   = 0ull;             // 512*512*8 f16 = 4,194,304 B
static const size_t O_W2   = 4194304ull;       // 2,097,152 B each
static const size_t O_W3   = 6291456ull;
static const size_t O_W4   = 8388608ull;
static const size_t O_H0   = 20971520ull;      // 16*512*6400 f16 = 104,857,600 B
static const size_t O_H1   = 125829120ull;     // 16*256*1598 uint = 26,181,632 B
static const size_t O_H2   = 20971520ull;      // alias h0 (dead after conv1)
static const size_t O_H3   = 34045952ull;
static const size_t O_FEATX= 152010752ull;     // 16*512*224 f16 = 3,670,016 B
static const size_t O_FEATY= 158498816ull;
static const size_t O_STATS= 164986880ull;     // 512 floats
// cost phase (weights/h0/h1 all dead).  C stored f16, value = 100*C:
static const size_t O_CXY  = 0ull;             // 8,388,608 B each
static const size_t O_CTXY = 8388608ull;
static const size_t O_CXX  = 16777216ull;
static const size_t O_CYY  = 25165824ull;
static const size_t O_AAX  = 33554432ull;
static const size_t O_AAY  = 33587200ull;
static const size_t O_F    = 33619968ull;      // 3*16*512 fp32
static const size_t O_G    = 33718272ull;

#define GLOAD_LDS16(gp, lp) __builtin_amdgcn_global_load_lds( \
    (const __attribute__((address_space(1))) void*)(gp),       \
    (__attribute__((address_space(3))) void*)(lp), 16, 0, 0)

// ---------------------------------------------------------------------------
// prep_w: convert conv weights fp32 -> single f16. W1 [oc][ic][8 taps];
// W2-4 pair-interleaved [oc][icpair][dt0 icA, dt0 icB, dt1 icA, ...].
// ---------------------------------------------------------------------------
__global__ __launch_bounds__(256) void prep_w(
    const float* __restrict__ W1, const float* __restrict__ W2,
    const float* __restrict__ W3, const float* __restrict__ W4,
    _Float16* __restrict__ w1, _Float16* __restrict__ w2,
    _Float16* __restrict__ w3, _Float16* __restrict__ w4)
{
    const int layer = blockIdx.y;
    const int e = blockIdx.x * 256 + threadIdx.x;
    float v[8];
    _Float16* dh;
    if (layer == 0) {
        const float4 a = *(const float4*)(W1 + (size_t)e * 8);
        const float4 c = *(const float4*)(W1 + (size_t)e * 8 + 4);
        v[0]=a.x; v[1]=a.y; v[2]=a.z; v[3]=a.w; v[4]=c.x; v[5]=c.y; v[6]=c.z; v[7]=c.w;
        dh = w1;
    } else {
        if (e >= 131072) return;
        const float* W = (layer == 1) ? W2 : (layer == 2) ? W3 : W4;
        dh = (layer == 1) ? w2 : (layer == 2) ? w3 : w4;
        const int oc = e >> 8, icp = e & 255;
        const float4 a = *(const float4*)(W + ((size_t)oc * 512 + icp * 2) * 4);
        const float4 c = *(const float4*)(W + ((size_t)oc * 512 + icp * 2 + 1) * 4);
        v[0]=a.x; v[1]=c.x; v[2]=a.y; v[3]=c.y; v[4]=a.z; v[5]=c.z; v[6]=a.w; v[7]=c.w;
    }
    half8v hi;
#pragma unroll
    for (int k = 0; k < 8; ++k) hi[k] = (_Float16)v[k];
    *(half8v*)(dh + (size_t)e * 8) = hi;
}

// ---------------------------------------------------------------------------
// conv0_store: raw conv0 (k=10,s=5) -> h0 f16 [b][512][6400] + GN stats.
// ---------------------------------------------------------------------------
__global__ __launch_bounds__(256) void conv0_store(
    const float* __restrict__ wav, const float* __restrict__ W0,
    _Float16* __restrict__ h0, float* __restrict__ stats)
{
    __shared__ float LW[5120];
    __shared__ float red[2][256];
    const int tid = threadIdx.x;
    for (int e = tid; e < 5120; e += 256) LW[e] = W0[e];

    const int b = blockIdx.y;
    const int t = blockIdx.x * 256 + tid;
    const bool valid = (t < 6399);
    float xv[10];
#pragma unroll
    for (int d = 0; d < 10; ++d) xv[d] = 0.f;
    if (valid) {
        const float* wp = wav + (size_t)b * 32000 + (size_t)t * 5;
#pragma unroll
        for (int d = 0; d < 10; ++d) xv[d] = wp[d];
    }
    __syncthreads();

    float lsum = 0.f, lsq = 0.f;
    _Float16* hb = h0 + (size_t)b * 512 * 6400;
    for (int oc = 0; oc < 512; ++oc) {
        float a = 0.f;
#pragma unroll
        for (int d = 0; d < 10; ++d) a += LW[oc * 10 + d] * xv[d];
        if (valid) {
            hb[(size_t)oc * 6400 + t] = (_Float16)a;
            lsum += a; lsq += a * a;
        }
    }
    red[0][tid] = lsum; red[1][tid] = lsq;
    __syncthreads();
    for (int s2 = 128; s2 > 0; s2 >>= 1) {
        if (tid < s2) { red[0][tid] += red[0][tid + s2]; red[1][tid] += red[1][tid + s2]; }
        __syncthreads();
    }
    if (tid == 0) {
        atomicAdd(&stats[2 * b], red[0][0]);
        atomicAdd(&stats[2 * b + 1], red[1][0]);
    }
}

// ---------------------------------------------------------------------------
// conv1_mfma v6: layer1 (K=8,S=4), 128oc x 128t tile (proven structure,
// round-8 = 1690us config) + FUSED GN0 affine+ReLU on the X-load path.
// relu's v>0?v:0 maps NaN/garbage (unwritten h0 tail slot 6399) to 0.
// LDS 38 KB -> 4 blocks/CU.
// ---------------------------------------------------------------------------
__global__ __launch_bounds__(256, 4) void conv1_mfma(
    const _Float16* __restrict__ h0,
    const _Float16* __restrict__ w1,
    const float* __restrict__ stats0,
    const float* __restrict__ gamma0, const float* __restrict__ beta0,
    _Float16* __restrict__ oh, float* __restrict__ stats1)
{
    __shared__ _Float16 LW[2][2][4][128][8];   // 32 KB [buf][k32l][q][oc][8]
    __shared__ float LSC[512], LSH[512];       // 4 KB GN0 fold tables
    __shared__ float red[2][256];

    const int tid  = threadIdx.x;
    const int lane = tid & 63, wv = tid >> 6;
    const int m    = lane & 15, quad = lane >> 4;
    const int wv2  = wv >> 1, wvt = wv & 1;

    // chunked XCD swizzle: 832 blocks = 8 chunks of 104; y (oc-tile) fastest
    const int raw = blockIdx.x;
    const int cid = (raw & 7) * 104 + (raw >> 3);
    const int b   = cid / 52;
    const int r2  = cid - b * 52;
    const int xt  = r2 >> 2, yt = r2 & 3;
    const int ocb = yt * 128;
    const int t0  = xt * 128;
    const int Lout = 1598;

    // --- GN0 fold tables (stats0 complete at launch boundary)
    {
        const float invN = 1.f / (512.f * 6399.f);
        const float mu = stats0[2 * b] * invN;
        const float var = stats0[2 * b + 1] * invN - mu * mu;
        const float rs = rsqrtf(var + 1e-5f);
        for (int ic = tid; ic < 512; ic += 256) {
            const float sc = rs * gamma0[ic];
            LSC[ic] = sc;
            LSH[ic] = beta0[ic] - mu * sc;
        }
    }

    float4v acc[4][4];
#pragma unroll
    for (int i = 0; i < 4; ++i)
#pragma unroll
        for (int j = 0; j < 4; ++j) acc[i][j] = (float4v){0.f, 0.f, 0.f, 0.f};

    const _Float16* hb = h0 + (size_t)b * 512 * 6400;
    const int gbase = t0 * 4;
    const _Float16* px = hb + (size_t)quad * 6400 + gbase + (wvt * 64 + m) * 4;

    const _Float16* wsrc[4];
#pragma unroll
    for (int r = 0; r < 4; ++r) {
        const int e = wv * 4 + r;
        const int oh2 = e & 1, q = (e >> 1) & 3, k32l = e >> 3;
        wsrc[r] = w1 + ((size_t)(ocb + oh2 * 64 + lane) * 512 + (k32l * 4 + q)) * 8;
    }
    auto stageW = [&](int buf) {
#pragma unroll
        for (int r = 0; r < 4; ++r) {
            const int e = wv * 4 + r;
            const int oh2 = e & 1, q = (e >> 1) & 3, k32l = e >> 3;
            GLOAD_LDS16(wsrc[r], &LW[buf][k32l][q][oh2 * 64][0]);
            wsrc[r] += 64;                     // 8 ic * 8 taps
        }
    };

    stageW(0);
    __syncthreads();

    for (int it = 0; it < 64; ++it) {
        const int buf = it & 1;
        if (it < 63) stageW(buf ^ 1);
#pragma unroll
        for (int k32l = 0; k32l < 2; ++k32l) {
            half8v a4[4], bfv[4];
#pragma unroll
            for (int i = 0; i < 4; ++i)
                a4[i] = *(const half8v*)&LW[buf][k32l][quad][wv2 * 64 + i * 16 + m][0];
            const int ic = quad + 4 * k32l + 8 * it;
            const _Float16 sch = (_Float16)LSC[ic];
            const _Float16 shh = (_Float16)LSH[ic];
            const _Float16* pr = px + (size_t)k32l * 25600;   // +4 rows
#pragma unroll
            for (int j = 0; j < 4; ++j) {
                half8v xv = *(const half8v*)(pr + j * 64);
#pragma unroll
                for (int k = 0; k < 8; ++k) {
                    const _Float16 v = xv[k] * sch + shh;
                    xv[k] = (v > (_Float16)0.f) ? v : (_Float16)0.f;
                }
                bfv[j] = xv;
            }
#pragma unroll
            for (int i = 0; i < 4; ++i)
#pragma unroll
                for (int j = 0; j < 4; ++j)
                    acc[i][j] = __builtin_amdgcn_mfma_f32_16x16x32_f16(a4[i], bfv[j], acc[i][j], 0, 0, 0);
        }
        px += 51200;                           // +8 rows
        __syncthreads();
    }

    // --- epilogue: pack f16 pairs + stats (RAW conv1 outputs, pre-GN1)
    float lsum = 0.f, lsq = 0.f;
    uint* ohU = (uint*)oh;
#pragma unroll
    for (int i = 0; i < 4; ++i) {
        const int ocb2 = ocb + wv2 * 64 + i * 16 + quad * 4;
#pragma unroll
        for (int j = 0; j < 4; ++j) {
            const int t = t0 + wvt * 64 + j * 16 + m;
            if (t < Lout) {
#pragma unroll
                for (int pr = 0; pr < 2; ++pr) {
                    const float v0 = acc[i][j][pr * 2], v1 = acc[i][j][pr * 2 + 1];
                    union { uint u; _Float16 h[2]; } pk;
                    pk.h[0] = (_Float16)v0; pk.h[1] = (_Float16)v1;
                    const uint p = (uint)((ocb2 >> 1) + pr);
                    ohU[((size_t)(b * 256 + p)) * Lout + t] = pk.u;
                    lsum += v0 + v1; lsq += v0 * v0 + v1 * v1;
                }
            }
        }
    }
    red[0][tid] = lsum; red[1][tid] = lsq;
    __syncthreads();
    for (int s2 = 128; s2 > 0; s2 >>= 1) {
        if (tid < s2) { red[0][tid] += red[0][tid + s2]; red[1][tid] += red[1][tid + s2]; }
        __syncthreads();
    }
    if (tid == 0) {
        atomicAdd(&stats1[2 * b], red[0][0]);
        atomicAdd(&stats1[2 * b + 1], red[1][0]);
    }
}

// ---------------------------------------------------------------------------
// conv_mfma v5: layers 2-4 (K=4,S=2). 128oc x 64t tile, register dbuf X
// prefetch + FUSED prev-layer GN affine+ReLU at consume time (round-8 =
// 1690us config; 64t keeps grids at 832/448/256 blocks).
// PAIRED: f16 pair-interleaved out; else f16 features [ch][224] (padded).
// ---------------------------------------------------------------------------
template <bool PAIRED>
__global__ __launch_bounds__(256, 4) void conv_mfma(
    const _Float16* __restrict__ x,
    const _Float16* __restrict__ w,
    const float* __restrict__ statsP,
    const float* __restrict__ gammaP, const float* __restrict__ betaP,
    _Float16* __restrict__ oh, _Float16* __restrict__ ofeat,
    float* __restrict__ statsO, int Lin, int Lout, int nx)
{
    __shared__ _Float16 LW[2][2][4][128][8];   // 32 KB
    __shared__ float LN[256][4];               // sc0,sh0,sc1,sh1 per pair, 4 KB
    __shared__ float red[2][256];

    const int tid  = threadIdx.x;
    const int lane = tid & 63, wv = tid >> 6;
    const int m    = lane & 15, quad = lane >> 4;
    const int wv2  = wv >> 1, wvt = wv & 1;

    // chunked XCD swizzle (nwg = nx*64, always % 8 == 0), y fastest in chunk
    const int raw = blockIdx.x;
    const int chunk = (nx * 64) >> 3;
    const int cid = (raw & 7) * chunk + (raw >> 3);
    const int perb = nx * 4;
    const int b   = cid / perb;
    const int r2  = cid - b * perb;
    const int xt  = r2 >> 2, yt = r2 & 3;
    const int ocb = yt * 128;
    const int t0  = xt * 64;

    // --- prev-layer GN fold tables
    {
        const float invN = 1.f / (512.f * (float)Lin);
        const float mu = statsP[2 * b] * invN;
        const float var = statsP[2 * b + 1] * invN - mu * mu;
        const float rs = rsqrtf(var + 1e-5f);
        const int c0 = 2 * tid, c1 = 2 * tid + 1;
        const float sc0 = rs * gammaP[c0], sc1 = rs * gammaP[c1];
        LN[tid][0] = sc0; LN[tid][1] = betaP[c0] - mu * sc0;
        LN[tid][2] = sc1; LN[tid][3] = betaP[c1] - mu * sc1;
    }

    float4v acc[4][2];
#pragma unroll
    for (int i = 0; i < 4; ++i)
#pragma unroll
        for (int j = 0; j < 2; ++j) acc[i][j] = (float4v){0.f, 0.f, 0.f, 0.f};

    const size_t rstride = (size_t)Lin * 2;
    const _Float16* px = x + ((size_t)(b * 256) + quad) * rstride
                           + t0 * 4 + (wvt * 32 + m) * 4;

    const _Float16* wsrc[4];
#pragma unroll
    for (int r = 0; r < 4; ++r) {
        const int e = wv * 4 + r;
        const int oh2 = e & 1, q = (e >> 1) & 3, k32l = e >> 3;
        wsrc[r] = w + ((size_t)(ocb + oh2 * 64 + lane) * 256 + (k32l * 4 + q)) * 8;
    }
    auto stageW = [&](int buf) {
#pragma unroll
        for (int r = 0; r < 4; ++r) {
            const int e = wv * 4 + r;
            const int oh2 = e & 1, q = (e >> 1) & 3, k32l = e >> 3;
            GLOAD_LDS16(wsrc[r], &LW[buf][k32l][q][oh2 * 64][0]);
            wsrc[r] += 64;                     // 8 icp * 8
        }
    };
    auto loadX = [&](half8v (&xr)[4], const _Float16* p) {
#pragma unroll
        for (int k32l = 0; k32l < 2; ++k32l)
#pragma unroll
            for (int j = 0; j < 2; ++j)
                xr[k32l * 2 + j] = *(const half8v*)(p + (size_t)k32l * 4 * rstride + j * 64);
    };
    auto compute = [&](int buf, half8v (&xr)[4], int plB) {
#pragma unroll
        for (int k32l = 0; k32l < 2; ++k32l) {
            half8v a4[4];
#pragma unroll
            for (int i = 0; i < 4; ++i)
                a4[i] = *(const half8v*)&LW[buf][k32l][quad][wv2 * 64 + i * 16 + m][0];
            const int pl = plB + quad + 4 * k32l;
            const _Float16 s0 = (_Float16)LN[pl][0], h0v = (_Float16)LN[pl][1];
            const _Float16 s1 = (_Float16)LN[pl][2], h1v = (_Float16)LN[pl][3];
            half8v xn[2];
#pragma unroll
            for (int j = 0; j < 2; ++j) {
                half8v xv = xr[k32l * 2 + j];
#pragma unroll
                for (int k = 0; k < 8; ++k) {
                    const _Float16 v = xv[k] * ((k & 1) ? s1 : s0) + ((k & 1) ? h1v : h0v);
                    xv[k] = (v > (_Float16)0.f) ? v : (_Float16)0.f;
                }
                xn[j] = xv;
            }
#pragma unroll
            for (int i = 0; i < 4; ++i)
#pragma unroll
                for (int j = 0; j < 2; ++j)
                    acc[i][j] = __builtin_amdgcn_mfma_f32_16x16x32_f16(a4[i], xn[j], acc[i][j], 0, 0, 0);
        }
    };

    half8v xrA[4], xrB[4];
    loadX(xrA, px); px += 8 * rstride;         // iter 0
    stageW(0);
    __syncthreads();

    for (int it = 0; it < 32; it += 2) {
        stageW(1);
        loadX(xrB, px); px += 8 * rstride;     // iter it+1
        compute(0, xrA, 8 * it);
        __syncthreads();
        if (it + 2 < 32) {
            stageW(0);
            loadX(xrA, px);                    // iter it+2
        }
        px += 8 * rstride;
        compute(1, xrB, 8 * (it + 1));
        __syncthreads();
    }

    // --- epilogue (RAW conv outputs, pre-GN)
    float lsum = 0.f, lsq = 0.f;
    uint* ohU = (uint*)oh;
#pragma unroll
    for (int i = 0; i < 4; ++i) {
        const int ocb2 = ocb + wv2 * 64 + i * 16 + quad * 4;
#pragma unroll
        for (int j = 0; j < 2; ++j) {
            const int t = t0 + wvt * 32 + j * 16 + m;
            if (t < Lout) {
                if (PAIRED) {
#pragma unroll
                    for (int pr = 0; pr < 2; ++pr) {
                        const float v0 = acc[i][j][pr * 2], v1 = acc[i][j][pr * 2 + 1];
                        union { uint u; _Float16 h[2]; } pk;
                        pk.h[0] = (_Float16)v0; pk.h[1] = (_Float16)v1;
                        const uint p = (uint)((ocb2 >> 1) + pr);
                        ohU[((size_t)(b * 256 + p)) * Lout + t] = pk.u;
                        lsum += v0 + v1; lsq += v0 * v0 + v1 * v1;
                    }
                } else {
#pragma unroll
                    for (int r = 0; r < 4; ++r) {
                        const float v = acc[i][j][r];
                        ofeat[((size_t)(b * 512 + ocb2 + r)) * 224 + t] = (_Float16)v;
                        lsum += v; lsq += v * v;
                    }
                }
            }
        }
    }
    red[0][tid] = lsum; red[1][tid] = lsq;
    __syncthreads();
    for (int s2 = 128; s2 > 0; s2 >>= 1) {
        if (tid < s2) { red[0][tid] += red[0][tid + s2]; red[1][tid] += red[1][tid + s2]; }
        __syncthreads();
    }
    if (tid == 0) {
        atomicAdd(&statsO[2 * b], red[0][0]);
        atomicAdd(&statsO[2 * b + 1], red[1][0]);
    }
}

// ---------------------------------------------------------------------------
// norm_feat: GN+affine+ReLU in place on f16 features [row][224], t<198.
// ---------------------------------------------------------------------------
__global__ __launch_bounds__(256) void norm_feat(
    _Float16* __restrict__ h, const float* __restrict__ stats,
    const float* __restrict__ gamma, const float* __restrict__ beta)
{
    const int row = blockIdx.y;
    const int b = row >> 9, oc = row & 511;
    const int t = threadIdx.x;
    if (t >= 198) return;
    const float invN = 1.f / (512.f * 198.f);
    const float mu = stats[2 * b] * invN;
    const float var = stats[2 * b + 1] * invN - mu * mu;
    const float rs = rsqrtf(var + 1e-5f);
    const float sc = rs * gamma[oc];
    const float sh = beta[oc] - mu * sc;
    const size_t i = (size_t)row * 224 + t;
    const float v = (float)h[i] * sc + sh;
    h[i] = (_Float16)(v > 0.f ? v : 0.f);
}

// ---------------------------------------------------------------------------
// aa_kernel: row squared-norms of f16 features [row][224] (pad is zero).
// ---------------------------------------------------------------------------
__global__ __launch_bounds__(256) void aa_kernel(
    const _Float16* __restrict__ fX, const _Float16* __restrict__ fY,
    float* __restrict__ aaX, float* __restrict__ aaY)
{
    const int wave = threadIdx.x >> 6, lane = threadIdx.x & 63;
    const int R = blockIdx.x * 4 + wave;
    const _Float16* f = (R < 8192) ? fX : fY;
    const int r = R & 8191;
    const _Float16* row = f + (size_t)r * 224;
    float s = 0.f;
    if (lane < 56) {
        const half4v v = *(const half4v*)(row + lane * 4);
#pragma unroll
        for (int k = 0; k < 4; ++k) { const float x = (float)v[k]; s += x * x; }
    }
#pragma unroll
    for (int off = 32; off > 0; off >>= 1) s += __shfl_xor(s, off);
    if (lane == 0) ((R < 8192) ? aaX : aaY)[r] = s;
}

// ---------------------------------------------------------------------------
// cost_kernel v2: MFMA GEMM on f16 features (K padded to 224, zeros).
// Symmetric mats (xx,yy): upper tiles only, mirror-write.
// M = f16( min(50 * max(aa[n]+bb[m]-2<p,q>, 0), 65000) ) == 100*C
// ---------------------------------------------------------------------------
__global__ __launch_bounds__(256) void cost_kernel(
    const _Float16* __restrict__ fX, const _Float16* __restrict__ fY,
    const float* __restrict__ aaX, const float* __restrict__ aaY,
    _Float16* __restrict__ Cxy, _Float16* __restrict__ Cxx,
    _Float16* __restrict__ Cyy, _Float16* __restrict__ CTxy)
{
    const int z = blockIdx.y;
    const int mat = z >> 4, b = z & 15;
    const int nt = blockIdx.x & 3, mt = blockIdx.x >> 2;
    if (mat != 0 && nt > mt) return;
    const _Float16 *P, *Q; const float *aP, *aQ;
    _Float16 *Cm, *CT;
    if (mat == 0)      { P = fX; Q = fY; aP = aaX; aQ = aaY; Cm = Cxy; CT = CTxy; }
    else if (mat == 1) { P = fX; Q = fX; aP = aaX; aQ = aaX; Cm = Cxx; CT = (nt < mt) ? Cxx : nullptr; }
    else               { P = fY; Q = fY; aP = aaY; aQ = aaY; Cm = Cyy; CT = (nt < mt) ? Cyy : nullptr; }

    const int tid = threadIdx.x, lane = tid & 63, wv = tid >> 6;
    const int m16 = lane & 15, quad = lane >> 4;
    const int wv2 = wv >> 1, wvt = wv & 1;
    const int nb = nt * 128 + wv2 * 64;
    const int mb = mt * 128 + wvt * 64;
    const _Float16* Pb = P + (size_t)b * 512 * 224;
    const _Float16* Qb = Q + (size_t)b * 512 * 224;

    float4v acc[4][4];
#pragma unroll
    for (int i = 0; i < 4; ++i)
#pragma unroll
        for (int j = 0; j < 4; ++j) acc[i][j] = (float4v){0.f, 0.f, 0.f, 0.f};

    for (int k32 = 0; k32 < 7; ++k32) {
        const int ko = k32 * 32 + quad * 8;
        half8v a4[4], b4[4];
#pragma unroll
        for (int i = 0; i < 4; ++i)
            a4[i] = *(const half8v*)(Pb + (size_t)(nb + i * 16 + m16) * 224 + ko);
#pragma unroll
        for (int j = 0; j < 4; ++j)
            b4[j] = *(const half8v*)(Qb + (size_t)(mb + j * 16 + m16) * 224 + ko);
#pragma unroll
        for (int i = 0; i < 4; ++i)
#pragma unroll
            for (int j = 0; j < 4; ++j)
                acc[i][j] = __builtin_amdgcn_mfma_f32_16x16x32_f16(a4[i], b4[j], acc[i][j], 0, 0, 0);
    }

#pragma unroll
    for (int i = 0; i < 4; ++i) {
        const int nrow0 = nb + i * 16 + quad * 4;
        float aa4[4];
#pragma unroll
        for (int r = 0; r < 4; ++r) aa4[r] = aP[b * 512 + nrow0 + r];
#pragma unroll
        for (int j = 0; j < 4; ++j) {
            const int mcol = mb + j * 16 + m16;
            const float bbm = aQ[b * 512 + mcol];
#pragma unroll
            for (int r = 0; r < 4; ++r) {
                const int n = nrow0 + r;
                float c = 50.f * fmaxf(aa4[r] + bbm - 2.f * acc[i][j][r], 0.f);
                c = fminf(c, 65000.f);
                const _Float16 ch = (_Float16)c;
                Cm[((size_t)(b * 512 + n)) * 512 + mcol] = ch;
                if (CT) CT[((size_t)(b * 512 + mcol)) * 512 + n] = ch;
            }
        }
    }
}

// ---------------------------------------------------------------------------
// Per-row half-update (two-pass max-then-sum; round-8 proven version:
// __expf = native v_exp_f32 fast path; plain exp2f/log2f regressed ~100us
// in rounds 9/10 -- suspected precise-OCML lowering).
// dst[p*512+i] = eps*log512 - eps*LSE_j( 400*src[j] - 4*M100[i,j] )
// ---------------------------------------------------------------------------
static __device__ __forceinline__ void sink_rows(
    float* __restrict__ dst, const float* __restrict__ src,
    const _Float16* __restrict__ Mb, int p, int i0, int lane)
{
    const float* sp = src + (size_t)p * 512;
    float s8[8];
    {
        const float4 sa = *(const float4*)&sp[lane * 8];
        const float4 sb = *(const float4*)&sp[lane * 8 + 4];
        s8[0]=sa.x*400.f; s8[1]=sa.y*400.f; s8[2]=sa.z*400.f; s8[3]=sa.w*400.f;
        s8[4]=sb.x*400.f; s8[5]=sb.y*400.f; s8[6]=sb.z*400.f; s8[7]=sb.w*400.f;
    }
#pragma unroll
    for (int rr = 0; rr < 4; ++rr) {
        const int i = i0 + rr;
        const half8v rv = *(const half8v*)(Mb + (size_t)i * 512 + lane * 8);
        float a8[8];
#pragma unroll
        for (int k = 0; k < 8; ++k) a8[k] = fmaf(-4.f, (float)rv[k], s8[k]);
        float mx = a8[0];
#pragma unroll
        for (int k = 1; k < 8; ++k) mx = fmaxf(mx, a8[k]);
        // wave-global max (fmax butterfly, no exps)
#pragma unroll
        for (int off = 32; off > 0; off >>= 1) mx = fmaxf(mx, __shfl_xor(mx, off));
        // sum of exp(a - global max)
        float ss = 0.f;
#pragma unroll
        for (int k = 0; k < 8; ++k) ss += __expf(a8[k] - mx);
#pragma unroll
        for (int off = 32; off > 0; off >>= 1) ss += __shfl_xor(ss, off);
        if (lane == 0)
            dst[(size_t)p * 512 + i] = EPS_LOG512 - EPS_SINK * (mx + logf(ss));
    }
}

// ---------------------------------------------------------------------------
// sink_update: one half-update per launch; grid (32,48), 256 thr.
// ---------------------------------------------------------------------------
__global__ __launch_bounds__(256) void sink_update(
    float* __restrict__ dst, const float* __restrict__ src,
    const _Float16* __restrict__ M0, const _Float16* __restrict__ M1,
    const _Float16* __restrict__ M2)
{
    const int p = blockIdx.y;
    const int mat = p >> 4, b = p & 15;
    const _Float16* M = ((mat == 0) ? M0 : ((mat == 1) ? M1 : M2)) + (size_t)b * 512 * 512;
    const int wave = threadIdx.x >> 6, lane = threadIdx.x & 63;
    const int i0 = blockIdx.x * 16 + wave * 4;
    sink_rows(dst, src, M, p, i0, lane);
}

// ---------------------------------------------------------------------------
__global__ __launch_bounds__(256) void final_kernel(
    const float* __restrict__ f, const float* __restrict__ g,
    float* __restrict__ out)
{
    const int b = blockIdx.x, tid = threadIdx.x;
    __shared__ float red[256];
    float a = 0.f;
    for (int n = tid; n < 512; n += 256) {
        const float xy = f[(0 * 16 + b) * 512 + n] + g[(0 * 16 + b) * 512 + n];
        const float xx = f[(1 * 16 + b) * 512 + n] + g[(1 * 16 + b) * 512 + n];
        const float yy = f[(2 * 16 + b) * 512 + n] + g[(2 * 16 + b) * 512 + n];
        a += xy - 0.5f * (xx + yy);
    }
    red[tid] = a;
    __syncthreads();
    for (int s2 = 128; s2 > 0; s2 >>= 1) {
        if (tid < s2) red[tid] += red[tid + s2];
        __syncthreads();
    }
    if (tid == 0) out[b] = red[0] * (1.0f / 512.0f);
}

// ---------------------------------------------------------------------------
extern "C" void kernel_launch(void* const* d_in, const int* in_sizes, int n_in,
                              void* d_out, int out_size, void* d_ws, size_t ws_size,
                              hipStream_t stream)
{
    (void)in_sizes; (void)n_in; (void)out_size; (void)ws_size;
    char* ws = (char*)d_ws;
    const float* yhat = (const float*)d_in[0];
    const float* ysig = (const float*)d_in[1];
    const float* Wl[5]; const float* gl[5]; const float* bl[5];
    for (int i = 0; i < 5; ++i) {
        Wl[i] = (const float*)d_in[2 + 3 * i];
        gl[i] = (const float*)d_in[3 + 3 * i];
        bl[i] = (const float*)d_in[4 + 3 * i];
    }
    float* out = (float*)d_out;
    float* statsA = (float*)(ws + O_STATS);

    _Float16* w1 = (_Float16*)(ws + O_W1);
    _Float16* w2 = (_Float16*)(ws + O_W2);
    _Float16* w3 = (_Float16*)(ws + O_W3);
    _Float16* w4 = (_Float16*)(ws + O_W4);
    _Float16* h0 = (_Float16*)(ws + O_H0);
    _Float16* h1 = (_Float16*)(ws + O_H1);
    _Float16* h2 = (_Float16*)(ws + O_H2);
    _Float16* h3 = (_Float16*)(ws + O_H3);

    hipMemsetAsync(statsA, 0, 512 * sizeof(float), stream);
    // zero f16 feature buffers (incl. K-pad columns 198..223)
    hipMemsetAsync(ws + O_FEATX, 0, 16 * 512 * 224 * 2, stream);
    hipMemsetAsync(ws + O_FEATY, 0, 16 * 512 * 224 * 2, stream);
    prep_w<<<dim3(1024, 4), 256, 0, stream>>>(Wl[1], Wl[2], Wl[3], Wl[4],
        w1, w2, w3, w4);

    for (int s = 0; s < 2; ++s) {
        const float* wav = (s == 0) ? yhat : ysig;
        float* st = statsA + (size_t)s * 160;
        _Float16* ft = (_Float16*)(ws + ((s == 0) ? O_FEATX : O_FEATY));

        conv0_store<<<dim3(25, 16), 256, 0, stream>>>(wav, Wl[0], h0, st);

        conv1_mfma<<<dim3(832), 256, 0, stream>>>(
            h0, w1, st, gl[0], bl[0], h1, st + 32);

        conv_mfma<true><<<dim3(832), 256, 0, stream>>>(
            h1, w2, st + 32, gl[1], bl[1], h2, nullptr, st + 64, 1598, 798, 13);

        conv_mfma<true><<<dim3(448), 256, 0, stream>>>(
            h2, w3, st + 64, gl[2], bl[2], h3, nullptr, st + 96, 798, 398, 7);

        conv_mfma<false><<<dim3(256), 256, 0, stream>>>(
            h3, w4, st + 96, gl[3], bl[3], nullptr, ft, st + 128, 398, 198, 4);

        norm_feat<<<dim3(1, 8192), 256, 0, stream>>>(
            ft, st + 128, gl[4], bl[4]);
    }

    _Float16* featX = (_Float16*)(ws + O_FEATX);
    _Float16* featY = (_Float16*)(ws + O_FEATY);
    aa_kernel<<<4096, 256, 0, stream>>>(featX, featY, (float*)(ws + O_AAX), (float*)(ws + O_AAY));
    cost_kernel<<<dim3(16, 48), 256, 0, stream>>>(
        featX, featY, (float*)(ws + O_AAX), (float*)(ws + O_AAY),
        (_Float16*)(ws + O_CXY), (_Float16*)(ws + O_CXX), (_Float16*)(ws + O_CYY),
        (_Float16*)(ws + O_CTXY));

    hipMemsetAsync(ws + O_F, 0, 2 * 24576 * sizeof(float), stream);

    float* fptr = (float*)(ws + O_F);
    float* gptr = (float*)(ws + O_G);
    _Float16* cxy  = (_Float16*)(ws + O_CXY);
    _Float16* ctxy = (_Float16*)(ws + O_CTXY);
    _Float16* cxx  = (_Float16*)(ws + O_CXX);
    _Float16* cyy  = (_Float16*)(ws + O_CYY);

    for (int it = 0; it < 50; ++it) {
        sink_update<<<dim3(32, 48), 256, 0, stream>>>(gptr, fptr, ctxy, cxx, cyy);
        sink_update<<<dim3(32, 48), 256, 0, stream>>>(fptr, gptr, cxy, cxx, cyy);
    }

    final_kernel<<<16, 256, 0, stream>>>(fptr, gptr, out);
}

// Round 12
// 1670.633 us; speedup vs baseline: 1.0767x; 1.0034x over previous
//
#include <hip/hip_runtime.h>

typedef unsigned int uint;
typedef unsigned short ushort;
using half8v  = __attribute__((ext_vector_type(8))) _Float16;
using half4v  = __attribute__((ext_vector_type(4))) _Float16;
using float4v = __attribute__((ext_vector_type(4))) float;

#define EPS_SINK 0.0025f
#define EPS_LOG512 0.015595811562598769f

// ---- workspace layout (BYTE offsets), peak ~165 MB ----
static const size_t O_W1   = 0ull;             // 512*512*8 f16 = 4,194,304 B
static const size_t O_W2   = 4194304ull;       // 2,097,152 B each
static const size_t O_W3   = 6291456ull;
static const size_t O_W4   = 8388608ull;
static const size_t O_H0   = 20971520ull;      // 16*512*6400 f16 = 104,857,600 B
static const size_t O_H1   = 125829120ull;     // 16*256*1598 uint = 26,181,632 B
static const size_t O_H2   = 20971520ull;      // alias h0 (dead after conv1)
static const size_t O_H3   = 34045952ull;
static const size_t O_FEATX= 152010752ull;     // 16*512*224 f16 = 3,670,016 B
static const size_t O_FEATY= 158498816ull;
static const size_t O_STATS= 164986880ull;     // 512 floats
// cost phase (weights/h0/h1 all dead).  C stored f16, value = 100*C:
static const size_t O_CXY  = 0ull;             // 8,388,608 B each
static const size_t O_CTXY = 8388608ull;
static const size_t O_CXX  = 16777216ull;
static const size_t O_CYY  = 25165824ull;
static const size_t O_AAX  = 33554432ull;
static const size_t O_AAY  = 33587200ull;
static const size_t O_F    = 33619968ull;      // 3*16*512 fp32
static const size_t O_G    = 33718272ull;

#define GLOAD_LDS16(gp, lp) __builtin_amdgcn_global_load_lds( \
    (const __attribute__((address_space(1))) void*)(gp),       \
    (__attribute__((address_space(3))) void*)(lp), 16, 0, 0)

// ---------------------------------------------------------------------------
// prep_w: convert conv weights fp32 -> single f16. W1 [oc][ic][8 taps];
// W2-4 pair-interleaved [oc][icpair][dt0 icA, dt0 icB, dt1 icA, ...].
// ---------------------------------------------------------------------------
__global__ __launch_bounds__(256) void prep_w(
    const float* __restrict__ W1, const float* __restrict__ W2,
    const float* __restrict__ W3, const float* __restrict__ W4,
    _Float16* __restrict__ w1, _Float16* __restrict__ w2,
    _Float16* __restrict__ w3, _Float16* __restrict__ w4)
{
    const int layer = blockIdx.y;
    const int e = blockIdx.x * 256 + threadIdx.x;
    float v[8];
    _Float16* dh;
    if (layer == 0) {
        const float4 a = *(const float4*)(W1 + (size_t)e * 8);
        const float4 c = *(const float4*)(W1 + (size_t)e * 8 + 4);
        v[0]=a.x; v[1]=a.y; v[2]=a.z; v[3]=a.w; v[4]=c.x; v[5]=c.y; v[6]=c.z; v[7]=c.w;
        dh = w1;
    } else {
        if (e >= 131072) return;
        const float* W = (layer == 1) ? W2 : (layer == 2) ? W3 : W4;
        dh = (layer == 1) ? w2 : (layer == 2) ? w3 : w4;
        const int oc = e >> 8, icp = e & 255;
        const float4 a = *(const float4*)(W + ((size_t)oc * 512 + icp * 2) * 4);
        const float4 c = *(const float4*)(W + ((size_t)oc * 512 + icp * 2 + 1) * 4);
        v[0]=a.x; v[1]=c.x; v[2]=a.y; v[3]=c.y; v[4]=a.z; v[5]=c.z; v[6]=a.w; v[7]=c.w;
    }
    half8v hi;
#pragma unroll
    for (int k = 0; k < 8; ++k) hi[k] = (_Float16)v[k];
    *(half8v*)(dh + (size_t)e * 8) = hi;
}

// ---------------------------------------------------------------------------
// conv0_store v2: raw conv0 (k=10,s=5) -> h0 f16 [b][512][6400] + GN stats.
// oc split 4-way: grid (25, 4, 16) = 1600 blocks (was 400 = 1.56 blk/CU,
// grid-starved). Each block: 128 oc x 256 t, 1280-float W slice in LDS.
// ---------------------------------------------------------------------------
__global__ __launch_bounds__(256) void conv0_store(
    const float* __restrict__ wav, const float* __restrict__ W0,
    _Float16* __restrict__ h0, float* __restrict__ stats)
{
    __shared__ float LW[1280];
    __shared__ float red[2][256];
    const int tid = threadIdx.x;
    const int ocq = blockIdx.y;                // 0..3, 128-oc chunk
    const int oc0 = ocq * 128;
    for (int e = tid; e < 1280; e += 256) LW[e] = W0[oc0 * 10 + e];

    const int b = blockIdx.z;
    const int t = blockIdx.x * 256 + tid;
    const bool valid = (t < 6399);
    float xv[10];
#pragma unroll
    for (int d = 0; d < 10; ++d) xv[d] = 0.f;
    if (valid) {
        const float* wp = wav + (size_t)b * 32000 + (size_t)t * 5;
#pragma unroll
        for (int d = 0; d < 10; ++d) xv[d] = wp[d];
    }
    __syncthreads();

    float lsum = 0.f, lsq = 0.f;
    _Float16* hb = h0 + (size_t)b * 512 * 6400 + (size_t)oc0 * 6400;
    for (int oc = 0; oc < 128; ++oc) {
        float a = 0.f;
#pragma unroll
        for (int d = 0; d < 10; ++d) a += LW[oc * 10 + d] * xv[d];
        if (valid) {
            hb[(size_t)oc * 6400 + t] = (_Float16)a;
            lsum += a; lsq += a * a;
        }
    }
    red[0][tid] = lsum; red[1][tid] = lsq;
    __syncthreads();
    for (int s2 = 128; s2 > 0; s2 >>= 1) {
        if (tid < s2) { red[0][tid] += red[0][tid + s2]; red[1][tid] += red[1][tid + s2]; }
        __syncthreads();
    }
    if (tid == 0) {
        atomicAdd(&stats[2 * b], red[0][0]);
        atomicAdd(&stats[2 * b + 1], red[1][0]);
    }
}

// ---------------------------------------------------------------------------
// conv1_mfma v6: layer1 (K=8,S=4), 128oc x 128t tile (proven structure,
// round-8 = 1690us config) + FUSED GN0 affine+ReLU on the X-load path.
// relu's v>0?v:0 maps NaN/garbage (unwritten h0 tail slot 6399) to 0.
// LDS 38 KB -> 4 blocks/CU.
// ---------------------------------------------------------------------------
__global__ __launch_bounds__(256, 4) void conv1_mfma(
    const _Float16* __restrict__ h0,
    const _Float16* __restrict__ w1,
    const float* __restrict__ stats0,
    const float* __restrict__ gamma0, const float* __restrict__ beta0,
    _Float16* __restrict__ oh, float* __restrict__ stats1)
{
    __shared__ _Float16 LW[2][2][4][128][8];   // 32 KB [buf][k32l][q][oc][8]
    __shared__ float LSC[512], LSH[512];       // 4 KB GN0 fold tables
    __shared__ float red[2][256];

    const int tid  = threadIdx.x;
    const int lane = tid & 63, wv = tid >> 6;
    const int m    = lane & 15, quad = lane >> 4;
    const int wv2  = wv >> 1, wvt = wv & 1;

    // chunked XCD swizzle: 832 blocks = 8 chunks of 104; y (oc-tile) fastest
    const int raw = blockIdx.x;
    const int cid = (raw & 7) * 104 + (raw >> 3);
    const int b   = cid / 52;
    const int r2  = cid - b * 52;
    const int xt  = r2 >> 2, yt = r2 & 3;
    const int ocb = yt * 128;
    const int t0  = xt * 128;
    const int Lout = 1598;

    // --- GN0 fold tables (stats0 complete at launch boundary)
    {
        const float invN = 1.f / (512.f * 6399.f);
        const float mu = stats0[2 * b] * invN;
        const float var = stats0[2 * b + 1] * invN - mu * mu;
        const float rs = rsqrtf(var + 1e-5f);
        for (int ic = tid; ic < 512; ic += 256) {
            const float sc = rs * gamma0[ic];
            LSC[ic] = sc;
            LSH[ic] = beta0[ic] - mu * sc;
        }
    }

    float4v acc[4][4];
#pragma unroll
    for (int i = 0; i < 4; ++i)
#pragma unroll
        for (int j = 0; j < 4; ++j) acc[i][j] = (float4v){0.f, 0.f, 0.f, 0.f};

    const _Float16* hb = h0 + (size_t)b * 512 * 6400;
    const int gbase = t0 * 4;
    const _Float16* px = hb + (size_t)quad * 6400 + gbase + (wvt * 64 + m) * 4;

    const _Float16* wsrc[4];
#pragma unroll
    for (int r = 0; r < 4; ++r) {
        const int e = wv * 4 + r;
        const int oh2 = e & 1, q = (e >> 1) & 3, k32l = e >> 3;
        wsrc[r] = w1 + ((size_t)(ocb + oh2 * 64 + lane) * 512 + (k32l * 4 + q)) * 8;
    }
    auto stageW = [&](int buf) {
#pragma unroll
        for (int r = 0; r < 4; ++r) {
            const int e = wv * 4 + r;
            const int oh2 = e & 1, q = (e >> 1) & 3, k32l = e >> 3;
            GLOAD_LDS16(wsrc[r], &LW[buf][k32l][q][oh2 * 64][0]);
            wsrc[r] += 64;                     // 8 ic * 8 taps
        }
    };

    stageW(0);
    __syncthreads();

    for (int it = 0; it < 64; ++it) {
        const int buf = it & 1;
        if (it < 63) stageW(buf ^ 1);
#pragma unroll
        for (int k32l = 0; k32l < 2; ++k32l) {
            half8v a4[4], bfv[4];
#pragma unroll
            for (int i = 0; i < 4; ++i)
                a4[i] = *(const half8v*)&LW[buf][k32l][quad][wv2 * 64 + i * 16 + m][0];
            const int ic = quad + 4 * k32l + 8 * it;
            const _Float16 sch = (_Float16)LSC[ic];
            const _Float16 shh = (_Float16)LSH[ic];
            const _Float16* pr = px + (size_t)k32l * 25600;   // +4 rows
#pragma unroll
            for (int j = 0; j < 4; ++j) {
                half8v xv = *(const half8v*)(pr + j * 64);
#pragma unroll
                for (int k = 0; k < 8; ++k) {
                    const _Float16 v = xv[k] * sch + shh;
                    xv[k] = (v > (_Float16)0.f) ? v : (_Float16)0.f;
                }
                bfv[j] = xv;
            }
#pragma unroll
            for (int i = 0; i < 4; ++i)
#pragma unroll
                for (int j = 0; j < 4; ++j)
                    acc[i][j] = __builtin_amdgcn_mfma_f32_16x16x32_f16(a4[i], bfv[j], acc[i][j], 0, 0, 0);
        }
        px += 51200;                           // +8 rows
        __syncthreads();
    }

    // --- epilogue: pack f16 pairs + stats (RAW conv1 outputs, pre-GN1)
    float lsum = 0.f, lsq = 0.f;
    uint* ohU = (uint*)oh;
#pragma unroll
    for (int i = 0; i < 4; ++i) {
        const int ocb2 = ocb + wv2 * 64 + i * 16 + quad * 4;
#pragma unroll
        for (int j = 0; j < 4; ++j) {
            const int t = t0 + wvt * 64 + j * 16 + m;
            if (t < Lout) {
#pragma unroll
                for (int pr = 0; pr < 2; ++pr) {
                    const float v0 = acc[i][j][pr * 2], v1 = acc[i][j][pr * 2 + 1];
                    union { uint u; _Float16 h[2]; } pk;
                    pk.h[0] = (_Float16)v0; pk.h[1] = (_Float16)v1;
                    const uint p = (uint)((ocb2 >> 1) + pr);
                    ohU[((size_t)(b * 256 + p)) * Lout + t] = pk.u;
                    lsum += v0 + v1; lsq += v0 * v0 + v1 * v1;
                }
            }
        }
    }
    red[0][tid] = lsum; red[1][tid] = lsq;
    __syncthreads();
    for (int s2 = 128; s2 > 0; s2 >>= 1) {
        if (tid < s2) { red[0][tid] += red[0][tid + s2]; red[1][tid] += red[1][tid + s2]; }
        __syncthreads();
    }
    if (tid == 0) {
        atomicAdd(&stats1[2 * b], red[0][0]);
        atomicAdd(&stats1[2 * b + 1], red[1][0]);
    }
}

// ---------------------------------------------------------------------------
// conv_mfma v5: layers 2-4 (K=4,S=2). 128oc x 64t tile, register dbuf X
// prefetch + FUSED prev-layer GN affine+ReLU at consume time (round-8 =
// 1690us config; 64t keeps grids at 832/448/256 blocks).
// PAIRED: f16 pair-interleaved out; else f16 features [ch][224] (padded).
// ---------------------------------------------------------------------------
template <bool PAIRED>
__global__ __launch_bounds__(256, 4) void conv_mfma(
    const _Float16* __restrict__ x,
    const _Float16* __restrict__ w,
    const float* __restrict__ statsP,
    const float* __restrict__ gammaP, const float* __restrict__ betaP,
    _Float16* __restrict__ oh, _Float16* __restrict__ ofeat,
    float* __restrict__ statsO, int Lin, int Lout, int nx)
{
    __shared__ _Float16 LW[2][2][4][128][8];   // 32 KB
    __shared__ float LN[256][4];               // sc0,sh0,sc1,sh1 per pair, 4 KB
    __shared__ float red[2][256];

    const int tid  = threadIdx.x;
    const int lane = tid & 63, wv = tid >> 6;
    const int m    = lane & 15, quad = lane >> 4;
    const int wv2  = wv >> 1, wvt = wv & 1;

    // chunked XCD swizzle (nwg = nx*64, always % 8 == 0), y fastest in chunk
    const int raw = blockIdx.x;
    const int chunk = (nx * 64) >> 3;
    const int cid = (raw & 7) * chunk + (raw >> 3);
    const int perb = nx * 4;
    const int b   = cid / perb;
    const int r2  = cid - b * perb;
    const int xt  = r2 >> 2, yt = r2 & 3;
    const int ocb = yt * 128;
    const int t0  = xt * 64;

    // --- prev-layer GN fold tables
    {
        const float invN = 1.f / (512.f * (float)Lin);
        const float mu = statsP[2 * b] * invN;
        const float var = statsP[2 * b + 1] * invN - mu * mu;
        const float rs = rsqrtf(var + 1e-5f);
        const int c0 = 2 * tid, c1 = 2 * tid + 1;
        const float sc0 = rs * gammaP[c0], sc1 = rs * gammaP[c1];
        LN[tid][0] = sc0; LN[tid][1] = betaP[c0] - mu * sc0;
        LN[tid][2] = sc1; LN[tid][3] = betaP[c1] - mu * sc1;
    }

    float4v acc[4][2];
#pragma unroll
    for (int i = 0; i < 4; ++i)
#pragma unroll
        for (int j = 0; j < 2; ++j) acc[i][j] = (float4v){0.f, 0.f, 0.f, 0.f};

    const size_t rstride = (size_t)Lin * 2;
    const _Float16* px = x + ((size_t)(b * 256) + quad) * rstride
                           + t0 * 4 + (wvt * 32 + m) * 4;

    const _Float16* wsrc[4];
#pragma unroll
    for (int r = 0; r < 4; ++r) {
        const int e = wv * 4 + r;
        const int oh2 = e & 1, q = (e >> 1) & 3, k32l = e >> 3;
        wsrc[r] = w + ((size_t)(ocb + oh2 * 64 + lane) * 256 + (k32l * 4 + q)) * 8;
    }
    auto stageW = [&](int buf) {
#pragma unroll
        for (int r = 0; r < 4; ++r) {
            const int e = wv * 4 + r;
            const int oh2 = e & 1, q = (e >> 1) & 3, k32l = e >> 3;
            GLOAD_LDS16(wsrc[r], &LW[buf][k32l][q][oh2 * 64][0]);
            wsrc[r] += 64;                     // 8 icp * 8
        }
    };
    auto loadX = [&](half8v (&xr)[4], const _Float16* p) {
#pragma unroll
        for (int k32l = 0; k32l < 2; ++k32l)
#pragma unroll
            for (int j = 0; j < 2; ++j)
                xr[k32l * 2 + j] = *(const half8v*)(p + (size_t)k32l * 4 * rstride + j * 64);
    };
    auto compute = [&](int buf, half8v (&xr)[4], int plB) {
#pragma unroll
        for (int k32l = 0; k32l < 2; ++k32l) {
            half8v a4[4];
#pragma unroll
            for (int i = 0; i < 4; ++i)
                a4[i] = *(const half8v*)&LW[buf][k32l][quad][wv2 * 64 + i * 16 + m][0];
            const int pl = plB + quad + 4 * k32l;
            const _Float16 s0 = (_Float16)LN[pl][0], h0v = (_Float16)LN[pl][1];
            const _Float16 s1 = (_Float16)LN[pl][2], h1v = (_Float16)LN[pl][3];
            half8v xn[2];
#pragma unroll
            for (int j = 0; j < 2; ++j) {
                half8v xv = xr[k32l * 2 + j];
#pragma unroll
                for (int k = 0; k < 8; ++k) {
                    const _Float16 v = xv[k] * ((k & 1) ? s1 : s0) + ((k & 1) ? h1v : h0v);
                    xv[k] = (v > (_Float16)0.f) ? v : (_Float16)0.f;
                }
                xn[j] = xv;
            }
#pragma unroll
            for (int i = 0; i < 4; ++i)
#pragma unroll
                for (int j = 0; j < 2; ++j)
                    acc[i][j] = __builtin_amdgcn_mfma_f32_16x16x32_f16(a4[i], xn[j], acc[i][j], 0, 0, 0);
        }
    };

    half8v xrA[4], xrB[4];
    loadX(xrA, px); px += 8 * rstride;         // iter 0
    stageW(0);
    __syncthreads();

    for (int it = 0; it < 32; it += 2) {
        stageW(1);
        loadX(xrB, px); px += 8 * rstride;     // iter it+1
        compute(0, xrA, 8 * it);
        __syncthreads();
        if (it + 2 < 32) {
            stageW(0);
            loadX(xrA, px);                    // iter it+2
        }
        px += 8 * rstride;
        compute(1, xrB, 8 * (it + 1));
        __syncthreads();
    }

    // --- epilogue (RAW conv outputs, pre-GN)
    float lsum = 0.f, lsq = 0.f;
    uint* ohU = (uint*)oh;
#pragma unroll
    for (int i = 0; i < 4; ++i) {
        const int ocb2 = ocb + wv2 * 64 + i * 16 + quad * 4;
#pragma unroll
        for (int j = 0; j < 2; ++j) {
            const int t = t0 + wvt * 32 + j * 16 + m;
            if (t < Lout) {
                if (PAIRED) {
#pragma unroll
                    for (int pr = 0; pr < 2; ++pr) {
                        const float v0 = acc[i][j][pr * 2], v1 = acc[i][j][pr * 2 + 1];
                        union { uint u; _Float16 h[2]; } pk;
                        pk.h[0] = (_Float16)v0; pk.h[1] = (_Float16)v1;
                        const uint p = (uint)((ocb2 >> 1) + pr);
                        ohU[((size_t)(b * 256 + p)) * Lout + t] = pk.u;
                        lsum += v0 + v1; lsq += v0 * v0 + v1 * v1;
                    }
                } else {
#pragma unroll
                    for (int r = 0; r < 4; ++r) {
                        const float v = acc[i][j][r];
                        ofeat[((size_t)(b * 512 + ocb2 + r)) * 224 + t] = (_Float16)v;
                        lsum += v; lsq += v * v;
                    }
                }
            }
        }
    }
    red[0][tid] = lsum; red[1][tid] = lsq;
    __syncthreads();
    for (int s2 = 128; s2 > 0; s2 >>= 1) {
        if (tid < s2) { red[0][tid] += red[0][tid + s2]; red[1][tid] += red[1][tid + s2]; }
        __syncthreads();
    }
    if (tid == 0) {
        atomicAdd(&statsO[2 * b], red[0][0]);
        atomicAdd(&statsO[2 * b + 1], red[1][0]);
    }
}

// ---------------------------------------------------------------------------
// norm_feat: GN+affine+ReLU in place on f16 features [row][224], t<198.
// ---------------------------------------------------------------------------
__global__ __launch_bounds__(256) void norm_feat(
    _Float16* __restrict__ h, const float* __restrict__ stats,
    const float* __restrict__ gamma, const float* __restrict__ beta)
{
    const int row = blockIdx.y;
    const int b = row >> 9, oc = row & 511;
    const int t = threadIdx.x;
    if (t >= 198) return;
    const float invN = 1.f / (512.f * 198.f);
    const float mu = stats[2 * b] * invN;
    const float var = stats[2 * b + 1] * invN - mu * mu;
    const float rs = rsqrtf(var + 1e-5f);
    const float sc = rs * gamma[oc];
    const float sh = beta[oc] - mu * sc;
    const size_t i = (size_t)row * 224 + t;
    const float v = (float)h[i] * sc + sh;
    h[i] = (_Float16)(v > 0.f ? v : 0.f);
}

// ---------------------------------------------------------------------------
// aa_kernel: row squared-norms of f16 features [row][224] (pad is zero).
// ---------------------------------------------------------------------------
__global__ __launch_bounds__(256) void aa_kernel(
    const _Float16* __restrict__ fX, const _Float16* __restrict__ fY,
    float* __restrict__ aaX, float* __restrict__ aaY)
{
    const int wave = threadIdx.x >> 6, lane = threadIdx.x & 63;
    const int R = blockIdx.x * 4 + wave;
    const _Float16* f = (R < 8192) ? fX : fY;
    const int r = R & 8191;
    const _Float16* row = f + (size_t)r * 224;
    float s = 0.f;
    if (lane < 56) {
        const half4v v = *(const half4v*)(row + lane * 4);
#pragma unroll
        for (int k = 0; k < 4; ++k) { const float x = (float)v[k]; s += x * x; }
    }
#pragma unroll
    for (int off = 32; off > 0; off >>= 1) s += __shfl_xor(s, off);
    if (lane == 0) ((R < 8192) ? aaX : aaY)[r] = s;
}

// ---------------------------------------------------------------------------
// cost_kernel v2: MFMA GEMM on f16 features (K padded to 224, zeros).
// Symmetric mats (xx,yy): upper tiles only, mirror-write.
// M = f16( min(50 * max(aa[n]+bb[m]-2<p,q>, 0), 65000) ) == 100*C
// ---------------------------------------------------------------------------
__global__ __launch_bounds__(256) void cost_kernel(
    const _Float16* __restrict__ fX, const _Float16* __restrict__ fY,
    const float* __restrict__ aaX, const float* __restrict__ aaY,
    _Float16* __restrict__ Cxy, _Float16* __restrict__ Cxx,
    _Float16* __restrict__ Cyy, _Float16* __restrict__ CTxy)
{
    const int z = blockIdx.y;
    const int mat = z >> 4, b = z & 15;
    const int nt = blockIdx.x & 3, mt = blockIdx.x >> 2;
    if (mat != 0 && nt > mt) return;
    const _Float16 *P, *Q; const float *aP, *aQ;
    _Float16 *Cm, *CT;
    if (mat == 0)      { P = fX; Q = fY; aP = aaX; aQ = aaY; Cm = Cxy; CT = CTxy; }
    else if (mat == 1) { P = fX; Q = fX; aP = aaX; aQ = aaX; Cm = Cxx; CT = (nt < mt) ? Cxx : nullptr; }
    else               { P = fY; Q = fY; aP = aaY; aQ = aaY; Cm = Cyy; CT = (nt < mt) ? Cyy : nullptr; }

    const int tid = threadIdx.x, lane = tid & 63, wv = tid >> 6;
    const int m16 = lane & 15, quad = lane >> 4;
    const int wv2 = wv >> 1, wvt = wv & 1;
    const int nb = nt * 128 + wv2 * 64;
    const int mb = mt * 128 + wvt * 64;
    const _Float16* Pb = P + (size_t)b * 512 * 224;
    const _Float16* Qb = Q + (size_t)b * 512 * 224;

    float4v acc[4][4];
#pragma unroll
    for (int i = 0; i < 4; ++i)
#pragma unroll
        for (int j = 0; j < 4; ++j) acc[i][j] = (float4v){0.f, 0.f, 0.f, 0.f};

    for (int k32 = 0; k32 < 7; ++k32) {
        const int ko = k32 * 32 + quad * 8;
        half8v a4[4], b4[4];
#pragma unroll
        for (int i = 0; i < 4; ++i)
            a4[i] = *(const half8v*)(Pb + (size_t)(nb + i * 16 + m16) * 224 + ko);
#pragma unroll
        for (int j = 0; j < 4; ++j)
            b4[j] = *(const half8v*)(Qb + (size_t)(mb + j * 16 + m16) * 224 + ko);
#pragma unroll
        for (int i = 0; i < 4; ++i)
#pragma unroll
            for (int j = 0; j < 4; ++j)
                acc[i][j] = __builtin_amdgcn_mfma_f32_16x16x32_f16(a4[i], b4[j], acc[i][j], 0, 0, 0);
    }

#pragma unroll
    for (int i = 0; i < 4; ++i) {
        const int nrow0 = nb + i * 16 + quad * 4;
        float aa4[4];
#pragma unroll
        for (int r = 0; r < 4; ++r) aa4[r] = aP[b * 512 + nrow0 + r];
#pragma unroll
        for (int j = 0; j < 4; ++j) {
            const int mcol = mb + j * 16 + m16;
            const float bbm = aQ[b * 512 + mcol];
#pragma unroll
            for (int r = 0; r < 4; ++r) {
                const int n = nrow0 + r;
                float c = 50.f * fmaxf(aa4[r] + bbm - 2.f * acc[i][j][r], 0.f);
                c = fminf(c, 65000.f);
                const _Float16 ch = (_Float16)c;
                Cm[((size_t)(b * 512 + n)) * 512 + mcol] = ch;
                if (CT) CT[((size_t)(b * 512 + mcol)) * 512 + n] = ch;
            }
        }
    }
}

// ---------------------------------------------------------------------------
// Per-row half-update (two-pass max-then-sum; __expf = native v_exp_f32.
// NOTE: bare exp2f/log2f regressed ~120us total (rounds 9/10) -- precise-OCML
// lowering; keep __expf/logf).
// dst[p*512+i] = eps*log512 - eps*LSE_j( 400*src[j] - 4*M100[i,j] )
// ---------------------------------------------------------------------------
static __device__ __forceinline__ void sink_rows(
    float* __restrict__ dst, const float* __restrict__ src,
    const _Float16* __restrict__ Mb, int p, int i0, int lane)
{
    const float* sp = src + (size_t)p * 512;
    float s8[8];
    {
        const float4 sa = *(const float4*)&sp[lane * 8];
        const float4 sb = *(const float4*)&sp[lane * 8 + 4];
        s8[0]=sa.x*400.f; s8[1]=sa.y*400.f; s8[2]=sa.z*400.f; s8[3]=sa.w*400.f;
        s8[4]=sb.x*400.f; s8[5]=sb.y*400.f; s8[6]=sb.z*400.f; s8[7]=sb.w*400.f;
    }
#pragma unroll
    for (int rr = 0; rr < 4; ++rr) {
        const int i = i0 + rr;
        const half8v rv = *(const half8v*)(Mb + (size_t)i * 512 + lane * 8);
        float a8[8];
#pragma unroll
        for (int k = 0; k < 8; ++k) a8[k] = fmaf(-4.f, (float)rv[k], s8[k]);
        float mx = a8[0];
#pragma unroll
        for (int k = 1; k < 8; ++k) mx = fmaxf(mx, a8[k]);
        // wave-global max (fmax butterfly, no exps)
#pragma unroll
        for (int off = 32; off > 0; off >>= 1) mx = fmaxf(mx, __shfl_xor(mx, off));
        // sum of exp(a - global max)
        float ss = 0.f;
#pragma unroll
        for (int k = 0; k < 8; ++k) ss += __expf(a8[k] - mx);
#pragma unroll
        for (int off = 32; off > 0; off >>= 1) ss += __shfl_xor(ss, off);
        if (lane == 0)
            dst[(size_t)p * 512 + i] = EPS_LOG512 - EPS_SINK * (mx + logf(ss));
    }
}

// ---------------------------------------------------------------------------
// sink_update: one half-update per launch; grid (32,48), 256 thr.
// ---------------------------------------------------------------------------
__global__ __launch_bounds__(256) void sink_update(
    float* __restrict__ dst, const float* __restrict__ src,
    const _Float16* __restrict__ M0, const _Float16* __restrict__ M1,
    const _Float16* __restrict__ M2)
{
    const int p = blockIdx.y;
    const int mat = p >> 4, b = p & 15;
    const _Float16* M = ((mat == 0) ? M0 : ((mat == 1) ? M1 : M2)) + (size_t)b * 512 * 512;
    const int wave = threadIdx.x >> 6, lane = threadIdx.x & 63;
    const int i0 = blockIdx.x * 16 + wave * 4;
    sink_rows(dst, src, M, p, i0, lane);
}

// ---------------------------------------------------------------------------
__global__ __launch_bounds__(256) void final_kernel(
    const float* __restrict__ f, const float* __restrict__ g,
    float* __restrict__ out)
{
    const int b = blockIdx.x, tid = threadIdx.x;
    __shared__ float red[256];
    float a = 0.f;
    for (int n = tid; n < 512; n += 256) {
        const float xy = f[(0 * 16 + b) * 512 + n] + g[(0 * 16 + b) * 512 + n];
        const float xx = f[(1 * 16 + b) * 512 + n] + g[(1 * 16 + b) * 512 + n];
        const float yy = f[(2 * 16 + b) * 512 + n] + g[(2 * 16 + b) * 512 + n];
        a += xy - 0.5f * (xx + yy);
    }
    red[tid] = a;
    __syncthreads();
    for (int s2 = 128; s2 > 0; s2 >>= 1) {
        if (tid < s2) red[tid] += red[tid + s2];
        __syncthreads();
    }
    if (tid == 0) out[b] = red[0] * (1.0f / 512.0f);
}

// ---------------------------------------------------------------------------
extern "C" void kernel_launch(void* const* d_in, const int* in_sizes, int n_in,
                              void* d_out, int out_size, void* d_ws, size_t ws_size,
                              hipStream_t stream)
{
    (void)in_sizes; (void)n_in; (void)out_size; (void)ws_size;
    char* ws = (char*)d_ws;
    const float* yhat = (const float*)d_in[0];
    const float* ysig = (const float*)d_in[1];
    const float* Wl[5]; const float* gl[5]; const float* bl[5];
    for (int i = 0; i < 5; ++i) {
        Wl[i] = (const float*)d_in[2 + 3 * i];
        gl[i] = (const float*)d_in[3 + 3 * i];
        bl[i] = (const float*)d_in[4 + 3 * i];
    }
    float* out = (float*)d_out;
    float* statsA = (float*)(ws + O_STATS);

    _Float16* w1 = (_Float16*)(ws + O_W1);
    _Float16* w2 = (_Float16*)(ws + O_W2);
    _Float16* w3 = (_Float16*)(ws + O_W3);
    _Float16* w4 = (_Float16*)(ws + O_W4);
    _Float16* h0 = (_Float16*)(ws + O_H0);
    _Float16* h1 = (_Float16*)(ws + O_H1);
    _Float16* h2 = (_Float16*)(ws + O_H2);
    _Float16* h3 = (_Float16*)(ws + O_H3);

    hipMemsetAsync(statsA, 0, 512 * sizeof(float), stream);
    // zero f16 feature buffers (incl. K-pad columns 198..223)
    hipMemsetAsync(ws + O_FEATX, 0, 16 * 512 * 224 * 2, stream);
    hipMemsetAsync(ws + O_FEATY, 0, 16 * 512 * 224 * 2, stream);
    prep_w<<<dim3(1024, 4), 256, 0, stream>>>(Wl[1], Wl[2], Wl[3], Wl[4],
        w1, w2, w3, w4);

    for (int s = 0; s < 2; ++s) {
        const float* wav = (s == 0) ? yhat : ysig;
        float* st = statsA + (size_t)s * 160;
        _Float16* ft = (_Float16*)(ws + ((s == 0) ? O_FEATX : O_FEATY));

        conv0_store<<<dim3(25, 4, 16), 256, 0, stream>>>(wav, Wl[0], h0, st);

        conv1_mfma<<<dim3(832), 256, 0, stream>>>(
            h0, w1, st, gl[0], bl[0], h1, st + 32);

        conv_mfma<true><<<dim3(832), 256, 0, stream>>>(
            h1, w2, st + 32, gl[1], bl[1], h2, nullptr, st + 64, 1598, 798, 13);

        conv_mfma<true><<<dim3(448), 256, 0, stream>>>(
            h2, w3, st + 64, gl[2], bl[2], h3, nullptr, st + 96, 798, 398, 7);

        conv_mfma<false><<<dim3(256), 256, 0, stream>>>(
            h3, w4, st + 96, gl[3], bl[3], nullptr, ft, st + 128, 398, 198, 4);

        norm_feat<<<dim3(1, 8192), 256, 0, stream>>>(
            ft, st + 128, gl[4], bl[4]);
    }

    _Float16* featX = (_Float16*)(ws + O_FEATX);
    _Float16* featY = (_Float16*)(ws + O_FEATY);
    aa_kernel<<<4096, 256, 0, stream>>>(featX, featY, (float*)(ws + O_AAX), (float*)(ws + O_AAY));
    cost_kernel<<<dim3(16, 48), 256, 0, stream>>>(
        featX, featY, (float*)(ws + O_AAX), (float*)(ws + O_AAY),
        (_Float16*)(ws + O_CXY), (_Float16*)(ws + O_CXX), (_Float16*)(ws + O_CYY),
        (_Float16*)(ws + O_CTXY));

    hipMemsetAsync(ws + O_F, 0, 2 * 24576 * sizeof(float), stream);

    float* fptr = (float*)(ws + O_F);
    float* gptr = (float*)(ws + O_G);
    _Float16* cxy  = (_Float16*)(ws + O_CXY);
    _Float16* ctxy = (_Float16*)(ws + O_CTXY);
    _Float16* cxx  = (_Float16*)(ws + O_CXX);
    _Float16* cyy  = (_Float16*)(ws + O_CYY);

    for (int it = 0; it < 50; ++it) {
        sink_update<<<dim3(32, 48), 256, 0, stream>>>(gptr, fptr, ctxy, cxx, cyy);
        sink_update<<<dim3(32, 48), 256, 0, stream>>>(fptr, gptr, cxy, cxx, cyy);
    }

    final_kernel<<<16, 256, 0, stream>>>(fptr, gptr, out);
}

// Round 13
// 1621.938 us; speedup vs baseline: 1.1090x; 1.0300x over previous
//
#include <hip/hip_runtime.h>

typedef unsigned int uint;
typedef unsigned short ushort;
using half8v  = __attribute__((ext_vector_type(8))) _Float16;
using half4v  = __attribute__((ext_vector_type(4))) _Float16;
using float4v = __attribute__((ext_vector_type(4))) float;

#define EPS_SINK 0.0025f
#define EPS_LOG512 0.015595811562598769f

// ---- workspace layout (BYTE offsets), peak ~165 MB ----
static const size_t O_W1   = 0ull;             // 512*512*8 f16 = 4,194,304 B
static const size_t O_W2   = 4194304ull;       // 2,097,152 B each
static const size_t O_W3   = 6291456ull;
static const size_t O_W4   = 8388608ull;
static const size_t O_H0   = 20971520ull;      // 16*512*6400 f16 = 104,857,600 B
static const size_t O_H1   = 125829120ull;     // 16*256*1598 uint = 26,181,632 B
static const size_t O_H2   = 20971520ull;      // alias h0 (dead after conv1)
static const size_t O_H3   = 34045952ull;
static const size_t O_FEATX= 152010752ull;     // 16*512*224 f16 = 3,670,016 B
static const size_t O_FEATY= 158498816ull;
static const size_t O_STATS= 164986880ull;     // 512 floats
// cost phase (weights/h0/h1 all dead).  C stored f16, value = 100*C:
static const size_t O_CXY  = 0ull;             // 8,388,608 B each
static const size_t O_CTXY = 8388608ull;
static const size_t O_CXX  = 16777216ull;
static const size_t O_CYY  = 25165824ull;
static const size_t O_AAX  = 33554432ull;
static const size_t O_AAY  = 33587200ull;
static const size_t O_F    = 33619968ull;      // 3*16*512 fp32
static const size_t O_G    = 33718272ull;

#define GLOAD_LDS16(gp, lp) __builtin_amdgcn_global_load_lds( \
    (const __attribute__((address_space(1))) void*)(gp),       \
    (__attribute__((address_space(3))) void*)(lp), 16, 0, 0)

// ---------------------------------------------------------------------------
// prep_w: convert conv weights fp32 -> single f16. W1 [oc][ic][8 taps];
// W2-4 pair-interleaved [oc][icpair][dt0 icA, dt0 icB, dt1 icA, ...].
// ---------------------------------------------------------------------------
__global__ __launch_bounds__(256) void prep_w(
    const float* __restrict__ W1, const float* __restrict__ W2,
    const float* __restrict__ W3, const float* __restrict__ W4,
    _Float16* __restrict__ w1, _Float16* __restrict__ w2,
    _Float16* __restrict__ w3, _Float16* __restrict__ w4)
{
    const int layer = blockIdx.y;
    const int e = blockIdx.x * 256 + threadIdx.x;
    float v[8];
    _Float16* dh;
    if (layer == 0) {
        const float4 a = *(const float4*)(W1 + (size_t)e * 8);
        const float4 c = *(const float4*)(W1 + (size_t)e * 8 + 4);
        v[0]=a.x; v[1]=a.y; v[2]=a.z; v[3]=a.w; v[4]=c.x; v[5]=c.y; v[6]=c.z; v[7]=c.w;
        dh = w1;
    } else {
        if (e >= 131072) return;
        const float* W = (layer == 1) ? W2 : (layer == 2) ? W3 : W4;
        dh = (layer == 1) ? w2 : (layer == 2) ? w3 : w4;
        const int oc = e >> 8, icp = e & 255;
        const float4 a = *(const float4*)(W + ((size_t)oc * 512 + icp * 2) * 4);
        const float4 c = *(const float4*)(W + ((size_t)oc * 512 + icp * 2 + 1) * 4);
        v[0]=a.x; v[1]=c.x; v[2]=a.y; v[3]=c.y; v[4]=a.z; v[5]=c.z; v[6]=a.w; v[7]=c.w;
    }
    half8v hi;
#pragma unroll
    for (int k = 0; k < 8; ++k) hi[k] = (_Float16)v[k];
    *(half8v*)(dh + (size_t)e * 8) = hi;
}

// ---------------------------------------------------------------------------
// conv0_store v3: raw conv0 (k=10,s=5) -> h0 f16 [b][512][6400] + GN stats.
// Input window (2565 fp32) staged in LDS; each thread owns 8 consecutive t
// (50 input floats in regs, reused across 32 ocs) and emits ONE half8 (16B)
// coalesced store per oc (was 2B/lane scalar stores). Grid (13, 4, 16).
// Slot t=6399 computed from OOB-clamped inputs -- feeds only conv1's
// discarded t>=1598 column. Stats count t<6399 only.
// ---------------------------------------------------------------------------
__global__ __launch_bounds__(256) void conv0_store(
    const float* __restrict__ wav, const float* __restrict__ W0,
    _Float16* __restrict__ h0, float* __restrict__ stats)
{
    __shared__ float LX[2565];
    __shared__ float LW[1280];
    __shared__ float red[2][256];
    const int tid = threadIdx.x;
    const int ocq = blockIdx.y;                // 0..3, 128-oc chunk
    const int oc0 = ocq * 128;
    const int b   = blockIdx.z;
    const int t0  = blockIdx.x * 512;
    const int w0  = t0 * 5;

    for (int e = tid; e < 1280; e += 256) LW[e] = W0[oc0 * 10 + e];
    const float* wb = wav + (size_t)b * 32000;
    for (int e = tid; e < 2565; e += 256)
        LX[e] = (w0 + e < 32000) ? wb[w0 + e] : 0.f;
    __syncthreads();

    const int lane6 = tid & 63;                // t8-group index within block
    const int wvi   = tid >> 6;                // 0..3
    const int t1    = t0 + lane6 * 8;          // first t of this thread's group
    const bool doS  = (t1 + 8 <= 6400);        // group fully within row
    float x[50];
    if (doS) {
#pragma unroll
        for (int j = 0; j < 50; ++j) x[j] = LX[lane6 * 40 + j];
    }

    float lsum = 0.f, lsq = 0.f;
    _Float16* hb = h0 + ((size_t)b * 512 + oc0) * 6400;
    if (doS) {
        for (int r = 0; r < 32; ++r) {
            const int oc = wvi + 4 * r;        // wave-uniform
            float w[10];
#pragma unroll
            for (int d = 0; d < 10; ++d) w[d] = LW[oc * 10 + d];
            half8v hv;
#pragma unroll
            for (int k = 0; k < 8; ++k) {
                float a = 0.f;
#pragma unroll
                for (int d = 0; d < 10; ++d) a = fmaf(w[d], x[k * 5 + d], a);
                hv[k] = (_Float16)a;
                if (t1 + k < 6399) { lsum += a; lsq += a * a; }
            }
            *(half8v*)(hb + (size_t)oc * 6400 + t1) = hv;
        }
    }
    red[0][tid] = lsum; red[1][tid] = lsq;
    __syncthreads();
    for (int s2 = 128; s2 > 0; s2 >>= 1) {
        if (tid < s2) { red[0][tid] += red[0][tid + s2]; red[1][tid] += red[1][tid + s2]; }
        __syncthreads();
    }
    if (tid == 0) {
        atomicAdd(&stats[2 * b], red[0][0]);
        atomicAdd(&stats[2 * b + 1], red[1][0]);
    }
}

// ---------------------------------------------------------------------------
// conv1_mfma v6: layer1 (K=8,S=4), 128oc x 128t tile (proven structure,
// round-8 = 1690us config) + FUSED GN0 affine+ReLU on the X-load path.
// LDS 38 KB -> 4 blocks/CU.
// ---------------------------------------------------------------------------
__global__ __launch_bounds__(256, 4) void conv1_mfma(
    const _Float16* __restrict__ h0,
    const _Float16* __restrict__ w1,
    const float* __restrict__ stats0,
    const float* __restrict__ gamma0, const float* __restrict__ beta0,
    _Float16* __restrict__ oh, float* __restrict__ stats1)
{
    __shared__ _Float16 LW[2][2][4][128][8];   // 32 KB [buf][k32l][q][oc][8]
    __shared__ float LSC[512], LSH[512];       // 4 KB GN0 fold tables
    __shared__ float red[2][256];

    const int tid  = threadIdx.x;
    const int lane = tid & 63, wv = tid >> 6;
    const int m    = lane & 15, quad = lane >> 4;
    const int wv2  = wv >> 1, wvt = wv & 1;

    // chunked XCD swizzle: 832 blocks = 8 chunks of 104; y (oc-tile) fastest
    const int raw = blockIdx.x;
    const int cid = (raw & 7) * 104 + (raw >> 3);
    const int b   = cid / 52;
    const int r2  = cid - b * 52;
    const int xt  = r2 >> 2, yt = r2 & 3;
    const int ocb = yt * 128;
    const int t0  = xt * 128;
    const int Lout = 1598;

    // --- GN0 fold tables (stats0 complete at launch boundary)
    {
        const float invN = 1.f / (512.f * 6399.f);
        const float mu = stats0[2 * b] * invN;
        const float var = stats0[2 * b + 1] * invN - mu * mu;
        const float rs = rsqrtf(var + 1e-5f);
        for (int ic = tid; ic < 512; ic += 256) {
            const float sc = rs * gamma0[ic];
            LSC[ic] = sc;
            LSH[ic] = beta0[ic] - mu * sc;
        }
    }

    float4v acc[4][4];
#pragma unroll
    for (int i = 0; i < 4; ++i)
#pragma unroll
        for (int j = 0; j < 4; ++j) acc[i][j] = (float4v){0.f, 0.f, 0.f, 0.f};

    const _Float16* hb = h0 + (size_t)b * 512 * 6400;
    const int gbase = t0 * 4;
    const _Float16* px = hb + (size_t)quad * 6400 + gbase + (wvt * 64 + m) * 4;

    const _Float16* wsrc[4];
#pragma unroll
    for (int r = 0; r < 4; ++r) {
        const int e = wv * 4 + r;
        const int oh2 = e & 1, q = (e >> 1) & 3, k32l = e >> 3;
        wsrc[r] = w1 + ((size_t)(ocb + oh2 * 64 + lane) * 512 + (k32l * 4 + q)) * 8;
    }
    auto stageW = [&](int buf) {
#pragma unroll
        for (int r = 0; r < 4; ++r) {
            const int e = wv * 4 + r;
            const int oh2 = e & 1, q = (e >> 1) & 3, k32l = e >> 3;
            GLOAD_LDS16(wsrc[r], &LW[buf][k32l][q][oh2 * 64][0]);
            wsrc[r] += 64;                     // 8 ic * 8 taps
        }
    };

    stageW(0);
    __syncthreads();

    for (int it = 0; it < 64; ++it) {
        const int buf = it & 1;
        if (it < 63) stageW(buf ^ 1);
#pragma unroll
        for (int k32l = 0; k32l < 2; ++k32l) {
            half8v a4[4], bfv[4];
#pragma unroll
            for (int i = 0; i < 4; ++i)
                a4[i] = *(const half8v*)&LW[buf][k32l][quad][wv2 * 64 + i * 16 + m][0];
            const int ic = quad + 4 * k32l + 8 * it;
            const _Float16 sch = (_Float16)LSC[ic];
            const _Float16 shh = (_Float16)LSH[ic];
            const _Float16* pr = px + (size_t)k32l * 25600;   // +4 rows
#pragma unroll
            for (int j = 0; j < 4; ++j) {
                half8v xv = *(const half8v*)(pr + j * 64);
#pragma unroll
                for (int k = 0; k < 8; ++k) {
                    const _Float16 v = xv[k] * sch + shh;
                    xv[k] = (v > (_Float16)0.f) ? v : (_Float16)0.f;
                }
                bfv[j] = xv;
            }
#pragma unroll
            for (int i = 0; i < 4; ++i)
#pragma unroll
                for (int j = 0; j < 4; ++j)
                    acc[i][j] = __builtin_amdgcn_mfma_f32_16x16x32_f16(a4[i], bfv[j], acc[i][j], 0, 0, 0);
        }
        px += 51200;                           // +8 rows
        __syncthreads();
    }

    // --- epilogue: pack f16 pairs + stats (RAW conv1 outputs, pre-GN1)
    float lsum = 0.f, lsq = 0.f;
    uint* ohU = (uint*)oh;
#pragma unroll
    for (int i = 0; i < 4; ++i) {
        const int ocb2 = ocb + wv2 * 64 + i * 16 + quad * 4;
#pragma unroll
        for (int j = 0; j < 4; ++j) {
            const int t = t0 + wvt * 64 + j * 16 + m;
            if (t < Lout) {
#pragma unroll
                for (int pr = 0; pr < 2; ++pr) {
                    const float v0 = acc[i][j][pr * 2], v1 = acc[i][j][pr * 2 + 1];
                    union { uint u; _Float16 h[2]; } pk;
                    pk.h[0] = (_Float16)v0; pk.h[1] = (_Float16)v1;
                    const uint p = (uint)((ocb2 >> 1) + pr);
                    ohU[((size_t)(b * 256 + p)) * Lout + t] = pk.u;
                    lsum += v0 + v1; lsq += v0 * v0 + v1 * v1;
                }
            }
        }
    }
    red[0][tid] = lsum; red[1][tid] = lsq;
    __syncthreads();
    for (int s2 = 128; s2 > 0; s2 >>= 1) {
        if (tid < s2) { red[0][tid] += red[0][tid + s2]; red[1][tid] += red[1][tid + s2]; }
        __syncthreads();
    }
    if (tid == 0) {
        atomicAdd(&stats1[2 * b], red[0][0]);
        atomicAdd(&stats1[2 * b + 1], red[1][0]);
    }
}

// ---------------------------------------------------------------------------
// conv_mfma v5: layers 2-4 (K=4,S=2). 128oc x 64t tile, register dbuf X
// prefetch + FUSED prev-layer GN affine+ReLU at consume time (round-8 =
// 1690us config; 64t keeps grids at 832/448/256 blocks).
// PAIRED: f16 pair-interleaved out; else f16 features [ch][224] (padded).
// ---------------------------------------------------------------------------
template <bool PAIRED>
__global__ __launch_bounds__(256, 4) void conv_mfma(
    const _Float16* __restrict__ x,
    const _Float16* __restrict__ w,
    const float* __restrict__ statsP,
    const float* __restrict__ gammaP, const float* __restrict__ betaP,
    _Float16* __restrict__ oh, _Float16* __restrict__ ofeat,
    float* __restrict__ statsO, int Lin, int Lout, int nx)
{
    __shared__ _Float16 LW[2][2][4][128][8];   // 32 KB
    __shared__ float LN[256][4];               // sc0,sh0,sc1,sh1 per pair, 4 KB
    __shared__ float red[2][256];

    const int tid  = threadIdx.x;
    const int lane = tid & 63, wv = tid >> 6;
    const int m    = lane & 15, quad = lane >> 4;
    const int wv2  = wv >> 1, wvt = wv & 1;

    // chunked XCD swizzle (nwg = nx*64, always % 8 == 0), y fastest in chunk
    const int raw = blockIdx.x;
    const int chunk = (nx * 64) >> 3;
    const int cid = (raw & 7) * chunk + (raw >> 3);
    const int perb = nx * 4;
    const int b   = cid / perb;
    const int r2  = cid - b * perb;
    const int xt  = r2 >> 2, yt = r2 & 3;
    const int ocb = yt * 128;
    const int t0  = xt * 64;

    // --- prev-layer GN fold tables
    {
        const float invN = 1.f / (512.f * (float)Lin);
        const float mu = statsP[2 * b] * invN;
        const float var = statsP[2 * b + 1] * invN - mu * mu;
        const float rs = rsqrtf(var + 1e-5f);
        const int c0 = 2 * tid, c1 = 2 * tid + 1;
        const float sc0 = rs * gammaP[c0], sc1 = rs * gammaP[c1];
        LN[tid][0] = sc0; LN[tid][1] = betaP[c0] - mu * sc0;
        LN[tid][2] = sc1; LN[tid][3] = betaP[c1] - mu * sc1;
    }

    float4v acc[4][2];
#pragma unroll
    for (int i = 0; i < 4; ++i)
#pragma unroll
        for (int j = 0; j < 2; ++j) acc[i][j] = (float4v){0.f, 0.f, 0.f, 0.f};

    const size_t rstride = (size_t)Lin * 2;
    const _Float16* px = x + ((size_t)(b * 256) + quad) * rstride
                           + t0 * 4 + (wvt * 32 + m) * 4;

    const _Float16* wsrc[4];
#pragma unroll
    for (int r = 0; r < 4; ++r) {
        const int e = wv * 4 + r;
        const int oh2 = e & 1, q = (e >> 1) & 3, k32l = e >> 3;
        wsrc[r] = w + ((size_t)(ocb + oh2 * 64 + lane) * 256 + (k32l * 4 + q)) * 8;
    }
    auto stageW = [&](int buf) {
#pragma unroll
        for (int r = 0; r < 4; ++r) {
            const int e = wv * 4 + r;
            const int oh2 = e & 1, q = (e >> 1) & 3, k32l = e >> 3;
            GLOAD_LDS16(wsrc[r], &LW[buf][k32l][q][oh2 * 64][0]);
            wsrc[r] += 64;                     // 8 icp * 8
        }
    };
    auto loadX = [&](half8v (&xr)[4], const _Float16* p) {
#pragma unroll
        for (int k32l = 0; k32l < 2; ++k32l)
#pragma unroll
            for (int j = 0; j < 2; ++j)
                xr[k32l * 2 + j] = *(const half8v*)(p + (size_t)k32l * 4 * rstride + j * 64);
    };
    auto compute = [&](int buf, half8v (&xr)[4], int plB) {
#pragma unroll
        for (int k32l = 0; k32l < 2; ++k32l) {
            half8v a4[4];
#pragma unroll
            for (int i = 0; i < 4; ++i)
                a4[i] = *(const half8v*)&LW[buf][k32l][quad][wv2 * 64 + i * 16 + m][0];
            const int pl = plB + quad + 4 * k32l;
            const _Float16 s0 = (_Float16)LN[pl][0], h0v = (_Float16)LN[pl][1];
            const _Float16 s1 = (_Float16)LN[pl][2], h1v = (_Float16)LN[pl][3];
            half8v xn[2];
#pragma unroll
            for (int j = 0; j < 2; ++j) {
                half8v xv = xr[k32l * 2 + j];
#pragma unroll
                for (int k = 0; k < 8; ++k) {
                    const _Float16 v = xv[k] * ((k & 1) ? s1 : s0) + ((k & 1) ? h1v : h0v);
                    xv[k] = (v > (_Float16)0.f) ? v : (_Float16)0.f;
                }
                xn[j] = xv;
            }
#pragma unroll
            for (int i = 0; i < 4; ++i)
#pragma unroll
                for (int j = 0; j < 2; ++j)
                    acc[i][j] = __builtin_amdgcn_mfma_f32_16x16x32_f16(a4[i], xn[j], acc[i][j], 0, 0, 0);
        }
    };

    half8v xrA[4], xrB[4];
    loadX(xrA, px); px += 8 * rstride;         // iter 0
    stageW(0);
    __syncthreads();

    for (int it = 0; it < 32; it += 2) {
        stageW(1);
        loadX(xrB, px); px += 8 * rstride;     // iter it+1
        compute(0, xrA, 8 * it);
        __syncthreads();
        if (it + 2 < 32) {
            stageW(0);
            loadX(xrA, px);                    // iter it+2
        }
        px += 8 * rstride;
        compute(1, xrB, 8 * (it + 1));
        __syncthreads();
    }

    // --- epilogue (RAW conv outputs, pre-GN)
    float lsum = 0.f, lsq = 0.f;
    uint* ohU = (uint*)oh;
#pragma unroll
    for (int i = 0; i < 4; ++i) {
        const int ocb2 = ocb + wv2 * 64 + i * 16 + quad * 4;
#pragma unroll
        for (int j = 0; j < 2; ++j) {
            const int t = t0 + wvt * 32 + j * 16 + m;
            if (t < Lout) {
                if (PAIRED) {
#pragma unroll
                    for (int pr = 0; pr < 2; ++pr) {
                        const float v0 = acc[i][j][pr * 2], v1 = acc[i][j][pr * 2 + 1];
                        union { uint u; _Float16 h[2]; } pk;
                        pk.h[0] = (_Float16)v0; pk.h[1] = (_Float16)v1;
                        const uint p = (uint)((ocb2 >> 1) + pr);
                        ohU[((size_t)(b * 256 + p)) * Lout + t] = pk.u;
                        lsum += v0 + v1; lsq += v0 * v0 + v1 * v1;
                    }
                } else {
#pragma unroll
                    for (int r = 0; r < 4; ++r) {
                        const float v = acc[i][j][r];
                        ofeat[((size_t)(b * 512 + ocb2 + r)) * 224 + t] = (_Float16)v;
                        lsum += v; lsq += v * v;
                    }
                }
            }
        }
    }
    red[0][tid] = lsum; red[1][tid] = lsq;
    __syncthreads();
    for (int s2 = 128; s2 > 0; s2 >>= 1) {
        if (tid < s2) { red[0][tid] += red[0][tid + s2]; red[1][tid] += red[1][tid + s2]; }
        __syncthreads();
    }
    if (tid == 0) {
        atomicAdd(&statsO[2 * b], red[0][0]);
        atomicAdd(&statsO[2 * b + 1], red[1][0]);
    }
}

// ---------------------------------------------------------------------------
// norm_feat: GN+affine+ReLU in place on f16 features [row][224], t<198.
// ---------------------------------------------------------------------------
__global__ __launch_bounds__(256) void norm_feat(
    _Float16* __restrict__ h, const float* __restrict__ stats,
    const float* __restrict__ gamma, const float* __restrict__ beta)
{
    const int row = blockIdx.y;
    const int b = row >> 9, oc = row & 511;
    const int t = threadIdx.x;
    if (t >= 198) return;
    const float invN = 1.f / (512.f * 198.f);
    const float mu = stats[2 * b] * invN;
    const float var = stats[2 * b + 1] * invN - mu * mu;
    const float rs = rsqrtf(var + 1e-5f);
    const float sc = rs * gamma[oc];
    const float sh = beta[oc] - mu * sc;
    const size_t i = (size_t)row * 224 + t;
    const float v = (float)h[i] * sc + sh;
    h[i] = (_Float16)(v > 0.f ? v : 0.f);
}

// ---------------------------------------------------------------------------
// aa_kernel: row squared-norms of f16 features [row][224] (pad is zero).
// ---------------------------------------------------------------------------
__global__ __launch_bounds__(256) void aa_kernel(
    const _Float16* __restrict__ fX, const _Float16* __restrict__ fY,
    float* __restrict__ aaX, float* __restrict__ aaY)
{
    const int wave = threadIdx.x >> 6, lane = threadIdx.x & 63;
    const int R = blockIdx.x * 4 + wave;
    const _Float16* f = (R < 8192) ? fX : fY;
    const int r = R & 8191;
    const _Float16* row = f + (size_t)r * 224;
    float s = 0.f;
    if (lane < 56) {
        const half4v v = *(const half4v*)(row + lane * 4);
#pragma unroll
        for (int k = 0; k < 4; ++k) { const float x = (float)v[k]; s += x * x; }
    }
#pragma unroll
    for (int off = 32; off > 0; off >>= 1) s += __shfl_xor(s, off);
    if (lane == 0) ((R < 8192) ? aaX : aaY)[r] = s;
}

// ---------------------------------------------------------------------------
// cost_kernel v2: MFMA GEMM on f16 features (K padded to 224, zeros).
// Symmetric mats (xx,yy): upper tiles only, mirror-write.
// M = f16( min(50 * max(aa[n]+bb[m]-2<p,q>, 0), 65000) ) == 100*C
// ---------------------------------------------------------------------------
__global__ __launch_bounds__(256) void cost_kernel(
    const _Float16* __restrict__ fX, const _Float16* __restrict__ fY,
    const float* __restrict__ aaX, const float* __restrict__ aaY,
    _Float16* __restrict__ Cxy, _Float16* __restrict__ Cxx,
    _Float16* __restrict__ Cyy, _Float16* __restrict__ CTxy)
{
    const int z = blockIdx.y;
    const int mat = z >> 4, b = z & 15;
    const int nt = blockIdx.x & 3, mt = blockIdx.x >> 2;
    if (mat != 0 && nt > mt) return;
    const _Float16 *P, *Q; const float *aP, *aQ;
    _Float16 *Cm, *CT;
    if (mat == 0)      { P = fX; Q = fY; aP = aaX; aQ = aaY; Cm = Cxy; CT = CTxy; }
    else if (mat == 1) { P = fX; Q = fX; aP = aaX; aQ = aaX; Cm = Cxx; CT = (nt < mt) ? Cxx : nullptr; }
    else               { P = fY; Q = fY; aP = aaY; aQ = aaY; Cm = Cyy; CT = (nt < mt) ? Cyy : nullptr; }

    const int tid = threadIdx.x, lane = tid & 63, wv = tid >> 6;
    const int m16 = lane & 15, quad = lane >> 4;
    const int wv2 = wv >> 1, wvt = wv & 1;
    const int nb = nt * 128 + wv2 * 64;
    const int mb = mt * 128 + wvt * 64;
    const _Float16* Pb = P + (size_t)b * 512 * 224;
    const _Float16* Qb = Q + (size_t)b * 512 * 224;

    float4v acc[4][4];
#pragma unroll
    for (int i = 0; i < 4; ++i)
#pragma unroll
        for (int j = 0; j < 4; ++j) acc[i][j] = (float4v){0.f, 0.f, 0.f, 0.f};

    for (int k32 = 0; k32 < 7; ++k32) {
        const int ko = k32 * 32 + quad * 8;
        half8v a4[4], b4[4];
#pragma unroll
        for (int i = 0; i < 4; ++i)
            a4[i] = *(const half8v*)(Pb + (size_t)(nb + i * 16 + m16) * 224 + ko);
#pragma unroll
        for (int j = 0; j < 4; ++j)
            b4[j] = *(const half8v*)(Qb + (size_t)(mb + j * 16 + m16) * 224 + ko);
#pragma unroll
        for (int i = 0; i < 4; ++i)
#pragma unroll
            for (int j = 0; j < 4; ++j)
                acc[i][j] = __builtin_amdgcn_mfma_f32_16x16x32_f16(a4[i], b4[j], acc[i][j], 0, 0, 0);
    }

#pragma unroll
    for (int i = 0; i < 4; ++i) {
        const int nrow0 = nb + i * 16 + quad * 4;
        float aa4[4];
#pragma unroll
        for (int r = 0; r < 4; ++r) aa4[r] = aP[b * 512 + nrow0 + r];
#pragma unroll
        for (int j = 0; j < 4; ++j) {
            const int mcol = mb + j * 16 + m16;
            const float bbm = aQ[b * 512 + mcol];
#pragma unroll
            for (int r = 0; r < 4; ++r) {
                const int n = nrow0 + r;
                float c = 50.f * fmaxf(aa4[r] + bbm - 2.f * acc[i][j][r], 0.f);
                c = fminf(c, 65000.f);
                const _Float16 ch = (_Float16)c;
                Cm[((size_t)(b * 512 + n)) * 512 + mcol] = ch;
                if (CT) CT[((size_t)(b * 512 + mcol)) * 512 + n] = ch;
            }
        }
    }
}

// ---------------------------------------------------------------------------
// Per-row half-update (two-pass max-then-sum; __expf = native v_exp_f32.
// NOTE: bare exp2f/log2f regressed ~120us total (rounds 9/10) -- precise-OCML
// lowering; keep __expf/logf).
// dst[p*512+i] = eps*log512 - eps*LSE_j( 400*src[j] - 4*M100[i,j] )
// ---------------------------------------------------------------------------
static __device__ __forceinline__ void sink_rows(
    float* __restrict__ dst, const float* __restrict__ src,
    const _Float16* __restrict__ Mb, int p, int i0, int lane)
{
    const float* sp = src + (size_t)p * 512;
    float s8[8];
    {
        const float4 sa = *(const float4*)&sp[lane * 8];
        const float4 sb = *(const float4*)&sp[lane * 8 + 4];
        s8[0]=sa.x*400.f; s8[1]=sa.y*400.f; s8[2]=sa.z*400.f; s8[3]=sa.w*400.f;
        s8[4]=sb.x*400.f; s8[5]=sb.y*400.f; s8[6]=sb.z*400.f; s8[7]=sb.w*400.f;
    }
#pragma unroll
    for (int rr = 0; rr < 4; ++rr) {
        const int i = i0 + rr;
        const half8v rv = *(const half8v*)(Mb + (size_t)i * 512 + lane * 8);
        float a8[8];
#pragma unroll
        for (int k = 0; k < 8; ++k) a8[k] = fmaf(-4.f, (float)rv[k], s8[k]);
        float mx = a8[0];
#pragma unroll
        for (int k = 1; k < 8; ++k) mx = fmaxf(mx, a8[k]);
        // wave-global max (fmax butterfly, no exps)
#pragma unroll
        for (int off = 32; off > 0; off >>= 1) mx = fmaxf(mx, __shfl_xor(mx, off));
        // sum of exp(a - global max)
        float ss = 0.f;
#pragma unroll
        for (int k = 0; k < 8; ++k) ss += __expf(a8[k] - mx);
#pragma unroll
        for (int off = 32; off > 0; off >>= 1) ss += __shfl_xor(ss, off);
        if (lane == 0)
            dst[(size_t)p * 512 + i] = EPS_LOG512 - EPS_SINK * (mx + logf(ss));
    }
}

// ---------------------------------------------------------------------------
// sink_update: one half-update per launch; grid (32,48), 256 thr.
// ---------------------------------------------------------------------------
__global__ __launch_bounds__(256) void sink_update(
    float* __restrict__ dst, const float* __restrict__ src,
    const _Float16* __restrict__ M0, const _Float16* __restrict__ M1,
    const _Float16* __restrict__ M2)
{
    const int p = blockIdx.y;
    const int mat = p >> 4, b = p & 15;
    const _Float16* M = ((mat == 0) ? M0 : ((mat == 1) ? M1 : M2)) + (size_t)b * 512 * 512;
    const int wave = threadIdx.x >> 6, lane = threadIdx.x & 63;
    const int i0 = blockIdx.x * 16 + wave * 4;
    sink_rows(dst, src, M, p, i0, lane);
}

// ---------------------------------------------------------------------------
__global__ __launch_bounds__(256) void final_kernel(
    const float* __restrict__ f, const float* __restrict__ g,
    float* __restrict__ out)
{
    const int b = blockIdx.x, tid = threadIdx.x;
    __shared__ float red[256];
    float a = 0.f;
    for (int n = tid; n < 512; n += 256) {
        const float xy = f[(0 * 16 + b) * 512 + n] + g[(0 * 16 + b) * 512 + n];
        const float xx = f[(1 * 16 + b) * 512 + n] + g[(1 * 16 + b) * 512 + n];
        const float yy = f[(2 * 16 + b) * 512 + n] + g[(2 * 16 + b) * 512 + n];
        a += xy - 0.5f * (xx + yy);
    }
    red[tid] = a;
    __syncthreads();
    for (int s2 = 128; s2 > 0; s2 >>= 1) {
        if (tid < s2) red[tid] += red[tid + s2];
        __syncthreads();
    }
    if (tid == 0) out[b] = red[0] * (1.0f / 512.0f);
}

// ---------------------------------------------------------------------------
extern "C" void kernel_launch(void* const* d_in, const int* in_sizes, int n_in,
                              void* d_out, int out_size, void* d_ws, size_t ws_size,
                              hipStream_t stream)
{
    (void)in_sizes; (void)n_in; (void)out_size; (void)ws_size;
    char* ws = (char*)d_ws;
    const float* yhat = (const float*)d_in[0];
    const float* ysig = (const float*)d_in[1];
    const float* Wl[5]; const float* gl[5]; const float* bl[5];
    for (int i = 0; i < 5; ++i) {
        Wl[i] = (const float*)d_in[2 + 3 * i];
        gl[i] = (const float*)d_in[3 + 3 * i];
        bl[i] = (const float*)d_in[4 + 3 * i];
    }
    float* out = (float*)d_out;
    float* statsA = (float*)(ws + O_STATS);

    _Float16* w1 = (_Float16*)(ws + O_W1);
    _Float16* w2 = (_Float16*)(ws + O_W2);
    _Float16* w3 = (_Float16*)(ws + O_W3);
    _Float16* w4 = (_Float16*)(ws + O_W4);
    _Float16* h0 = (_Float16*)(ws + O_H0);
    _Float16* h1 = (_Float16*)(ws + O_H1);
    _Float16* h2 = (_Float16*)(ws + O_H2);
    _Float16* h3 = (_Float16*)(ws + O_H3);

    hipMemsetAsync(statsA, 0, 512 * sizeof(float), stream);
    // zero both f16 feature buffers (incl. K-pad cols) in one contiguous span
    hipMemsetAsync(ws + O_FEATX, 0, (O_FEATY - O_FEATX) + 16 * 512 * 224 * 2, stream);
    prep_w<<<dim3(1024, 4), 256, 0, stream>>>(Wl[1], Wl[2], Wl[3], Wl[4],
        w1, w2, w3, w4);

    for (int s = 0; s < 2; ++s) {
        const float* wav = (s == 0) ? yhat : ysig;
        float* st = statsA + (size_t)s * 160;
        _Float16* ft = (_Float16*)(ws + ((s == 0) ? O_FEATX : O_FEATY));

        conv0_store<<<dim3(13, 4, 16), 256, 0, stream>>>(wav, Wl[0], h0, st);

        conv1_mfma<<<dim3(832), 256, 0, stream>>>(
            h0, w1, st, gl[0], bl[0], h1, st + 32);

        conv_mfma<true><<<dim3(832), 256, 0, stream>>>(
            h1, w2, st + 32, gl[1], bl[1], h2, nullptr, st + 64, 1598, 798, 13);

        conv_mfma<true><<<dim3(448), 256, 0, stream>>>(
            h2, w3, st + 64, gl[2], bl[2], h3, nullptr, st + 96, 798, 398, 7);

        conv_mfma<false><<<dim3(256), 256, 0, stream>>>(
            h3, w4, st + 96, gl[3], bl[3], nullptr, ft, st + 128, 398, 198, 4);

        norm_feat<<<dim3(1, 8192), 256, 0, stream>>>(
            ft, st + 128, gl[4], bl[4]);
    }

    _Float16* featX = (_Float16*)(ws + O_FEATX);
    _Float16* featY = (_Float16*)(ws + O_FEATY);
    aa_kernel<<<4096, 256, 0, stream>>>(featX, featY, (float*)(ws + O_AAX), (float*)(ws + O_AAY));
    cost_kernel<<<dim3(16, 48), 256, 0, stream>>>(
        featX, featY, (float*)(ws + O_AAX), (float*)(ws + O_AAY),
        (_Float16*)(ws + O_CXY), (_Float16*)(ws + O_CXX), (_Float16*)(ws + O_CYY),
        (_Float16*)(ws + O_CTXY));

    hipMemsetAsync(ws + O_F, 0, 2 * 24576 * sizeof(float), stream);

    float* fptr = (float*)(ws + O_F);
    float* gptr = (float*)(ws + O_G);
    _Float16* cxy  = (_Float16*)(ws + O_CXY);
    _Float16* ctxy = (_Float16*)(ws + O_CTXY);
    _Float16* cxx  = (_Float16*)(ws + O_CXX);
    _Float16* cyy  = (_Float16*)(ws + O_CYY);

    for (int it = 0; it < 50; ++it) {
        sink_update<<<dim3(32, 48), 256, 0, stream>>>(gptr, fptr, ctxy, cxx, cyy);
        sink_update<<<dim3(32, 48), 256, 0, stream>>>(fptr, gptr, cxy, cxx, cyy);
    }

    final_kernel<<<16, 256, 0, stream>>>(fptr, gptr, out);
}

// Round 14
// 1574.749 us; speedup vs baseline: 1.1423x; 1.0300x over previous
//
#include <hip/hip_runtime.h>

typedef unsigned int uint;
typedef unsigned short ushort;
using half8v  = __attribute__((ext_vector_type(8))) _Float16;
using half4v  = __attribute__((ext_vector_type(4))) _Float16;
using float4v = __attribute__((ext_vector_type(4))) float;

#define EPS_SINK 0.0025f
#define EPS_LOG512 0.015595811562598769f

// ---- workspace layout (BYTE offsets), peak ~161.1 MB ----
// conv phase:
static const size_t O_W1   = 0ull;             // 4,194,304
static const size_t O_W2   = 4194304ull;       // 2,097,152 each
static const size_t O_W3   = 6291456ull;
static const size_t O_W4   = 8388608ull;       // ends 10,485,760
static const size_t O_H2X  = 10485760ull;      // 13,074,432 -> 23,560,192 (outside h0)
static const size_t O_H3X  = 23560192ull;      //  6,516,736 -> 30,076,928
static const size_t O_H0   = 30076928ull;      // 104,857,600 -> 134,934,528
static const size_t O_H2Y  = 30076928ull;      // alias h0 (dead after conv1(Y))
static const size_t O_H3Y  = 43151360ull;      // -> 49,668,096 (inside h0 span)
static const size_t O_H1   = 134934528ull;     // 26,181,632 -> 161,116,160 (X then Y)
static const size_t O_FEATX= 134934528ull;     // overlays dead h1; 3,670,016
static const size_t O_FEATY= 138604544ull;     // -> 142,274,560
static const size_t O_STATS= 161116160ull;     // 512 floats
// cost phase (weights/h0/h1/h2/h3 all dead).  C stored f16, value = 100*C:
static const size_t O_CXY  = 0ull;             // 8,388,608 each
static const size_t O_CTXY = 8388608ull;
static const size_t O_CXX  = 16777216ull;
static const size_t O_CYY  = 25165824ull;
static const size_t O_AAX  = 33554432ull;
static const size_t O_AAY  = 33587200ull;
static const size_t O_F    = 33619968ull;      // 3*16*512 fp32
static const size_t O_G    = 33718272ull;

#define GLOAD_LDS16(gp, lp) __builtin_amdgcn_global_load_lds( \
    (const __attribute__((address_space(1))) void*)(gp),       \
    (__attribute__((address_space(3))) void*)(lp), 16, 0, 0)

// ---------------------------------------------------------------------------
// prep_w: convert conv weights fp32 -> single f16. W1 [oc][ic][8 taps];
// W2-4 pair-interleaved [oc][icpair][dt0 icA, dt0 icB, dt1 icA, ...].
// ---------------------------------------------------------------------------
__global__ __launch_bounds__(256) void prep_w(
    const float* __restrict__ W1, const float* __restrict__ W2,
    const float* __restrict__ W3, const float* __restrict__ W4,
    _Float16* __restrict__ w1, _Float16* __restrict__ w2,
    _Float16* __restrict__ w3, _Float16* __restrict__ w4)
{
    const int layer = blockIdx.y;
    const int e = blockIdx.x * 256 + threadIdx.x;
    float v[8];
    _Float16* dh;
    if (layer == 0) {
        const float4 a = *(const float4*)(W1 + (size_t)e * 8);
        const float4 c = *(const float4*)(W1 + (size_t)e * 8 + 4);
        v[0]=a.x; v[1]=a.y; v[2]=a.z; v[3]=a.w; v[4]=c.x; v[5]=c.y; v[6]=c.z; v[7]=c.w;
        dh = w1;
    } else {
        if (e >= 131072) return;
        const float* W = (layer == 1) ? W2 : (layer == 2) ? W3 : W4;
        dh = (layer == 1) ? w2 : (layer == 2) ? w3 : w4;
        const int oc = e >> 8, icp = e & 255;
        const float4 a = *(const float4*)(W + ((size_t)oc * 512 + icp * 2) * 4);
        const float4 c = *(const float4*)(W + ((size_t)oc * 512 + icp * 2 + 1) * 4);
        v[0]=a.x; v[1]=c.x; v[2]=a.y; v[3]=c.y; v[4]=a.z; v[5]=c.z; v[6]=a.w; v[7]=c.w;
    }
    half8v hi;
#pragma unroll
    for (int k = 0; k < 8; ++k) hi[k] = (_Float16)v[k];
    *(half8v*)(dh + (size_t)e * 8) = hi;
}

// ---------------------------------------------------------------------------
// conv0_store v3: raw conv0 (k=10,s=5) -> h0 f16 [b][512][6400] + GN stats.
// Input window staged in LDS; each thread owns 8 consecutive t and emits one
// half8 (16B) coalesced store per oc. Grid (13, 4, 16).
// ---------------------------------------------------------------------------
__global__ __launch_bounds__(256) void conv0_store(
    const float* __restrict__ wav, const float* __restrict__ W0,
    _Float16* __restrict__ h0, float* __restrict__ stats)
{
    __shared__ float LX[2565];
    __shared__ float LW[1280];
    __shared__ float red[2][256];
    const int tid = threadIdx.x;
    const int ocq = blockIdx.y;                // 0..3, 128-oc chunk
    const int oc0 = ocq * 128;
    const int b   = blockIdx.z;
    const int t0  = blockIdx.x * 512;
    const int w0  = t0 * 5;

    for (int e = tid; e < 1280; e += 256) LW[e] = W0[oc0 * 10 + e];
    const float* wb = wav + (size_t)b * 32000;
    for (int e = tid; e < 2565; e += 256)
        LX[e] = (w0 + e < 32000) ? wb[w0 + e] : 0.f;
    __syncthreads();

    const int lane6 = tid & 63;                // t8-group index within block
    const int wvi   = tid >> 6;                // 0..3
    const int t1    = t0 + lane6 * 8;          // first t of this thread's group
    const bool doS  = (t1 + 8 <= 6400);        // group fully within row
    float x[50];
    if (doS) {
#pragma unroll
        for (int j = 0; j < 50; ++j) x[j] = LX[lane6 * 40 + j];
    }

    float lsum = 0.f, lsq = 0.f;
    _Float16* hb = h0 + ((size_t)b * 512 + oc0) * 6400;
    if (doS) {
        for (int r = 0; r < 32; ++r) {
            const int oc = wvi + 4 * r;        // wave-uniform
            float w[10];
#pragma unroll
            for (int d = 0; d < 10; ++d) w[d] = LW[oc * 10 + d];
            half8v hv;
#pragma unroll
            for (int k = 0; k < 8; ++k) {
                float a = 0.f;
#pragma unroll
                for (int d = 0; d < 10; ++d) a = fmaf(w[d], x[k * 5 + d], a);
                hv[k] = (_Float16)a;
                if (t1 + k < 6399) { lsum += a; lsq += a * a; }
            }
            *(half8v*)(hb + (size_t)oc * 6400 + t1) = hv;
        }
    }
    red[0][tid] = lsum; red[1][tid] = lsq;
    __syncthreads();
    for (int s2 = 128; s2 > 0; s2 >>= 1) {
        if (tid < s2) { red[0][tid] += red[0][tid + s2]; red[1][tid] += red[1][tid + s2]; }
        __syncthreads();
    }
    if (tid == 0) {
        atomicAdd(&stats[2 * b], red[0][0]);
        atomicAdd(&stats[2 * b + 1], red[1][0]);
    }
}

// ---------------------------------------------------------------------------
// conv1_mfma v6: layer1 (K=8,S=4), 128oc x 128t tile + FUSED GN0 affine+ReLU
// on the X-load path. LDS 38 KB -> 4 blocks/CU.
// ---------------------------------------------------------------------------
__global__ __launch_bounds__(256, 4) void conv1_mfma(
    const _Float16* __restrict__ h0,
    const _Float16* __restrict__ w1,
    const float* __restrict__ stats0,
    const float* __restrict__ gamma0, const float* __restrict__ beta0,
    _Float16* __restrict__ oh, float* __restrict__ stats1)
{
    __shared__ _Float16 LW[2][2][4][128][8];   // 32 KB [buf][k32l][q][oc][8]
    __shared__ float LSC[512], LSH[512];       // 4 KB GN0 fold tables
    __shared__ float red[2][256];

    const int tid  = threadIdx.x;
    const int lane = tid & 63, wv = tid >> 6;
    const int m    = lane & 15, quad = lane >> 4;
    const int wv2  = wv >> 1, wvt = wv & 1;

    // chunked XCD swizzle: 832 blocks = 8 chunks of 104; y (oc-tile) fastest
    const int raw = blockIdx.x;
    const int cid = (raw & 7) * 104 + (raw >> 3);
    const int b   = cid / 52;
    const int r2  = cid - b * 52;
    const int xt  = r2 >> 2, yt = r2 & 3;
    const int ocb = yt * 128;
    const int t0  = xt * 128;
    const int Lout = 1598;

    // --- GN0 fold tables (stats0 complete at launch boundary)
    {
        const float invN = 1.f / (512.f * 6399.f);
        const float mu = stats0[2 * b] * invN;
        const float var = stats0[2 * b + 1] * invN - mu * mu;
        const float rs = rsqrtf(var + 1e-5f);
        for (int ic = tid; ic < 512; ic += 256) {
            const float sc = rs * gamma0[ic];
            LSC[ic] = sc;
            LSH[ic] = beta0[ic] - mu * sc;
        }
    }

    float4v acc[4][4];
#pragma unroll
    for (int i = 0; i < 4; ++i)
#pragma unroll
        for (int j = 0; j < 4; ++j) acc[i][j] = (float4v){0.f, 0.f, 0.f, 0.f};

    const _Float16* hb = h0 + (size_t)b * 512 * 6400;
    const int gbase = t0 * 4;
    const _Float16* px = hb + (size_t)quad * 6400 + gbase + (wvt * 64 + m) * 4;

    const _Float16* wsrc[4];
#pragma unroll
    for (int r = 0; r < 4; ++r) {
        const int e = wv * 4 + r;
        const int oh2 = e & 1, q = (e >> 1) & 3, k32l = e >> 3;
        wsrc[r] = w1 + ((size_t)(ocb + oh2 * 64 + lane) * 512 + (k32l * 4 + q)) * 8;
    }
    auto stageW = [&](int buf) {
#pragma unroll
        for (int r = 0; r < 4; ++r) {
            const int e = wv * 4 + r;
            const int oh2 = e & 1, q = (e >> 1) & 3, k32l = e >> 3;
            GLOAD_LDS16(wsrc[r], &LW[buf][k32l][q][oh2 * 64][0]);
            wsrc[r] += 64;                     // 8 ic * 8 taps
        }
    };

    stageW(0);
    __syncthreads();

    for (int it = 0; it < 64; ++it) {
        const int buf = it & 1;
        if (it < 63) stageW(buf ^ 1);
#pragma unroll
        for (int k32l = 0; k32l < 2; ++k32l) {
            half8v a4[4], bfv[4];
#pragma unroll
            for (int i = 0; i < 4; ++i)
                a4[i] = *(const half8v*)&LW[buf][k32l][quad][wv2 * 64 + i * 16 + m][0];
            const int ic = quad + 4 * k32l + 8 * it;
            const _Float16 sch = (_Float16)LSC[ic];
            const _Float16 shh = (_Float16)LSH[ic];
            const _Float16* pr = px + (size_t)k32l * 25600;   // +4 rows
#pragma unroll
            for (int j = 0; j < 4; ++j) {
                half8v xv = *(const half8v*)(pr + j * 64);
#pragma unroll
                for (int k = 0; k < 8; ++k) {
                    const _Float16 v = xv[k] * sch + shh;
                    xv[k] = (v > (_Float16)0.f) ? v : (_Float16)0.f;
                }
                bfv[j] = xv;
            }
#pragma unroll
            for (int i = 0; i < 4; ++i)
#pragma unroll
                for (int j = 0; j < 4; ++j)
                    acc[i][j] = __builtin_amdgcn_mfma_f32_16x16x32_f16(a4[i], bfv[j], acc[i][j], 0, 0, 0);
        }
        px += 51200;                           // +8 rows
        __syncthreads();
    }

    // --- epilogue: pack f16 pairs + stats (RAW conv1 outputs, pre-GN1)
    float lsum = 0.f, lsq = 0.f;
    uint* ohU = (uint*)oh;
#pragma unroll
    for (int i = 0; i < 4; ++i) {
        const int ocb2 = ocb + wv2 * 64 + i * 16 + quad * 4;
#pragma unroll
        for (int j = 0; j < 4; ++j) {
            const int t = t0 + wvt * 64 + j * 16 + m;
            if (t < Lout) {
#pragma unroll
                for (int pr = 0; pr < 2; ++pr) {
                    const float v0 = acc[i][j][pr * 2], v1 = acc[i][j][pr * 2 + 1];
                    union { uint u; _Float16 h[2]; } pk;
                    pk.h[0] = (_Float16)v0; pk.h[1] = (_Float16)v1;
                    const uint p = (uint)((ocb2 >> 1) + pr);
                    ohU[((size_t)(b * 256 + p)) * Lout + t] = pk.u;
                    lsum += v0 + v1; lsq += v0 * v0 + v1 * v1;
                }
            }
        }
    }
    red[0][tid] = lsum; red[1][tid] = lsq;
    __syncthreads();
    for (int s2 = 128; s2 > 0; s2 >>= 1) {
        if (tid < s2) { red[0][tid] += red[0][tid + s2]; red[1][tid] += red[1][tid + s2]; }
        __syncthreads();
    }
    if (tid == 0) {
        atomicAdd(&stats1[2 * b], red[0][0]);
        atomicAdd(&stats1[2 * b + 1], red[1][0]);
    }
}

// ---------------------------------------------------------------------------
// conv_mfma v6: layers 2-4 (K=4,S=2). 128oc x 64t tile, register dbuf X
// prefetch + FUSED prev-layer GN affine+ReLU. SIGNAL-BATCHED: blockIdx.y
// selects signal (X/Y) pointer slots -- deep layers (3,4) launch once with
// gridDim.y=2, doubling occupancy (conv4 was 1 blk/CU grid-starved).
// PAIRED: f16 pair-interleaved out; else f16 features [ch][224] incl.
// self-zeroed K-pad cols 198..223 (replaces feat memset).
// ---------------------------------------------------------------------------
template <bool PAIRED>
__global__ __launch_bounds__(256, 4) void conv_mfma(
    const _Float16* __restrict__ x0s, const _Float16* __restrict__ x1s,
    const _Float16* __restrict__ w,
    const float* __restrict__ statsP0, const float* __restrict__ statsP1,
    const float* __restrict__ gammaP, const float* __restrict__ betaP,
    _Float16* __restrict__ oh0, _Float16* __restrict__ oh1,
    _Float16* __restrict__ of0, _Float16* __restrict__ of1,
    float* __restrict__ statsO0, float* __restrict__ statsO1,
    int Lin, int Lout, int nx)
{
    __shared__ _Float16 LW[2][2][4][128][8];   // 32 KB
    __shared__ float LN[256][4];               // sc0,sh0,sc1,sh1 per pair, 4 KB
    __shared__ float red[2][256];

    const int sig = blockIdx.y;
    const _Float16* x       = sig ? x1s : x0s;
    const float*    statsP  = sig ? statsP1 : statsP0;
    _Float16*       oh      = sig ? oh1 : oh0;
    _Float16*       ofeat   = sig ? of1 : of0;
    float*          statsO  = sig ? statsO1 : statsO0;

    const int tid  = threadIdx.x;
    const int lane = tid & 63, wv = tid >> 6;
    const int m    = lane & 15, quad = lane >> 4;
    const int wv2  = wv >> 1, wvt = wv & 1;

    // chunked XCD swizzle (nwg = nx*64, always % 8 == 0), y fastest in chunk
    const int raw = blockIdx.x;
    const int chunk = (nx * 64) >> 3;
    const int cid = (raw & 7) * chunk + (raw >> 3);
    const int perb = nx * 4;
    const int b   = cid / perb;
    const int r2  = cid - b * perb;
    const int xt  = r2 >> 2, yt = r2 & 3;
    const int ocb = yt * 128;
    const int t0  = xt * 64;

    // --- prev-layer GN fold tables
    {
        const float invN = 1.f / (512.f * (float)Lin);
        const float mu = statsP[2 * b] * invN;
        const float var = statsP[2 * b + 1] * invN - mu * mu;
        const float rs = rsqrtf(var + 1e-5f);
        const int c0 = 2 * tid, c1 = 2 * tid + 1;
        const float sc0 = rs * gammaP[c0], sc1 = rs * gammaP[c1];
        LN[tid][0] = sc0; LN[tid][1] = betaP[c0] - mu * sc0;
        LN[tid][2] = sc1; LN[tid][3] = betaP[c1] - mu * sc1;
    }

    float4v acc[4][2];
#pragma unroll
    for (int i = 0; i < 4; ++i)
#pragma unroll
        for (int j = 0; j < 2; ++j) acc[i][j] = (float4v){0.f, 0.f, 0.f, 0.f};

    const size_t rstride = (size_t)Lin * 2;
    const _Float16* px = x + ((size_t)(b * 256) + quad) * rstride
                           + t0 * 4 + (wvt * 32 + m) * 4;

    const _Float16* wsrc[4];
#pragma unroll
    for (int r = 0; r < 4; ++r) {
        const int e = wv * 4 + r;
        const int oh2 = e & 1, q = (e >> 1) & 3, k32l = e >> 3;
        wsrc[r] = w + ((size_t)(ocb + oh2 * 64 + lane) * 256 + (k32l * 4 + q)) * 8;
    }
    auto stageW = [&](int buf) {
#pragma unroll
        for (int r = 0; r < 4; ++r) {
            const int e = wv * 4 + r;
            const int oh2 = e & 1, q = (e >> 1) & 3, k32l = e >> 3;
            GLOAD_LDS16(wsrc[r], &LW[buf][k32l][q][oh2 * 64][0]);
            wsrc[r] += 64;                     // 8 icp * 8
        }
    };
    auto loadX = [&](half8v (&xr)[4], const _Float16* p) {
#pragma unroll
        for (int k32l = 0; k32l < 2; ++k32l)
#pragma unroll
            for (int j = 0; j < 2; ++j)
                xr[k32l * 2 + j] = *(const half8v*)(p + (size_t)k32l * 4 * rstride + j * 64);
    };
    auto compute = [&](int buf, half8v (&xr)[4], int plB) {
#pragma unroll
        for (int k32l = 0; k32l < 2; ++k32l) {
            half8v a4[4];
#pragma unroll
            for (int i = 0; i < 4; ++i)
                a4[i] = *(const half8v*)&LW[buf][k32l][quad][wv2 * 64 + i * 16 + m][0];
            const int pl = plB + quad + 4 * k32l;
            const _Float16 s0 = (_Float16)LN[pl][0], h0v = (_Float16)LN[pl][1];
            const _Float16 s1 = (_Float16)LN[pl][2], h1v = (_Float16)LN[pl][3];
            half8v xn[2];
#pragma unroll
            for (int j = 0; j < 2; ++j) {
                half8v xv = xr[k32l * 2 + j];
#pragma unroll
                for (int k = 0; k < 8; ++k) {
                    const _Float16 v = xv[k] * ((k & 1) ? s1 : s0) + ((k & 1) ? h1v : h0v);
                    xv[k] = (v > (_Float16)0.f) ? v : (_Float16)0.f;
                }
                xn[j] = xv;
            }
#pragma unroll
            for (int i = 0; i < 4; ++i)
#pragma unroll
                for (int j = 0; j < 2; ++j)
                    acc[i][j] = __builtin_amdgcn_mfma_f32_16x16x32_f16(a4[i], xn[j], acc[i][j], 0, 0, 0);
        }
    };

    half8v xrA[4], xrB[4];
    loadX(xrA, px); px += 8 * rstride;         // iter 0
    stageW(0);
    __syncthreads();

    for (int it = 0; it < 32; it += 2) {
        stageW(1);
        loadX(xrB, px); px += 8 * rstride;     // iter it+1
        compute(0, xrA, 8 * it);
        __syncthreads();
        if (it + 2 < 32) {
            stageW(0);
            loadX(xrA, px);                    // iter it+2
        }
        px += 8 * rstride;
        compute(1, xrB, 8 * (it + 1));
        __syncthreads();
    }

    // --- epilogue (RAW conv outputs, pre-GN)
    float lsum = 0.f, lsq = 0.f;
    uint* ohU = (uint*)oh;
#pragma unroll
    for (int i = 0; i < 4; ++i) {
        const int ocb2 = ocb + wv2 * 64 + i * 16 + quad * 4;
#pragma unroll
        for (int j = 0; j < 2; ++j) {
            const int t = t0 + wvt * 32 + j * 16 + m;
            if (PAIRED) {
                if (t < Lout) {
#pragma unroll
                    for (int pr = 0; pr < 2; ++pr) {
                        const float v0 = acc[i][j][pr * 2], v1 = acc[i][j][pr * 2 + 1];
                        union { uint u; _Float16 h[2]; } pk;
                        pk.h[0] = (_Float16)v0; pk.h[1] = (_Float16)v1;
                        const uint p = (uint)((ocb2 >> 1) + pr);
                        ohU[((size_t)(b * 256 + p)) * Lout + t] = pk.u;
                        lsum += v0 + v1; lsq += v0 * v0 + v1 * v1;
                    }
                }
            } else {
                // features [ch][224]; write K-pad zeros for t in [Lout,224)
                if (t < 224) {
#pragma unroll
                    for (int r = 0; r < 4; ++r) {
                        const float v = acc[i][j][r];
                        ofeat[((size_t)(b * 512 + ocb2 + r)) * 224 + t] =
                            (t < Lout) ? (_Float16)v : (_Float16)0.f;
                        if (t < Lout) { lsum += v; lsq += v * v; }
                    }
                }
            }
        }
    }
    red[0][tid] = lsum; red[1][tid] = lsq;
    __syncthreads();
    for (int s2 = 128; s2 > 0; s2 >>= 1) {
        if (tid < s2) { red[0][tid] += red[0][tid + s2]; red[1][tid] += red[1][tid + s2]; }
        __syncthreads();
    }
    if (tid == 0) {
        atomicAdd(&statsO[2 * b], red[0][0]);
        atomicAdd(&statsO[2 * b + 1], red[1][0]);
    }
}

// ---------------------------------------------------------------------------
// norm_feat: GN+affine+ReLU in place on f16 features [row][224], t<198.
// Signal-batched: blockIdx.y in [0,16384): bit 13 selects signal.
// ---------------------------------------------------------------------------
__global__ __launch_bounds__(256) void norm_feat(
    _Float16* __restrict__ hX, _Float16* __restrict__ hY,
    const float* __restrict__ statsX, const float* __restrict__ statsY,
    const float* __restrict__ gamma, const float* __restrict__ beta)
{
    const int row0 = blockIdx.y;
    const int sig = row0 >> 13;
    const int row = row0 & 8191;
    _Float16* h = sig ? hY : hX;
    const float* stats = sig ? statsY : statsX;
    const int b = row >> 9, oc = row & 511;
    const int t = threadIdx.x;
    if (t >= 198) return;
    const float invN = 1.f / (512.f * 198.f);
    const float mu = stats[2 * b] * invN;
    const float var = stats[2 * b + 1] * invN - mu * mu;
    const float rs = rsqrtf(var + 1e-5f);
    const float sc = rs * gamma[oc];
    const float sh = beta[oc] - mu * sc;
    const size_t i = (size_t)row * 224 + t;
    const float v = (float)h[i] * sc + sh;
    h[i] = (_Float16)(v > 0.f ? v : 0.f);
}

// ---------------------------------------------------------------------------
// aa_kernel: row squared-norms of f16 features [row][224] (pad is zero).
// ---------------------------------------------------------------------------
__global__ __launch_bounds__(256) void aa_kernel(
    const _Float16* __restrict__ fX, const _Float16* __restrict__ fY,
    float* __restrict__ aaX, float* __restrict__ aaY)
{
    const int wave = threadIdx.x >> 6, lane = threadIdx.x & 63;
    const int R = blockIdx.x * 4 + wave;
    const _Float16* f = (R < 8192) ? fX : fY;
    const int r = R & 8191;
    const _Float16* row = f + (size_t)r * 224;
    float s = 0.f;
    if (lane < 56) {
        const half4v v = *(const half4v*)(row + lane * 4);
#pragma unroll
        for (int k = 0; k < 4; ++k) { const float x = (float)v[k]; s += x * x; }
    }
#pragma unroll
    for (int off = 32; off > 0; off >>= 1) s += __shfl_xor(s, off);
    if (lane == 0) ((R < 8192) ? aaX : aaY)[r] = s;
}

// ---------------------------------------------------------------------------
// cost_kernel v2: MFMA GEMM on f16 features (K padded to 224, zeros).
// Symmetric mats (xx,yy): upper tiles only, mirror-write.
// M = f16( min(50 * max(aa[n]+bb[m]-2<p,q>, 0), 65000) ) == 100*C
// ---------------------------------------------------------------------------
__global__ __launch_bounds__(256) void cost_kernel(
    const _Float16* __restrict__ fX, const _Float16* __restrict__ fY,
    const float* __restrict__ aaX, const float* __restrict__ aaY,
    _Float16* __restrict__ Cxy, _Float16* __restrict__ Cxx,
    _Float16* __restrict__ Cyy, _Float16* __restrict__ CTxy)
{
    const int z = blockIdx.y;
    const int mat = z >> 4, b = z & 15;
    const int nt = blockIdx.x & 3, mt = blockIdx.x >> 2;
    if (mat != 0 && nt > mt) return;
    const _Float16 *P, *Q; const float *aP, *aQ;
    _Float16 *Cm, *CT;
    if (mat == 0)      { P = fX; Q = fY; aP = aaX; aQ = aaY; Cm = Cxy; CT = CTxy; }
    else if (mat == 1) { P = fX; Q = fX; aP = aaX; aQ = aaX; Cm = Cxx; CT = (nt < mt) ? Cxx : nullptr; }
    else               { P = fY; Q = fY; aP = aaY; aQ = aaY; Cm = Cyy; CT = (nt < mt) ? Cyy : nullptr; }

    const int tid = threadIdx.x, lane = tid & 63, wv = tid >> 6;
    const int m16 = lane & 15, quad = lane >> 4;
    const int wv2 = wv >> 1, wvt = wv & 1;
    const int nb = nt * 128 + wv2 * 64;
    const int mb = mt * 128 + wvt * 64;
    const _Float16* Pb = P + (size_t)b * 512 * 224;
    const _Float16* Qb = Q + (size_t)b * 512 * 224;

    float4v acc[4][4];
#pragma unroll
    for (int i = 0; i < 4; ++i)
#pragma unroll
        for (int j = 0; j < 4; ++j) acc[i][j] = (float4v){0.f, 0.f, 0.f, 0.f};

    for (int k32 = 0; k32 < 7; ++k32) {
        const int ko = k32 * 32 + quad * 8;
        half8v a4[4], b4[4];
#pragma unroll
        for (int i = 0; i < 4; ++i)
            a4[i] = *(const half8v*)(Pb + (size_t)(nb + i * 16 + m16) * 224 + ko);
#pragma unroll
        for (int j = 0; j < 4; ++j)
            b4[j] = *(const half8v*)(Qb + (size_t)(mb + j * 16 + m16) * 224 + ko);
#pragma unroll
        for (int i = 0; i < 4; ++i)
#pragma unroll
            for (int j = 0; j < 4; ++j)
                acc[i][j] = __builtin_amdgcn_mfma_f32_16x16x32_f16(a4[i], b4[j], acc[i][j], 0, 0, 0);
    }

#pragma unroll
    for (int i = 0; i < 4; ++i) {
        const int nrow0 = nb + i * 16 + quad * 4;
        float aa4[4];
#pragma unroll
        for (int r = 0; r < 4; ++r) aa4[r] = aP[b * 512 + nrow0 + r];
#pragma unroll
        for (int j = 0; j < 4; ++j) {
            const int mcol = mb + j * 16 + m16;
            const float bbm = aQ[b * 512 + mcol];
#pragma unroll
            for (int r = 0; r < 4; ++r) {
                const int n = nrow0 + r;
                float c = 50.f * fmaxf(aa4[r] + bbm - 2.f * acc[i][j][r], 0.f);
                c = fminf(c, 65000.f);
                const _Float16 ch = (_Float16)c;
                Cm[((size_t)(b * 512 + n)) * 512 + mcol] = ch;
                if (CT) CT[((size_t)(b * 512 + mcol)) * 512 + n] = ch;
            }
        }
    }
}

// ---------------------------------------------------------------------------
// Per-row half-update (two-pass max-then-sum; __expf = native v_exp_f32.
// NOTE: bare exp2f/log2f regressed ~120us total (rounds 9/10) -- precise-OCML
// lowering; keep __expf/logf).
// dst[p*512+i] = eps*log512 - eps*LSE_j( 400*src[j] - 4*M100[i,j] )
// ---------------------------------------------------------------------------
static __device__ __forceinline__ void sink_rows(
    float* __restrict__ dst, const float* __restrict__ src,
    const _Float16* __restrict__ Mb, int p, int i0, int lane)
{
    const float* sp = src + (size_t)p * 512;
    float s8[8];
    {
        const float4 sa = *(const float4*)&sp[lane * 8];
        const float4 sb = *(const float4*)&sp[lane * 8 + 4];
        s8[0]=sa.x*400.f; s8[1]=sa.y*400.f; s8[2]=sa.z*400.f; s8[3]=sa.w*400.f;
        s8[4]=sb.x*400.f; s8[5]=sb.y*400.f; s8[6]=sb.z*400.f; s8[7]=sb.w*400.f;
    }
#pragma unroll
    for (int rr = 0; rr < 4; ++rr) {
        const int i = i0 + rr;
        const half8v rv = *(const half8v*)(Mb + (size_t)i * 512 + lane * 8);
        float a8[8];
#pragma unroll
        for (int k = 0; k < 8; ++k) a8[k] = fmaf(-4.f, (float)rv[k], s8[k]);
        float mx = a8[0];
#pragma unroll
        for (int k = 1; k < 8; ++k) mx = fmaxf(mx, a8[k]);
        // wave-global max (fmax butterfly, no exps)
#pragma unroll
        for (int off = 32; off > 0; off >>= 1) mx = fmaxf(mx, __shfl_xor(mx, off));
        // sum of exp(a - global max)
        float ss = 0.f;
#pragma unroll
        for (int k = 0; k < 8; ++k) ss += __expf(a8[k] - mx);
#pragma unroll
        for (int off = 32; off > 0; off >>= 1) ss += __shfl_xor(ss, off);
        if (lane == 0)
            dst[(size_t)p * 512 + i] = EPS_LOG512 - EPS_SINK * (mx + logf(ss));
    }
}

// ---------------------------------------------------------------------------
// sink_update: one half-update per launch; grid (32,48), 256 thr.
// ---------------------------------------------------------------------------
__global__ __launch_bounds__(256) void sink_update(
    float* __restrict__ dst, const float* __restrict__ src,
    const _Float16* __restrict__ M0, const _Float16* __restrict__ M1,
    const _Float16* __restrict__ M2)
{
    const int p = blockIdx.y;
    const int mat = p >> 4, b = p & 15;
    const _Float16* M = ((mat == 0) ? M0 : ((mat == 1) ? M1 : M2)) + (size_t)b * 512 * 512;
    const int wave = threadIdx.x >> 6, lane = threadIdx.x & 63;
    const int i0 = blockIdx.x * 16 + wave * 4;
    sink_rows(dst, src, M, p, i0, lane);
}

// ---------------------------------------------------------------------------
__global__ __launch_bounds__(256) void final_kernel(
    const float* __restrict__ f, const float* __restrict__ g,
    float* __restrict__ out)
{
    const int b = blockIdx.x, tid = threadIdx.x;
    __shared__ float red[256];
    float a = 0.f;
    for (int n = tid; n < 512; n += 256) {
        const float xy = f[(0 * 16 + b) * 512 + n] + g[(0 * 16 + b) * 512 + n];
        const float xx = f[(1 * 16 + b) * 512 + n] + g[(1 * 16 + b) * 512 + n];
        const float yy = f[(2 * 16 + b) * 512 + n] + g[(2 * 16 + b) * 512 + n];
        a += xy - 0.5f * (xx + yy);
    }
    red[tid] = a;
    __syncthreads();
    for (int s2 = 128; s2 > 0; s2 >>= 1) {
        if (tid < s2) red[tid] += red[tid + s2];
        __syncthreads();
    }
    if (tid == 0) out[b] = red[0] * (1.0f / 512.0f);
}

// ---------------------------------------------------------------------------
extern "C" void kernel_launch(void* const* d_in, const int* in_sizes, int n_in,
                              void* d_out, int out_size, void* d_ws, size_t ws_size,
                              hipStream_t stream)
{
    (void)in_sizes; (void)n_in; (void)out_size; (void)ws_size;
    char* ws = (char*)d_ws;
    const float* yhat = (const float*)d_in[0];
    const float* ysig = (const float*)d_in[1];
    const float* Wl[5]; const float* gl[5]; const float* bl[5];
    for (int i = 0; i < 5; ++i) {
        Wl[i] = (const float*)d_in[2 + 3 * i];
        gl[i] = (const float*)d_in[3 + 3 * i];
        bl[i] = (const float*)d_in[4 + 3 * i];
    }
    float* out = (float*)d_out;
    float* statsA = (float*)(ws + O_STATS);

    _Float16* w1 = (_Float16*)(ws + O_W1);
    _Float16* w2 = (_Float16*)(ws + O_W2);
    _Float16* w3 = (_Float16*)(ws + O_W3);
    _Float16* w4 = (_Float16*)(ws + O_W4);
    _Float16* h0  = (_Float16*)(ws + O_H0);
    _Float16* h1  = (_Float16*)(ws + O_H1);
    _Float16* h2X = (_Float16*)(ws + O_H2X);
    _Float16* h2Y = (_Float16*)(ws + O_H2Y);
    _Float16* h3X = (_Float16*)(ws + O_H3X);
    _Float16* h3Y = (_Float16*)(ws + O_H3Y);
    _Float16* featX = (_Float16*)(ws + O_FEATX);
    _Float16* featY = (_Float16*)(ws + O_FEATY);
    float* stX = statsA;           // signal X stats (160 floats)
    float* stY = statsA + 160;     // signal Y stats

    hipMemsetAsync(statsA, 0, 512 * sizeof(float), stream);
    prep_w<<<dim3(1024, 4), 256, 0, stream>>>(Wl[1], Wl[2], Wl[3], Wl[4],
        w1, w2, w3, w4);

    // --- X pipeline through conv2 (h0 is per-signal scratch)
    conv0_store<<<dim3(13, 4, 16), 256, 0, stream>>>(yhat, Wl[0], h0, stX);
    conv1_mfma<<<dim3(832), 256, 0, stream>>>(
        h0, w1, stX, gl[0], bl[0], h1, stX + 32);
    conv_mfma<true><<<dim3(832, 1), 256, 0, stream>>>(
        h1, h1, w2, stX + 32, stX + 32, gl[1], bl[1],
        h2X, h2X, nullptr, nullptr, stX + 64, stX + 64, 1598, 798, 13);

    // --- Y pipeline through conv2
    conv0_store<<<dim3(13, 4, 16), 256, 0, stream>>>(ysig, Wl[0], h0, stY);
    conv1_mfma<<<dim3(832), 256, 0, stream>>>(
        h0, w1, stY, gl[0], bl[0], h1, stY + 32);
    conv_mfma<true><<<dim3(832, 1), 256, 0, stream>>>(
        h1, h1, w2, stY + 32, stY + 32, gl[1], bl[1],
        h2Y, h2Y, nullptr, nullptr, stY + 64, stY + 64, 1598, 798, 13);

    // --- batched conv3 (both signals; 896 blocks)
    conv_mfma<true><<<dim3(448, 2), 256, 0, stream>>>(
        h2X, h2Y, w3, stX + 64, stY + 64, gl[2], bl[2],
        h3X, h3Y, nullptr, nullptr, stX + 96, stY + 96, 798, 398, 7);

    // --- batched conv4 (both signals; 512 blocks; self-zeroes K-pad cols)
    conv_mfma<false><<<dim3(256, 2), 256, 0, stream>>>(
        h3X, h3Y, w4, stX + 96, stY + 96, gl[3], bl[3],
        nullptr, nullptr, featX, featY, stX + 128, stY + 128, 398, 198, 4);

    // --- batched norm_feat
    norm_feat<<<dim3(1, 16384), 256, 0, stream>>>(
        featX, featY, stX + 128, stY + 128, gl[4], bl[4]);

    aa_kernel<<<4096, 256, 0, stream>>>(featX, featY, (float*)(ws + O_AAX), (float*)(ws + O_AAY));
    cost_kernel<<<dim3(16, 48), 256, 0, stream>>>(
        featX, featY, (float*)(ws + O_AAX), (float*)(ws + O_AAY),
        (_Float16*)(ws + O_CXY), (_Float16*)(ws + O_CXX), (_Float16*)(ws + O_CYY),
        (_Float16*)(ws + O_CTXY));

    hipMemsetAsync(ws + O_F, 0, 2 * 24576 * sizeof(float), stream);

    float* fptr = (float*)(ws + O_F);
    float* gptr = (float*)(ws + O_G);
    _Float16* cxy  = (_Float16*)(ws + O_CXY);
    _Float16* ctxy = (_Float16*)(ws + O_CTXY);
    _Float16* cxx  = (_Float16*)(ws + O_CXX);
    _Float16* cyy  = (_Float16*)(ws + O_CYY);

    for (int it = 0; it < 50; ++it) {
        sink_update<<<dim3(32, 48), 256, 0, stream>>>(gptr, fptr, ctxy, cxx, cyy);
        sink_update<<<dim3(32, 48), 256, 0, stream>>>(fptr, gptr, cxy, cxx, cyy);
    }

    final_kernel<<<16, 256, 0, stream>>>(fptr, gptr, out);
}

// Round 15
// 1543.732 us; speedup vs baseline: 1.1652x; 1.0201x over previous
//
#include <hip/hip_runtime.h>

typedef unsigned int uint;
typedef unsigned short ushort;
using half8v  = __attribute__((ext_vector_type(8))) _Float16;
using half4v  = __attribute__((ext_vector_type(4))) _Float16;
using float4v = __attribute__((ext_vector_type(4))) float;

#define EPS_SINK 0.0025f
#define EPS_LOG512 0.015595811562598769f

// ---- workspace layout (BYTE offsets), peak ~161.1 MB ----
// conv phase:
static const size_t O_W1   = 0ull;             // 4,194,304
static const size_t O_W2   = 4194304ull;       // 2,097,152 each
static const size_t O_W3   = 6291456ull;
static const size_t O_W4   = 8388608ull;       // ends 10,485,760
static const size_t O_H2X  = 10485760ull;      // 13,074,432 -> 23,560,192 (outside h0)
static const size_t O_H3X  = 23560192ull;      //  6,516,736 -> 30,076,928
static const size_t O_H0   = 30076928ull;      // 104,857,600 -> 134,934,528
static const size_t O_H2Y  = 30076928ull;      // alias h0 (dead after conv1(Y))
static const size_t O_H3Y  = 43151360ull;      // -> 49,668,096 (inside h0 span)
static const size_t O_H1   = 134934528ull;     // 26,181,632 -> 161,116,160 (X then Y)
static const size_t O_FEATX= 134934528ull;     // overlays dead h1; 3,670,016
static const size_t O_FEATY= 138604544ull;     // -> 142,274,560
static const size_t O_STATS= 161116160ull;     // 512 floats
// cost phase (weights/h0/h1/h2/h3 all dead).  C stored f16, value = 100*C:
static const size_t O_CXY  = 0ull;             // 8,388,608 each
static const size_t O_CTXY = 8388608ull;
static const size_t O_CXX  = 16777216ull;
static const size_t O_CYY  = 25165824ull;
static const size_t O_AAX  = 33554432ull;
static const size_t O_AAY  = 33587200ull;
static const size_t O_F    = 33619968ull;      // 3*16*512 fp32
static const size_t O_G    = 33718272ull;

#define GLOAD_LDS16(gp, lp) __builtin_amdgcn_global_load_lds( \
    (const __attribute__((address_space(1))) void*)(gp),       \
    (__attribute__((address_space(3))) void*)(lp), 16, 0, 0)

// ---------------------------------------------------------------------------
// prep_w: convert conv weights fp32 -> single f16. W1 [oc][ic][8 taps];
// W2-4 pair-interleaved [oc][icpair][dt0 icA, dt0 icB, dt1 icA, ...].
// ---------------------------------------------------------------------------
__global__ __launch_bounds__(256) void prep_w(
    const float* __restrict__ W1, const float* __restrict__ W2,
    const float* __restrict__ W3, const float* __restrict__ W4,
    _Float16* __restrict__ w1, _Float16* __restrict__ w2,
    _Float16* __restrict__ w3, _Float16* __restrict__ w4)
{
    const int layer = blockIdx.y;
    const int e = blockIdx.x * 256 + threadIdx.x;
    float v[8];
    _Float16* dh;
    if (layer == 0) {
        const float4 a = *(const float4*)(W1 + (size_t)e * 8);
        const float4 c = *(const float4*)(W1 + (size_t)e * 8 + 4);
        v[0]=a.x; v[1]=a.y; v[2]=a.z; v[3]=a.w; v[4]=c.x; v[5]=c.y; v[6]=c.z; v[7]=c.w;
        dh = w1;
    } else {
        if (e >= 131072) return;
        const float* W = (layer == 1) ? W2 : (layer == 2) ? W3 : W4;
        dh = (layer == 1) ? w2 : (layer == 2) ? w3 : w4;
        const int oc = e >> 8, icp = e & 255;
        const float4 a = *(const float4*)(W + ((size_t)oc * 512 + icp * 2) * 4);
        const float4 c = *(const float4*)(W + ((size_t)oc * 512 + icp * 2 + 1) * 4);
        v[0]=a.x; v[1]=c.x; v[2]=a.y; v[3]=c.y; v[4]=a.z; v[5]=c.z; v[6]=a.w; v[7]=c.w;
    }
    half8v hi;
#pragma unroll
    for (int k = 0; k < 8; ++k) hi[k] = (_Float16)v[k];
    *(half8v*)(dh + (size_t)e * 8) = hi;
}

// ---------------------------------------------------------------------------
// conv0_store v4: raw conv0 (k=10,s=5) -> h0 f16 [b][512][6400] + GN stats.
// Input window staged in LDS with +1/40 PAD (stride-41 reads: gcd(41,32)=1 ->
// conflict-free; v3's stride-40 reads were 16-way = 1.57M conflicts).
// Each thread owns 8 consecutive t, emits one half8 store per oc.
// ---------------------------------------------------------------------------
__global__ __launch_bounds__(256) void conv0_store(
    const float* __restrict__ wav, const float* __restrict__ W0,
    _Float16* __restrict__ h0, float* __restrict__ stats)
{
    __shared__ float LX[2640];                 // 2565 + pad(e/40)
    __shared__ float LW[1280];
    __shared__ float red[2][256];
    const int tid = threadIdx.x;
    const int ocq = blockIdx.y;                // 0..3, 128-oc chunk
    const int oc0 = ocq * 128;
    const int b   = blockIdx.z;
    const int t0  = blockIdx.x * 512;
    const int w0  = t0 * 5;

    for (int e = tid; e < 1280; e += 256) LW[e] = W0[oc0 * 10 + e];
    const float* wb = wav + (size_t)b * 32000;
    for (int e = tid; e < 2565; e += 256)
        LX[e + e / 40] = (w0 + e < 32000) ? wb[w0 + e] : 0.f;
    __syncthreads();

    const int lane6 = tid & 63;                // t8-group index within block
    const int wvi   = tid >> 6;                // 0..3
    const int t1    = t0 + lane6 * 8;          // first t of this thread's group
    const bool doS  = (t1 + 8 <= 6400);        // group fully within row
    float x[50];
    if (doS) {
#pragma unroll
        for (int j = 0; j < 50; ++j) x[j] = LX[lane6 * 41 + j + (j >= 40 ? 1 : 0)];
    }

    float lsum = 0.f, lsq = 0.f;
    _Float16* hb = h0 + ((size_t)b * 512 + oc0) * 6400;
    if (doS) {
        for (int r = 0; r < 32; ++r) {
            const int oc = wvi + 4 * r;        // wave-uniform
            float w[10];
#pragma unroll
            for (int d = 0; d < 10; ++d) w[d] = LW[oc * 10 + d];
            half8v hv;
#pragma unroll
            for (int k = 0; k < 8; ++k) {
                float a = 0.f;
#pragma unroll
                for (int d = 0; d < 10; ++d) a = fmaf(w[d], x[k * 5 + d], a);
                hv[k] = (_Float16)a;
                if (t1 + k < 6399) { lsum += a; lsq += a * a; }
            }
            *(half8v*)(hb + (size_t)oc * 6400 + t1) = hv;
        }
    }
    red[0][tid] = lsum; red[1][tid] = lsq;
    __syncthreads();
    for (int s2 = 128; s2 > 0; s2 >>= 1) {
        if (tid < s2) { red[0][tid] += red[0][tid + s2]; red[1][tid] += red[1][tid + s2]; }
        __syncthreads();
    }
    if (tid == 0) {
        atomicAdd(&stats[2 * b], red[0][0]);
        atomicAdd(&stats[2 * b + 1], red[1][0]);
    }
}

// ---------------------------------------------------------------------------
// conv1_mfma v6: layer1 (K=8,S=4), 128oc x 128t tile + FUSED GN0 affine+ReLU
// on the X-load path. LDS 38 KB -> 4 blocks/CU.
// ---------------------------------------------------------------------------
__global__ __launch_bounds__(256, 4) void conv1_mfma(
    const _Float16* __restrict__ h0,
    const _Float16* __restrict__ w1,
    const float* __restrict__ stats0,
    const float* __restrict__ gamma0, const float* __restrict__ beta0,
    _Float16* __restrict__ oh, float* __restrict__ stats1)
{
    __shared__ _Float16 LW[2][2][4][128][8];   // 32 KB [buf][k32l][q][oc][8]
    __shared__ float LSC[512], LSH[512];       // 4 KB GN0 fold tables
    __shared__ float red[2][256];

    const int tid  = threadIdx.x;
    const int lane = tid & 63, wv = tid >> 6;
    const int m    = lane & 15, quad = lane >> 4;
    const int wv2  = wv >> 1, wvt = wv & 1;

    // chunked XCD swizzle: 832 blocks = 8 chunks of 104; y (oc-tile) fastest
    const int raw = blockIdx.x;
    const int cid = (raw & 7) * 104 + (raw >> 3);
    const int b   = cid / 52;
    const int r2  = cid - b * 52;
    const int xt  = r2 >> 2, yt = r2 & 3;
    const int ocb = yt * 128;
    const int t0  = xt * 128;
    const int Lout = 1598;

    // --- GN0 fold tables (stats0 complete at launch boundary)
    {
        const float invN = 1.f / (512.f * 6399.f);
        const float mu = stats0[2 * b] * invN;
        const float var = stats0[2 * b + 1] * invN - mu * mu;
        const float rs = rsqrtf(var + 1e-5f);
        for (int ic = tid; ic < 512; ic += 256) {
            const float sc = rs * gamma0[ic];
            LSC[ic] = sc;
            LSH[ic] = beta0[ic] - mu * sc;
        }
    }

    float4v acc[4][4];
#pragma unroll
    for (int i = 0; i < 4; ++i)
#pragma unroll
        for (int j = 0; j < 4; ++j) acc[i][j] = (float4v){0.f, 0.f, 0.f, 0.f};

    const _Float16* hb = h0 + (size_t)b * 512 * 6400;
    const int gbase = t0 * 4;
    const _Float16* px = hb + (size_t)quad * 6400 + gbase + (wvt * 64 + m) * 4;

    const _Float16* wsrc[4];
#pragma unroll
    for (int r = 0; r < 4; ++r) {
        const int e = wv * 4 + r;
        const int oh2 = e & 1, q = (e >> 1) & 3, k32l = e >> 3;
        wsrc[r] = w1 + ((size_t)(ocb + oh2 * 64 + lane) * 512 + (k32l * 4 + q)) * 8;
    }
    auto stageW = [&](int buf) {
#pragma unroll
        for (int r = 0; r < 4; ++r) {
            const int e = wv * 4 + r;
            const int oh2 = e & 1, q = (e >> 1) & 3, k32l = e >> 3;
            GLOAD_LDS16(wsrc[r], &LW[buf][k32l][q][oh2 * 64][0]);
            wsrc[r] += 64;                     // 8 ic * 8 taps
        }
    };

    stageW(0);
    __syncthreads();

    for (int it = 0; it < 64; ++it) {
        const int buf = it & 1;
        if (it < 63) stageW(buf ^ 1);
#pragma unroll
        for (int k32l = 0; k32l < 2; ++k32l) {
            half8v a4[4], bfv[4];
#pragma unroll
            for (int i = 0; i < 4; ++i)
                a4[i] = *(const half8v*)&LW[buf][k32l][quad][wv2 * 64 + i * 16 + m][0];
            const int ic = quad + 4 * k32l + 8 * it;
            const _Float16 sch = (_Float16)LSC[ic];
            const _Float16 shh = (_Float16)LSH[ic];
            const _Float16* pr = px + (size_t)k32l * 25600;   // +4 rows
#pragma unroll
            for (int j = 0; j < 4; ++j) {
                half8v xv = *(const half8v*)(pr + j * 64);
#pragma unroll
                for (int k = 0; k < 8; ++k) {
                    const _Float16 v = xv[k] * sch + shh;
                    xv[k] = (v > (_Float16)0.f) ? v : (_Float16)0.f;
                }
                bfv[j] = xv;
            }
#pragma unroll
            for (int i = 0; i < 4; ++i)
#pragma unroll
                for (int j = 0; j < 4; ++j)
                    acc[i][j] = __builtin_amdgcn_mfma_f32_16x16x32_f16(a4[i], bfv[j], acc[i][j], 0, 0, 0);
        }
        px += 51200;                           // +8 rows
        __syncthreads();
    }

    // --- epilogue: pack f16 pairs + stats (RAW conv1 outputs, pre-GN1)
    float lsum = 0.f, lsq = 0.f;
    uint* ohU = (uint*)oh;
#pragma unroll
    for (int i = 0; i < 4; ++i) {
        const int ocb2 = ocb + wv2 * 64 + i * 16 + quad * 4;
#pragma unroll
        for (int j = 0; j < 4; ++j) {
            const int t = t0 + wvt * 64 + j * 16 + m;
            if (t < Lout) {
#pragma unroll
                for (int pr = 0; pr < 2; ++pr) {
                    const float v0 = acc[i][j][pr * 2], v1 = acc[i][j][pr * 2 + 1];
                    union { uint u; _Float16 h[2]; } pk;
                    pk.h[0] = (_Float16)v0; pk.h[1] = (_Float16)v1;
                    const uint p = (uint)((ocb2 >> 1) + pr);
                    ohU[((size_t)(b * 256 + p)) * Lout + t] = pk.u;
                    lsum += v0 + v1; lsq += v0 * v0 + v1 * v1;
                }
            }
        }
    }
    red[0][tid] = lsum; red[1][tid] = lsq;
    __syncthreads();
    for (int s2 = 128; s2 > 0; s2 >>= 1) {
        if (tid < s2) { red[0][tid] += red[0][tid + s2]; red[1][tid] += red[1][tid + s2]; }
        __syncthreads();
    }
    if (tid == 0) {
        atomicAdd(&stats1[2 * b], red[0][0]);
        atomicAdd(&stats1[2 * b + 1], red[1][0]);
    }
}

// ---------------------------------------------------------------------------
// conv_mfma v6: layers 2-4 (K=4,S=2). 128oc x 64t tile, register dbuf X
// prefetch + FUSED prev-layer GN affine+ReLU. SIGNAL-BATCHED via blockIdx.y.
// PAIRED: f16 pair-interleaved out; else f16 features [ch][224] incl.
// self-zeroed K-pad cols 198..223.
// ---------------------------------------------------------------------------
template <bool PAIRED>
__global__ __launch_bounds__(256, 4) void conv_mfma(
    const _Float16* __restrict__ x0s, const _Float16* __restrict__ x1s,
    const _Float16* __restrict__ w,
    const float* __restrict__ statsP0, const float* __restrict__ statsP1,
    const float* __restrict__ gammaP, const float* __restrict__ betaP,
    _Float16* __restrict__ oh0, _Float16* __restrict__ oh1,
    _Float16* __restrict__ of0, _Float16* __restrict__ of1,
    float* __restrict__ statsO0, float* __restrict__ statsO1,
    int Lin, int Lout, int nx)
{
    __shared__ _Float16 LW[2][2][4][128][8];   // 32 KB
    __shared__ float LN[256][4];               // sc0,sh0,sc1,sh1 per pair, 4 KB
    __shared__ float red[2][256];

    const int sig = blockIdx.y;
    const _Float16* x       = sig ? x1s : x0s;
    const float*    statsP  = sig ? statsP1 : statsP0;
    _Float16*       oh      = sig ? oh1 : oh0;
    _Float16*       ofeat   = sig ? of1 : of0;
    float*          statsO  = sig ? statsO1 : statsO0;

    const int tid  = threadIdx.x;
    const int lane = tid & 63, wv = tid >> 6;
    const int m    = lane & 15, quad = lane >> 4;
    const int wv2  = wv >> 1, wvt = wv & 1;

    // chunked XCD swizzle (nwg = nx*64, always % 8 == 0), y fastest in chunk
    const int raw = blockIdx.x;
    const int chunk = (nx * 64) >> 3;
    const int cid = (raw & 7) * chunk + (raw >> 3);
    const int perb = nx * 4;
    const int b   = cid / perb;
    const int r2  = cid - b * perb;
    const int xt  = r2 >> 2, yt = r2 & 3;
    const int ocb = yt * 128;
    const int t0  = xt * 64;

    // --- prev-layer GN fold tables
    {
        const float invN = 1.f / (512.f * (float)Lin);
        const float mu = statsP[2 * b] * invN;
        const float var = statsP[2 * b + 1] * invN - mu * mu;
        const float rs = rsqrtf(var + 1e-5f);
        const int c0 = 2 * tid, c1 = 2 * tid + 1;
        const float sc0 = rs * gammaP[c0], sc1 = rs * gammaP[c1];
        LN[tid][0] = sc0; LN[tid][1] = betaP[c0] - mu * sc0;
        LN[tid][2] = sc1; LN[tid][3] = betaP[c1] - mu * sc1;
    }

    float4v acc[4][2];
#pragma unroll
    for (int i = 0; i < 4; ++i)
#pragma unroll
        for (int j = 0; j < 2; ++j) acc[i][j] = (float4v){0.f, 0.f, 0.f, 0.f};

    const size_t rstride = (size_t)Lin * 2;
    const _Float16* px = x + ((size_t)(b * 256) + quad) * rstride
                           + t0 * 4 + (wvt * 32 + m) * 4;

    const _Float16* wsrc[4];
#pragma unroll
    for (int r = 0; r < 4; ++r) {
        const int e = wv * 4 + r;
        const int oh2 = e & 1, q = (e >> 1) & 3, k32l = e >> 3;
        wsrc[r] = w + ((size_t)(ocb + oh2 * 64 + lane) * 256 + (k32l * 4 + q)) * 8;
    }
    auto stageW = [&](int buf) {
#pragma unroll
        for (int r = 0; r < 4; ++r) {
            const int e = wv * 4 + r;
            const int oh2 = e & 1, q = (e >> 1) & 3, k32l = e >> 3;
            GLOAD_LDS16(wsrc[r], &LW[buf][k32l][q][oh2 * 64][0]);
            wsrc[r] += 64;                     // 8 icp * 8
        }
    };
    auto loadX = [&](half8v (&xr)[4], const _Float16* p) {
#pragma unroll
        for (int k32l = 0; k32l < 2; ++k32l)
#pragma unroll
            for (int j = 0; j < 2; ++j)
                xr[k32l * 2 + j] = *(const half8v*)(p + (size_t)k32l * 4 * rstride + j * 64);
    };
    auto compute = [&](int buf, half8v (&xr)[4], int plB) {
#pragma unroll
        for (int k32l = 0; k32l < 2; ++k32l) {
            half8v a4[4];
#pragma unroll
            for (int i = 0; i < 4; ++i)
                a4[i] = *(const half8v*)&LW[buf][k32l][quad][wv2 * 64 + i * 16 + m][0];
            const int pl = plB + quad + 4 * k32l;
            const _Float16 s0 = (_Float16)LN[pl][0], h0v = (_Float16)LN[pl][1];
            const _Float16 s1 = (_Float16)LN[pl][2], h1v = (_Float16)LN[pl][3];
            half8v xn[2];
#pragma unroll
            for (int j = 0; j < 2; ++j) {
                half8v xv = xr[k32l * 2 + j];
#pragma unroll
                for (int k = 0; k < 8; ++k) {
                    const _Float16 v = xv[k] * ((k & 1) ? s1 : s0) + ((k & 1) ? h1v : h0v);
                    xv[k] = (v > (_Float16)0.f) ? v : (_Float16)0.f;
                }
                xn[j] = xv;
            }
#pragma unroll
            for (int i = 0; i < 4; ++i)
#pragma unroll
                for (int j = 0; j < 2; ++j)
                    acc[i][j] = __builtin_amdgcn_mfma_f32_16x16x32_f16(a4[i], xn[j], acc[i][j], 0, 0, 0);
        }
    };

    half8v xrA[4], xrB[4];
    loadX(xrA, px); px += 8 * rstride;         // iter 0
    stageW(0);
    __syncthreads();

    for (int it = 0; it < 32; it += 2) {
        stageW(1);
        loadX(xrB, px); px += 8 * rstride;     // iter it+1
        compute(0, xrA, 8 * it);
        __syncthreads();
        if (it + 2 < 32) {
            stageW(0);
            loadX(xrA, px);                    // iter it+2
        }
        px += 8 * rstride;
        compute(1, xrB, 8 * (it + 1));
        __syncthreads();
    }

    // --- epilogue (RAW conv outputs, pre-GN)
    float lsum = 0.f, lsq = 0.f;
    uint* ohU = (uint*)oh;
#pragma unroll
    for (int i = 0; i < 4; ++i) {
        const int ocb2 = ocb + wv2 * 64 + i * 16 + quad * 4;
#pragma unroll
        for (int j = 0; j < 2; ++j) {
            const int t = t0 + wvt * 32 + j * 16 + m;
            if (PAIRED) {
                if (t < Lout) {
#pragma unroll
                    for (int pr = 0; pr < 2; ++pr) {
                        const float v0 = acc[i][j][pr * 2], v1 = acc[i][j][pr * 2 + 1];
                        union { uint u; _Float16 h[2]; } pk;
                        pk.h[0] = (_Float16)v0; pk.h[1] = (_Float16)v1;
                        const uint p = (uint)((ocb2 >> 1) + pr);
                        ohU[((size_t)(b * 256 + p)) * Lout + t] = pk.u;
                        lsum += v0 + v1; lsq += v0 * v0 + v1 * v1;
                    }
                }
            } else {
                // features [ch][224]; write K-pad zeros for t in [Lout,224)
                if (t < 224) {
#pragma unroll
                    for (int r = 0; r < 4; ++r) {
                        const float v = acc[i][j][r];
                        ofeat[((size_t)(b * 512 + ocb2 + r)) * 224 + t] =
                            (t < Lout) ? (_Float16)v : (_Float16)0.f;
                        if (t < Lout) { lsum += v; lsq += v * v; }
                    }
                }
            }
        }
    }
    red[0][tid] = lsum; red[1][tid] = lsq;
    __syncthreads();
    for (int s2 = 128; s2 > 0; s2 >>= 1) {
        if (tid < s2) { red[0][tid] += red[0][tid + s2]; red[1][tid] += red[1][tid + s2]; }
        __syncthreads();
    }
    if (tid == 0) {
        atomicAdd(&statsO[2 * b], red[0][0]);
        atomicAdd(&statsO[2 * b + 1], red[1][0]);
    }
}

// ---------------------------------------------------------------------------
// norm_feat: GN+affine+ReLU in place on f16 features [row][224], t<198.
// Signal-batched: blockIdx.y in [0,16384): bit 13 selects signal.
// ---------------------------------------------------------------------------
__global__ __launch_bounds__(256) void norm_feat(
    _Float16* __restrict__ hX, _Float16* __restrict__ hY,
    const float* __restrict__ statsX, const float* __restrict__ statsY,
    const float* __restrict__ gamma, const float* __restrict__ beta)
{
    const int row0 = blockIdx.y;
    const int sig = row0 >> 13;
    const int row = row0 & 8191;
    _Float16* h = sig ? hY : hX;
    const float* stats = sig ? statsY : statsX;
    const int b = row >> 9, oc = row & 511;
    const int t = threadIdx.x;
    if (t >= 198) return;
    const float invN = 1.f / (512.f * 198.f);
    const float mu = stats[2 * b] * invN;
    const float var = stats[2 * b + 1] * invN - mu * mu;
    const float rs = rsqrtf(var + 1e-5f);
    const float sc = rs * gamma[oc];
    const float sh = beta[oc] - mu * sc;
    const size_t i = (size_t)row * 224 + t;
    const float v = (float)h[i] * sc + sh;
    h[i] = (_Float16)(v > 0.f ? v : 0.f);
}

// ---------------------------------------------------------------------------
// aa_kernel: row squared-norms of f16 features [row][224] (pad is zero).
// ---------------------------------------------------------------------------
__global__ __launch_bounds__(256) void aa_kernel(
    const _Float16* __restrict__ fX, const _Float16* __restrict__ fY,
    float* __restrict__ aaX, float* __restrict__ aaY)
{
    const int wave = threadIdx.x >> 6, lane = threadIdx.x & 63;
    const int R = blockIdx.x * 4 + wave;
    const _Float16* f = (R < 8192) ? fX : fY;
    const int r = R & 8191;
    const _Float16* row = f + (size_t)r * 224;
    float s = 0.f;
    if (lane < 56) {
        const half4v v = *(const half4v*)(row + lane * 4);
#pragma unroll
        for (int k = 0; k < 4; ++k) { const float x = (float)v[k]; s += x * x; }
    }
#pragma unroll
    for (int off = 32; off > 0; off >>= 1) s += __shfl_xor(s, off);
    if (lane == 0) ((R < 8192) ? aaX : aaY)[r] = s;
}

// ---------------------------------------------------------------------------
// cost_kernel v2: MFMA GEMM on f16 features (K padded to 224, zeros).
// Symmetric mats (xx,yy): upper tiles only, mirror-write.
// M = f16( min(50 * max(aa[n]+bb[m]-2<p,q>, 0), 65000) ) == 100*C
// ---------------------------------------------------------------------------
__global__ __launch_bounds__(256) void cost_kernel(
    const _Float16* __restrict__ fX, const _Float16* __restrict__ fY,
    const float* __restrict__ aaX, const float* __restrict__ aaY,
    _Float16* __restrict__ Cxy, _Float16* __restrict__ Cxx,
    _Float16* __restrict__ Cyy, _Float16* __restrict__ CTxy)
{
    const int z = blockIdx.y;
    const int mat = z >> 4, b = z & 15;
    const int nt = blockIdx.x & 3, mt = blockIdx.x >> 2;
    if (mat != 0 && nt > mt) return;
    const _Float16 *P, *Q; const float *aP, *aQ;
    _Float16 *Cm, *CT;
    if (mat == 0)      { P = fX; Q = fY; aP = aaX; aQ = aaY; Cm = Cxy; CT = CTxy; }
    else if (mat == 1) { P = fX; Q = fX; aP = aaX; aQ = aaX; Cm = Cxx; CT = (nt < mt) ? Cxx : nullptr; }
    else               { P = fY; Q = fY; aP = aaY; aQ = aaY; Cm = Cyy; CT = (nt < mt) ? Cyy : nullptr; }

    const int tid = threadIdx.x, lane = tid & 63, wv = tid >> 6;
    const int m16 = lane & 15, quad = lane >> 4;
    const int wv2 = wv >> 1, wvt = wv & 1;
    const int nb = nt * 128 + wv2 * 64;
    const int mb = mt * 128 + wvt * 64;
    const _Float16* Pb = P + (size_t)b * 512 * 224;
    const _Float16* Qb = Q + (size_t)b * 512 * 224;

    float4v acc[4][4];
#pragma unroll
    for (int i = 0; i < 4; ++i)
#pragma unroll
        for (int j = 0; j < 4; ++j) acc[i][j] = (float4v){0.f, 0.f, 0.f, 0.f};

    for (int k32 = 0; k32 < 7; ++k32) {
        const int ko = k32 * 32 + quad * 8;
        half8v a4[4], b4[4];
#pragma unroll
        for (int i = 0; i < 4; ++i)
            a4[i] = *(const half8v*)(Pb + (size_t)(nb + i * 16 + m16) * 224 + ko);
#pragma unroll
        for (int j = 0; j < 4; ++j)
            b4[j] = *(const half8v*)(Qb + (size_t)(mb + j * 16 + m16) * 224 + ko);
#pragma unroll
        for (int i = 0; i < 4; ++i)
#pragma unroll
            for (int j = 0; j < 4; ++j)
                acc[i][j] = __builtin_amdgcn_mfma_f32_16x16x32_f16(a4[i], b4[j], acc[i][j], 0, 0, 0);
    }

#pragma unroll
    for (int i = 0; i < 4; ++i) {
        const int nrow0 = nb + i * 16 + quad * 4;
        float aa4[4];
#pragma unroll
        for (int r = 0; r < 4; ++r) aa4[r] = aP[b * 512 + nrow0 + r];
#pragma unroll
        for (int j = 0; j < 4; ++j) {
            const int mcol = mb + j * 16 + m16;
            const float bbm = aQ[b * 512 + mcol];
#pragma unroll
            for (int r = 0; r < 4; ++r) {
                const int n = nrow0 + r;
                float c = 50.f * fmaxf(aa4[r] + bbm - 2.f * acc[i][j][r], 0.f);
                c = fminf(c, 65000.f);
                const _Float16 ch = (_Float16)c;
                Cm[((size_t)(b * 512 + n)) * 512 + mcol] = ch;
                if (CT) CT[((size_t)(b * 512 + mcol)) * 512 + n] = ch;
            }
        }
    }
}

// ---------------------------------------------------------------------------
// Per-row half-update (two-pass max-then-sum; __expf = native v_exp_f32.
// NOTE: bare exp2f/log2f regressed ~120us total (rounds 9/10) -- keep __expf).
// dst[p*512+i] = eps*log512 - eps*LSE_j( 400*src[j] - 4*M100[i,j] )
// ---------------------------------------------------------------------------
static __device__ __forceinline__ void sink_rows(
    float* __restrict__ dst, const float* __restrict__ src,
    const _Float16* __restrict__ Mb, int p, int i0, int lane)
{
    const float* sp = src + (size_t)p * 512;
    float s8[8];
    {
        const float4 sa = *(const float4*)&sp[lane * 8];
        const float4 sb = *(const float4*)&sp[lane * 8 + 4];
        s8[0]=sa.x*400.f; s8[1]=sa.y*400.f; s8[2]=sa.z*400.f; s8[3]=sa.w*400.f;
        s8[4]=sb.x*400.f; s8[5]=sb.y*400.f; s8[6]=sb.z*400.f; s8[7]=sb.w*400.f;
    }
#pragma unroll
    for (int rr = 0; rr < 4; ++rr) {
        const int i = i0 + rr;
        const half8v rv = *(const half8v*)(Mb + (size_t)i * 512 + lane * 8);
        float a8[8];
#pragma unroll
        for (int k = 0; k < 8; ++k) a8[k] = fmaf(-4.f, (float)rv[k], s8[k]);
        float mx = a8[0];
#pragma unroll
        for (int k = 1; k < 8; ++k) mx = fmaxf(mx, a8[k]);
        // wave-global max (fmax butterfly, no exps)
#pragma unroll
        for (int off = 32; off > 0; off >>= 1) mx = fmaxf(mx, __shfl_xor(mx, off));
        // sum of exp(a - global max)
        float ss = 0.f;
#pragma unroll
        for (int k = 0; k < 8; ++k) ss += __expf(a8[k] - mx);
#pragma unroll
        for (int off = 32; off > 0; off >>= 1) ss += __shfl_xor(ss, off);
        if (lane == 0)
            dst[(size_t)p * 512 + i] = EPS_LOG512 - EPS_SINK * (mx + logf(ss));
    }
}

// ---------------------------------------------------------------------------
// sink_update v2: one half-update per launch; 1536 1D blocks with
// XCD-PARTITIONED matrix mapping: assuming round-robin block->XCD dispatch
// (L % 8), XCD k owns matrices {xy: 2k,2k+1} + {sym: 16+4k..16+4k+3} =
// 2x1MB (C+CT) + 4x0.5MB = 4MB == per-XCD L2. C stays L2-resident across
// all 100 launches (prev grid spread every matrix over all 8 XCDs ->
// 24.6MB footprint/XCD -> thrash; measured 12.7MB HBM fetch/launch).
// ---------------------------------------------------------------------------
__global__ __launch_bounds__(256) void sink_update(
    float* __restrict__ dst, const float* __restrict__ src,
    const _Float16* __restrict__ M0, const _Float16* __restrict__ M1,
    const _Float16* __restrict__ M2)
{
    const int L = blockIdx.x;
    const int k = L & 7;                       // XCD (round-robin assumption)
    const int mloc = L >> 3;                   // 0..191 within XCD
    const int idx = mloc >> 5;                 // 0..5: which owned matrix
    const int chunk = mloc & 31;               // 32 row-chunks of 16
    const int p = (idx < 2) ? (2 * k + idx) : (16 + 4 * k + (idx - 2));
    const int mat = p >> 4, b = p & 15;
    const _Float16* M = ((mat == 0) ? M0 : ((mat == 1) ? M1 : M2)) + (size_t)b * 512 * 512;
    const int wave = threadIdx.x >> 6, lane = threadIdx.x & 63;
    const int i0 = chunk * 16 + wave * 4;
    sink_rows(dst, src, M, p, i0, lane);
}

// ---------------------------------------------------------------------------
__global__ __launch_bounds__(256) void final_kernel(
    const float* __restrict__ f, const float* __restrict__ g,
    float* __restrict__ out)
{
    const int b = blockIdx.x, tid = threadIdx.x;
    __shared__ float red[256];
    float a = 0.f;
    for (int n = tid; n < 512; n += 256) {
        const float xy = f[(0 * 16 + b) * 512 + n] + g[(0 * 16 + b) * 512 + n];
        const float xx = f[(1 * 16 + b) * 512 + n] + g[(1 * 16 + b) * 512 + n];
        const float yy = f[(2 * 16 + b) * 512 + n] + g[(2 * 16 + b) * 512 + n];
        a += xy - 0.5f * (xx + yy);
    }
    red[tid] = a;
    __syncthreads();
    for (int s2 = 128; s2 > 0; s2 >>= 1) {
        if (tid < s2) red[tid] += red[tid + s2];
        __syncthreads();
    }
    if (tid == 0) out[b] = red[0] * (1.0f / 512.0f);
}

// ---------------------------------------------------------------------------
extern "C" void kernel_launch(void* const* d_in, const int* in_sizes, int n_in,
                              void* d_out, int out_size, void* d_ws, size_t ws_size,
                              hipStream_t stream)
{
    (void)in_sizes; (void)n_in; (void)out_size; (void)ws_size;
    char* ws = (char*)d_ws;
    const float* yhat = (const float*)d_in[0];
    const float* ysig = (const float*)d_in[1];
    const float* Wl[5]; const float* gl[5]; const float* bl[5];
    for (int i = 0; i < 5; ++i) {
        Wl[i] = (const float*)d_in[2 + 3 * i];
        gl[i] = (const float*)d_in[3 + 3 * i];
        bl[i] = (const float*)d_in[4 + 3 * i];
    }
    float* out = (float*)d_out;
    float* statsA = (float*)(ws + O_STATS);

    _Float16* w1 = (_Float16*)(ws + O_W1);
    _Float16* w2 = (_Float16*)(ws + O_W2);
    _Float16* w3 = (_Float16*)(ws + O_W3);
    _Float16* w4 = (_Float16*)(ws + O_W4);
    _Float16* h0  = (_Float16*)(ws + O_H0);
    _Float16* h1  = (_Float16*)(ws + O_H1);
    _Float16* h2X = (_Float16*)(ws + O_H2X);
    _Float16* h2Y = (_Float16*)(ws + O_H2Y);
    _Float16* h3X = (_Float16*)(ws + O_H3X);
    _Float16* h3Y = (_Float16*)(ws + O_H3Y);
    _Float16* featX = (_Float16*)(ws + O_FEATX);
    _Float16* featY = (_Float16*)(ws + O_FEATY);
    float* stX = statsA;           // signal X stats (160 floats)
    float* stY = statsA + 160;     // signal Y stats

    hipMemsetAsync(statsA, 0, 512 * sizeof(float), stream);
    prep_w<<<dim3(1024, 4), 256, 0, stream>>>(Wl[1], Wl[2], Wl[3], Wl[4],
        w1, w2, w3, w4);

    // --- X pipeline through conv2 (h0 is per-signal scratch)
    conv0_store<<<dim3(13, 4, 16), 256, 0, stream>>>(yhat, Wl[0], h0, stX);
    conv1_mfma<<<dim3(832), 256, 0, stream>>>(
        h0, w1, stX, gl[0], bl[0], h1, stX + 32);
    conv_mfma<true><<<dim3(832, 1), 256, 0, stream>>>(
        h1, h1, w2, stX + 32, stX + 32, gl[1], bl[1],
        h2X, h2X, nullptr, nullptr, stX + 64, stX + 64, 1598, 798, 13);

    // --- Y pipeline through conv2
    conv0_store<<<dim3(13, 4, 16), 256, 0, stream>>>(ysig, Wl[0], h0, stY);
    conv1_mfma<<<dim3(832), 256, 0, stream>>>(
        h0, w1, stY, gl[0], bl[0], h1, stY + 32);
    conv_mfma<true><<<dim3(832, 1), 256, 0, stream>>>(
        h1, h1, w2, stY + 32, stY + 32, gl[1], bl[1],
        h2Y, h2Y, nullptr, nullptr, stY + 64, stY + 64, 1598, 798, 13);

    // --- batched conv3 (both signals; 896 blocks)
    conv_mfma<true><<<dim3(448, 2), 256, 0, stream>>>(
        h2X, h2Y, w3, stX + 64, stY + 64, gl[2], bl[2],
        h3X, h3Y, nullptr, nullptr, stX + 96, stY + 96, 798, 398, 7);

    // --- batched conv4 (both signals; 512 blocks; self-zeroes K-pad cols)
    conv_mfma<false><<<dim3(256, 2), 256, 0, stream>>>(
        h3X, h3Y, w4, stX + 96, stY + 96, gl[3], bl[3],
        nullptr, nullptr, featX, featY, stX + 128, stY + 128, 398, 198, 4);

    // --- batched norm_feat
    norm_feat<<<dim3(1, 16384), 256, 0, stream>>>(
        featX, featY, stX + 128, stY + 128, gl[4], bl[4]);

    aa_kernel<<<4096, 256, 0, stream>>>(featX, featY, (float*)(ws + O_AAX), (float*)(ws + O_AAY));
    cost_kernel<<<dim3(16, 48), 256, 0, stream>>>(
        featX, featY, (float*)(ws + O_AAX), (float*)(ws + O_AAY),
        (_Float16*)(ws + O_CXY), (_Float16*)(ws + O_CXX), (_Float16*)(ws + O_CYY),
        (_Float16*)(ws + O_CTXY));

    hipMemsetAsync(ws + O_F, 0, 2 * 24576 * sizeof(float), stream);

    float* fptr = (float*)(ws + O_F);
    float* gptr = (float*)(ws + O_G);
    _Float16* cxy  = (_Float16*)(ws + O_CXY);
    _Float16* ctxy = (_Float16*)(ws + O_CTXY);
    _Float16* cxx  = (_Float16*)(ws + O_CXX);
    _Float16* cyy  = (_Float16*)(ws + O_CYY);

    for (int it = 0; it < 50; ++it) {
        sink_update<<<dim3(1536), 256, 0, stream>>>(gptr, fptr, ctxy, cxx, cyy);
        sink_update<<<dim3(1536), 256, 0, stream>>>(fptr, gptr, cxy, cxx, cyy);
    }

    final_kernel<<<16, 256, 0, stream>>>(fptr, gptr, out);
}